// Round 2
// baseline (1032.272 us; speedup 1.0000x reference)
//
#include <hip/hip_runtime.h>

typedef unsigned short u16;
typedef unsigned int u32;
typedef __attribute__((ext_vector_type(8))) short bf16x8;
typedef __attribute__((ext_vector_type(4))) float f32x4;

constexpr int H = 2048;
constexpr int NH = 16;
constexpr int HD = 128;
constexpr float SCALE = 0.08838834764831845f; // 1/sqrt(128)

__device__ __forceinline__ u16 f2bf(float f) {
    u32 u = __float_as_uint(f);
    u32 r = u + 0x7fffu + ((u >> 16) & 1u);   // RNE (finite inputs only)
    return (u16)(r >> 16);
}
__device__ __forceinline__ u32 pack2(float x, float y) {
    return (u32)f2bf(x) | ((u32)f2bf(y) << 16);
}

// ---------------- f32 -> bf16 convert (vectorized) ----------------
__global__ __launch_bounds__(256) void cvt_f32_bf16(const float* __restrict__ in,
                                                    u16* __restrict__ out, int n4) {
    int i = blockIdx.x * 256 + threadIdx.x;
    if (i >= n4) return;
    float4 v = reinterpret_cast<const float4*>(in)[i];
    uint2 o;
    o.x = pack2(v.x, v.y);
    o.y = pack2(v.z, v.w);
    reinterpret_cast<uint2*>(out)[i] = o;
}

// ---------------- RMSNorm f32 -> bf16, H=2048, one block per row ----------------
__global__ __launch_bounds__(256) void rmsnorm_kernel(const float* __restrict__ x,
                                                      const float* __restrict__ w,
                                                      u16* __restrict__ y) {
    int r = blockIdx.x;
    const float4* xr = reinterpret_cast<const float4*>(x + (size_t)r * H);
    int t = threadIdx.x;
    float4 v0 = xr[t * 2], v1 = xr[t * 2 + 1];
    float ss = v0.x * v0.x + v0.y * v0.y + v0.z * v0.z + v0.w * v0.w
             + v1.x * v1.x + v1.y * v1.y + v1.z * v1.z + v1.w * v1.w;
#pragma unroll
    for (int d = 1; d < 64; d <<= 1) ss += __shfl_xor(ss, d);
    __shared__ float red[4];
    if ((t & 63) == 0) red[t >> 6] = ss;
    __syncthreads();
    float tot = red[0] + red[1] + red[2] + red[3];
    float rs = rsqrtf(tot * (1.0f / H) + 1e-6f);
    const float4* wr = reinterpret_cast<const float4*>(w);
    float4 w0 = wr[t * 2], w1 = wr[t * 2 + 1];
    uint4 o;
    o.x = pack2(v0.x * rs * w0.x, v0.y * rs * w0.y);
    o.y = pack2(v0.z * rs * w0.z, v0.w * rs * w0.w);
    o.z = pack2(v1.x * rs * w1.x, v1.y * rs * w1.y);
    o.w = pack2(v1.z * rs * w1.z, v1.w * rs * w1.w);
    reinterpret_cast<uint4*>(y + (size_t)r * H)[t] = o;
}

// ---------------- GEMM: C[M,N] = A_bf16[M,K] @ B_f32[K,N] ----------------
// MODE 0: store bf16 C.  MODE 1: Cf = resid + sigmoid(*gate_p) * acc (f32 out).
#define BM 128
#define BN 128
#define BK 32
#define LDSP 40

template <int MODE>
__global__ __launch_bounds__(256)
void gemm_bf16(const u16* __restrict__ A, const float* __restrict__ Bw,
               u16* __restrict__ Cb, float* __restrict__ Cf,
               const float* __restrict__ resid, const float* __restrict__ gate_p,
               int M, int N, int K) {
    __shared__ u16 As[BM * LDSP];
    __shared__ u16 Bs[BN * LDSP];
    const int t = threadIdx.x;
    const int lane = t & 63, wid = t >> 6;
    const int wm = wid >> 1, wn = wid & 1;
    const int brow = blockIdx.y * BM, bcol = blockIdx.x * BN;

    f32x4 acc[4][4] = {};
    const int arow = t >> 1, aseg = (t & 1) * 16;   // 16 bf16 per thread
    const int b_row = t >> 3, b_f4 = t & 7;
    const int k0 = (lane >> 4) * 8;

    for (int kt = 0; kt < K; kt += BK) {
        // stage A (bf16): 128x32, 32B per thread (2 x uint4)
        const u16* asrc = A + (size_t)(brow + arow) * K + kt + aseg;
        *reinterpret_cast<uint4*>(&As[arow * LDSP + aseg]) =
            *reinterpret_cast<const uint4*>(asrc);
        *reinterpret_cast<uint4*>(&As[arow * LDSP + aseg + 8]) =
            *reinterpret_cast<const uint4*>(asrc + 8);
        // stage B (f32 -> bf16, transposed): 32x128
#pragma unroll
        for (int j = 0; j < 4; ++j) {
            int c4 = b_f4 + j * 8;
            float4 bv = *reinterpret_cast<const float4*>(Bw + (size_t)(kt + b_row) * N + bcol + c4 * 4);
            int col = c4 * 4;
            Bs[(col + 0) * LDSP + b_row] = f2bf(bv.x);
            Bs[(col + 1) * LDSP + b_row] = f2bf(bv.y);
            Bs[(col + 2) * LDSP + b_row] = f2bf(bv.z);
            Bs[(col + 3) * LDSP + b_row] = f2bf(bv.w);
        }
        __syncthreads();
        bf16x8 af[4], bfr[4];
#pragma unroll
        for (int i = 0; i < 4; ++i)
            af[i] = *reinterpret_cast<const bf16x8*>(&As[(wm * 64 + i * 16 + (lane & 15)) * LDSP + k0]);
#pragma unroll
        for (int j = 0; j < 4; ++j)
            bfr[j] = *reinterpret_cast<const bf16x8*>(&Bs[(wn * 64 + j * 16 + (lane & 15)) * LDSP + k0]);
#pragma unroll
        for (int i = 0; i < 4; ++i)
#pragma unroll
            for (int j = 0; j < 4; ++j)
                acc[i][j] = __builtin_amdgcn_mfma_f32_16x16x32_bf16(af[i], bfr[j], acc[i][j], 0, 0, 0);
        __syncthreads();
    }
    float g = 0.f;
    if (MODE == 1) g = 1.0f / (1.0f + expf(-gate_p[0]));
    const int r0 = (lane >> 4) * 4, c0 = lane & 15;
#pragma unroll
    for (int i = 0; i < 4; ++i) {
#pragma unroll
        for (int j = 0; j < 4; ++j) {
            int col = bcol + wn * 64 + j * 16 + c0;
#pragma unroll
            for (int r = 0; r < 4; ++r) {
                int row = brow + wm * 64 + i * 16 + r0 + r;
                float v = acc[i][j][r];
                if (MODE == 0) Cb[(size_t)row * N + col] = f2bf(v);
                else Cf[(size_t)row * N + col] = resid[(size_t)row * N + col] + g * v;
            }
        }
    }
}

// ---------------- coarse attention (ND=64 keys, exact softmax) ----------------
// grid: B*NH*(S/64), block 256 (4 waves x 16 query rows)
__global__ __launch_bounds__(256)
void coarse_attn(const u16* __restrict__ q, const u16* __restrict__ kc,
                 const u16* __restrict__ vc, const float* __restrict__ mask,
                 float* __restrict__ doc_part, u16* __restrict__ attn_c) {
    constexpr int SC = 2048 / 64;
    int bid = blockIdx.x;
    int b = bid / (NH * SC);
    int rem = bid % (NH * SC);
    int h = rem / SC, sc = rem % SC;
    int kv = h >> 2;
    int t = threadIdx.x, lane = t & 63, wid = t >> 6;
    const int l15 = lane & 15, k0 = (lane >> 4) * 8;

    __shared__ u16 Kt[64 * 136];
    __shared__ u16 Vt[128 * 72];
    __shared__ u16 Pt[4][16 * 72];
    __shared__ float p_acc[64];

    {   // stage K [64 keys][128 d]
        int n = t >> 2, s2 = t & 3;
        const u16* src = kc + (size_t)(b * 64 + n) * 512 + kv * 128;
#pragma unroll
        for (int u = 0; u < 4; ++u) {
            int sg = s2 + u * 4;
            *reinterpret_cast<uint4*>(&Kt[n * 136 + sg * 8]) =
                *reinterpret_cast<const uint4*>(src + sg * 8);
        }
    }
    {   // stage V transposed: Vt[d][key]
        int n = t & 63, dblk = t >> 6;
        const u16* src = vc + (size_t)(b * 64 + n) * 512 + kv * 128 + dblk * 32;
#pragma unroll
        for (int u = 0; u < 4; ++u) {
            u16 tmp[8];
            *reinterpret_cast<uint4*>(tmp) = *reinterpret_cast<const uint4*>(src + u * 8);
#pragma unroll
            for (int e = 0; e < 8; ++e) Vt[(dblk * 32 + u * 8 + e) * 72 + n] = tmp[e];
        }
    }
    if (t < 64) p_acc[t] = 0.f;
    __syncthreads();

    int qrow = sc * 64 + wid * 16 + l15;
    const u16* qsrc = q + (size_t)(b * 2048 + qrow) * 2048 + h * 128;
    bf16x8 af[4];
#pragma unroll
    for (int kk = 0; kk < 4; ++kk)
        af[kk] = *reinterpret_cast<const bf16x8*>(qsrc + kk * 32 + k0);

    f32x4 sc4[4] = {};
#pragma unroll
    for (int kk = 0; kk < 4; ++kk)
#pragma unroll
        for (int j = 0; j < 4; ++j) {
            bf16x8 bfr = *reinterpret_cast<const bf16x8*>(&Kt[(j * 16 + l15) * 136 + kk * 32 + k0]);
            sc4[j] = __builtin_amdgcn_mfma_f32_16x16x32_bf16(af[kk], bfr, sc4[j], 0, 0, 0);
        }

    float s[4][4];
#pragma unroll
    for (int j = 0; j < 4; ++j) {
        float bia = (1.0f - mask[b * 64 + j * 16 + l15]) * -1e9f;
#pragma unroll
        for (int r = 0; r < 4; ++r) s[j][r] = sc4[j][r] * SCALE + bia;
    }
    float m4[4], l4[4];
#pragma unroll
    for (int r = 0; r < 4; ++r) {
        float m = fmaxf(fmaxf(s[0][r], s[1][r]), fmaxf(s[2][r], s[3][r]));
#pragma unroll
        for (int d = 1; d < 16; d <<= 1) m = fmaxf(m, __shfl_xor(m, d));
        m4[r] = m;
    }
#pragma unroll
    for (int r = 0; r < 4; ++r) {
        float l = 0.f;
#pragma unroll
        for (int j = 0; j < 4; ++j) { s[j][r] = expf(s[j][r] - m4[r]); l += s[j][r]; }
#pragma unroll
        for (int d = 1; d < 16; d <<= 1) l += __shfl_xor(l, d);
        l4[r] = l;
    }
#pragma unroll
    for (int j = 0; j < 4; ++j) {
        float cs = 0.f;
#pragma unroll
        for (int r = 0; r < 4; ++r) {
            float pr = s[j][r] / l4[r];
            Pt[wid][((lane >> 4) * 4 + r) * 72 + j * 16 + l15] = f2bf(pr);
            cs += pr;
        }
        cs += __shfl_xor(cs, 16);
        cs += __shfl_xor(cs, 32);
        if (lane < 16) atomicAdd(&p_acc[j * 16 + lane], cs);
    }
    __syncthreads();

    f32x4 o4[8] = {};
#pragma unroll
    for (int kk2 = 0; kk2 < 2; ++kk2) {
        bf16x8 a2 = *reinterpret_cast<const bf16x8*>(&Pt[wid][l15 * 72 + kk2 * 32 + k0]);
#pragma unroll
        for (int j2 = 0; j2 < 8; ++j2) {
            bf16x8 b2 = *reinterpret_cast<const bf16x8*>(&Vt[(j2 * 16 + l15) * 72 + kk2 * 32 + k0]);
            o4[j2] = __builtin_amdgcn_mfma_f32_16x16x32_bf16(a2, b2, o4[j2], 0, 0, 0);
        }
    }
#pragma unroll
    for (int j2 = 0; j2 < 8; ++j2)
#pragma unroll
        for (int r = 0; r < 4; ++r) {
            int row = sc * 64 + wid * 16 + (lane >> 4) * 4 + r;
            attn_c[(size_t)(b * 2048 + row) * 2048 + h * 128 + j2 * 16 + l15] = f2bf(o4[j2][r]);
        }
    if (t < 64) atomicAdd(&doc_part[(blockIdx.x & 7) * 128 + b * 64 + t], p_acc[t]);
}

// ---------------- doc-score finalize + fine bias ----------------
__global__ void doc_finalize(const float* __restrict__ doc_part, float* __restrict__ log_ds) {
    int t = threadIdx.x; // 128
    float s = 0.f;
#pragma unroll
    for (int i = 0; i < 8; ++i) s += doc_part[i * 128 + t];
    log_ds[t] = logf(s / 32768.0f + 1e-6f);
}

__global__ __launch_bounds__(256)
void bias_kernel(const float* __restrict__ log_ds, const int* __restrict__ map,
                 const float* __restrict__ tmask, float* __restrict__ bias) {
    int i = blockIdx.x * 256 + threadIdx.x;
    if (i >= 2 * 2048) return;
    int b = i >> 11;
    bias[i] = log_ds[b * 64 + map[i]] + (1.0f - tmask[i]) * -1e9f;
}

// ---------------- fine flash attention (T=2048, KB=32 tiles) ----------------
__global__ __launch_bounds__(256)
void flash_attn(const u16* __restrict__ q, const u16* __restrict__ kf,
                const u16* __restrict__ vf, const float* __restrict__ bias,
                u16* __restrict__ attn_f) {
    constexpr int SC = 2048 / 64;
    int bid = blockIdx.x;
    int b = bid / (NH * SC);
    int rem = bid % (NH * SC);
    int h = rem / SC, sc = rem % SC;
    int kv = h >> 2;
    int t = threadIdx.x, lane = t & 63, wid = t >> 6;
    const int l15 = lane & 15, k0 = (lane >> 4) * 8;

    __shared__ u16 Kt[32 * 136];
    __shared__ u16 Vt[128 * 40];
    __shared__ u16 Pt[4][16 * 40];
    __shared__ float bias_s[32];

    int qrow = sc * 64 + wid * 16 + l15;
    const u16* qsrc = q + (size_t)(b * 2048 + qrow) * 2048 + h * 128;
    bf16x8 af[4];
#pragma unroll
    for (int kk = 0; kk < 4; ++kk)
        af[kk] = *reinterpret_cast<const bf16x8*>(qsrc + kk * 32 + k0);

    float m4[4] = {-1e30f, -1e30f, -1e30f, -1e30f};
    float l4[4] = {};
    f32x4 o4[8] = {};

    for (int t0 = 0; t0 < 2048; t0 += 32) {
        {   // stage K [32][128]
            int n = t >> 3, sg = t & 7;
            const u16* src = kf + (size_t)(b * 2048 + t0 + n) * 512 + kv * 128;
            *reinterpret_cast<uint4*>(&Kt[n * 136 + sg * 8]) =
                *reinterpret_cast<const uint4*>(src + sg * 8);
            *reinterpret_cast<uint4*>(&Kt[n * 136 + (sg + 8) * 8]) =
                *reinterpret_cast<const uint4*>(src + (sg + 8) * 8);
        }
        {   // stage V transposed: Vt[d][key]
            int n = t & 31, dblk = t >> 5;
            const u16* src = vf + (size_t)(b * 2048 + t0 + n) * 512 + kv * 128 + dblk * 16;
            u16 tmp[8];
            *reinterpret_cast<uint4*>(tmp) = *reinterpret_cast<const uint4*>(src);
#pragma unroll
            for (int e = 0; e < 8; ++e) Vt[(dblk * 16 + e) * 40 + n] = tmp[e];
            *reinterpret_cast<uint4*>(tmp) = *reinterpret_cast<const uint4*>(src + 8);
#pragma unroll
            for (int e = 0; e < 8; ++e) Vt[(dblk * 16 + 8 + e) * 40 + n] = tmp[e];
        }
        if (t < 32) bias_s[t] = bias[b * 2048 + t0 + t];
        __syncthreads();

        f32x4 sc4[2] = {};
#pragma unroll
        for (int kk = 0; kk < 4; ++kk)
#pragma unroll
            for (int j = 0; j < 2; ++j) {
                bf16x8 bfr = *reinterpret_cast<const bf16x8*>(&Kt[(j * 16 + l15) * 136 + kk * 32 + k0]);
                sc4[j] = __builtin_amdgcn_mfma_f32_16x16x32_bf16(af[kk], bfr, sc4[j], 0, 0, 0);
            }

        float s[2][4];
#pragma unroll
        for (int j = 0; j < 2; ++j) {
            float bia = bias_s[j * 16 + l15];
#pragma unroll
            for (int r = 0; r < 4; ++r) s[j][r] = sc4[j][r] * SCALE + bia;
        }
        float sc_old[4];
#pragma unroll
        for (int r = 0; r < 4; ++r) {
            float m = fmaxf(s[0][r], s[1][r]);
#pragma unroll
            for (int d = 1; d < 16; d <<= 1) m = fmaxf(m, __shfl_xor(m, d));
            float mn = fmaxf(m4[r], m);
            sc_old[r] = expf(m4[r] - mn);
            m4[r] = mn;
            float ps = 0.f;
#pragma unroll
            for (int j = 0; j < 2; ++j) { s[j][r] = expf(s[j][r] - mn); ps += s[j][r]; }
#pragma unroll
            for (int d = 1; d < 16; d <<= 1) ps += __shfl_xor(ps, d);
            l4[r] = l4[r] * sc_old[r] + ps;
        }
#pragma unroll
        for (int j = 0; j < 2; ++j)
#pragma unroll
            for (int r = 0; r < 4; ++r)
                Pt[wid][((lane >> 4) * 4 + r) * 40 + j * 16 + l15] = f2bf(s[j][r]);
#pragma unroll
        for (int j2 = 0; j2 < 8; ++j2)
#pragma unroll
            for (int r = 0; r < 4; ++r) o4[j2][r] *= sc_old[r];
        __syncthreads();

        bf16x8 a2 = *reinterpret_cast<const bf16x8*>(&Pt[wid][l15 * 40 + k0]);
#pragma unroll
        for (int j2 = 0; j2 < 8; ++j2) {
            bf16x8 b2 = *reinterpret_cast<const bf16x8*>(&Vt[(j2 * 16 + l15) * 40 + k0]);
            o4[j2] = __builtin_amdgcn_mfma_f32_16x16x32_bf16(a2, b2, o4[j2], 0, 0, 0);
        }
        __syncthreads();
    }
#pragma unroll
    for (int j2 = 0; j2 < 8; ++j2)
#pragma unroll
        for (int r = 0; r < 4; ++r) {
            int row = sc * 64 + wid * 16 + (lane >> 4) * 4 + r;
            attn_f[(size_t)(b * 2048 + row) * 2048 + h * 128 + j2 * 16 + l15] =
                f2bf(o4[j2][r] / l4[r]);
        }
}

// ---------------- launch ----------------
extern "C" void kernel_launch(void* const* d_in, const int* in_sizes, int n_in,
                              void* d_out, int out_size, void* d_ws, size_t ws_size,
                              hipStream_t stream) {
    const float* hidden = (const float*)d_in[0];
    const float* dsk    = (const float*)d_in[1];
    const float* dsv    = (const float*)d_in[2];
    const float* dsmask = (const float*)d_in[3];
    const float* tk     = (const float*)d_in[4];
    const float* tv     = (const float*)d_in[5];
    const float* tmask  = (const float*)d_in[6];
    const float* cn_w   = (const float*)d_in[7];
    const float* cq_w   = (const float*)d_in[8];
    const float* ck_w   = (const float*)d_in[9];
    const float* cv_w   = (const float*)d_in[10];
    const float* co_w   = (const float*)d_in[11];
    const float* c_gate = (const float*)d_in[12];
    const float* fn_w   = (const float*)d_in[13];
    const float* fq_w   = (const float*)d_in[14];
    const float* fk_w   = (const float*)d_in[15];
    const float* fv_w   = (const float*)d_in[16];
    const float* fo_w   = (const float*)d_in[17];
    const float* f_gate = (const float*)d_in[18];
    const int*   map    = (const int*)d_in[19];
    float* out_f = (float*)d_out;

    char* ws = (char*)d_ws;
    size_t off = 0;
    auto alloc = [&](size_t bytes) {
        char* p = ws + off;
        off += (bytes + 255) & ~(size_t)255;
        return p;
    };
    u16*  normA    = (u16*)alloc(4096ULL * 2048 * 2);
    u16*  qbuf     = (u16*)alloc(4096ULL * 2048 * 2);
    float* out32   = (float*)alloc(4096ULL * 2048 * 4);
    u16*  kc       = (u16*)alloc(128ULL * 512 * 2);
    u16*  vc       = (u16*)alloc(128ULL * 512 * 2);
    u16*  dskb     = (u16*)alloc(128ULL * 2048 * 2);
    u16*  dsvb     = (u16*)alloc(128ULL * 2048 * 2);
    u16*  kfb      = (u16*)alloc(4096ULL * 512 * 2);
    u16*  vfb      = (u16*)alloc(4096ULL * 512 * 2);
    float* doc_part = (float*)alloc(8 * 128 * 4);
    float* log_ds   = (float*)alloc(128 * 4);
    float* biasb    = (float*)alloc(4096 * 4);

    hipMemsetAsync(doc_part, 0, 8 * 128 * 4, stream);

    cvt_f32_bf16<<<(128 * 2048 / 4 + 255) / 256, 256, 0, stream>>>(dsk, dskb, 128 * 2048 / 4);
    cvt_f32_bf16<<<(128 * 2048 / 4 + 255) / 256, 256, 0, stream>>>(dsv, dsvb, 128 * 2048 / 4);
    rmsnorm_kernel<<<4096, 256, 0, stream>>>(hidden, cn_w, normA);

    // coarse projections
    gemm_bf16<0><<<dim3(16, 32), 256, 0, stream>>>(normA, cq_w, qbuf, nullptr, nullptr, nullptr, 4096, 2048, 2048);
    gemm_bf16<0><<<dim3(4, 1), 256, 0, stream>>>(dskb, ck_w, kc, nullptr, nullptr, nullptr, 128, 512, 2048);
    gemm_bf16<0><<<dim3(4, 1), 256, 0, stream>>>(dsvb, cv_w, vc, nullptr, nullptr, nullptr, 128, 512, 2048);

    // coarse attention (writes attn_c into normA) + doc-score partials
    coarse_attn<<<1024, 256, 0, stream>>>(qbuf, kc, vc, dsmask, doc_part, normA);
    doc_finalize<<<1, 128, 0, stream>>>(doc_part, log_ds);
    bias_kernel<<<16, 256, 0, stream>>>(log_ds, map, tmask, biasb);

    // o-proj + residual + gate -> out32
    gemm_bf16<1><<<dim3(16, 32), 256, 0, stream>>>(normA, co_w, nullptr, out32, hidden, c_gate, 4096, 2048, 2048);

    // fine stage
    rmsnorm_kernel<<<4096, 256, 0, stream>>>(out32, fn_w, qbuf);
    gemm_bf16<0><<<dim3(16, 32), 256, 0, stream>>>(qbuf, fq_w, normA, nullptr, nullptr, nullptr, 4096, 2048, 2048);
    cvt_f32_bf16<<<(4096 * 2048 / 4 + 255) / 256, 256, 0, stream>>>(tk, qbuf, 4096 * 2048 / 4);
    gemm_bf16<0><<<dim3(4, 32), 256, 0, stream>>>(qbuf, fk_w, kfb, nullptr, nullptr, nullptr, 4096, 512, 2048);
    cvt_f32_bf16<<<(4096 * 2048 / 4 + 255) / 256, 256, 0, stream>>>(tv, qbuf, 4096 * 2048 / 4);
    gemm_bf16<0><<<dim3(4, 32), 256, 0, stream>>>(qbuf, fv_w, vfb, nullptr, nullptr, nullptr, 4096, 512, 2048);

    flash_attn<<<1024, 256, 0, stream>>>(normA, kfb, vfb, biasb, qbuf);

    // final o-proj + residual + gate -> d_out
    gemm_bf16<1><<<dim3(16, 32), 256, 0, stream>>>(qbuf, fo_w, nullptr, out_f, out32, f_gate, 4096, 2048, 2048);
}

// Round 3
// 699.216 us; speedup vs baseline: 1.4763x; 1.4763x over previous
//
#include <hip/hip_runtime.h>

typedef unsigned short u16;
typedef unsigned int u32;
typedef __attribute__((ext_vector_type(8))) short bf16x8;
typedef __attribute__((ext_vector_type(4))) float f32x4;

constexpr int NH = 16;
constexpr int H = 2048;
constexpr float SCALE = 0.08838834764831845f; // 1/sqrt(128)

__device__ __forceinline__ u16 f2bf(float f) {
    u32 u = __float_as_uint(f);
    u32 r = u + 0x7fffu + ((u >> 16) & 1u);   // RNE (finite inputs only)
    return (u16)(r >> 16);
}
__device__ __forceinline__ u32 pack2(float x, float y) {
    return (u32)f2bf(x) | ((u32)f2bf(y) << 16);
}

#define GLD_LDS16(gsrc, ldst)                                                  \
    __builtin_amdgcn_global_load_lds(                                          \
        (const __attribute__((address_space(1))) void*)(gsrc),                 \
        (__attribute__((address_space(3))) void*)(ldst), 16, 0, 0)

// ---------------- f32 -> bf16 convert (vectorized) ----------------
__global__ __launch_bounds__(256) void cvt_f32_bf16(const float* __restrict__ in,
                                                    u16* __restrict__ out, int n4) {
    int i = blockIdx.x * 256 + threadIdx.x;
    if (i >= n4) return;
    float4 v = reinterpret_cast<const float4*>(in)[i];
    uint2 o;
    o.x = pack2(v.x, v.y);
    o.y = pack2(v.z, v.w);
    reinterpret_cast<uint2*>(out)[i] = o;
}

// ---------------- weight transpose + convert: f32[K][N] -> bf16[N][K] ----------------
__global__ __launch_bounds__(256)
void transpose_cvt(const float* __restrict__ in, u16* __restrict__ out, int K, int N) {
    __shared__ u16 tile[32][33];
    int bn = blockIdx.x * 32, bk = blockIdx.y * 32;
    int tx = threadIdx.x & 31, ty = threadIdx.x >> 5;  // ty 0..7
#pragma unroll
    for (int r = 0; r < 32; r += 8)
        tile[tx][r + ty] = f2bf(in[(size_t)(bk + r + ty) * N + bn + tx]);
    __syncthreads();
#pragma unroll
    for (int r = 0; r < 32; r += 8)
        out[(size_t)(bn + r + ty) * K + bk + tx] = tile[r + ty][tx];
}

// ---------------- RMSNorm f32 -> bf16, H=2048, one block per row ----------------
__global__ __launch_bounds__(256) void rmsnorm_kernel(const float* __restrict__ x,
                                                      const float* __restrict__ w,
                                                      u16* __restrict__ y) {
    int r = blockIdx.x;
    const float4* xr = reinterpret_cast<const float4*>(x + (size_t)r * H);
    int t = threadIdx.x;
    float4 v0 = xr[t * 2], v1 = xr[t * 2 + 1];
    float ss = v0.x * v0.x + v0.y * v0.y + v0.z * v0.z + v0.w * v0.w
             + v1.x * v1.x + v1.y * v1.y + v1.z * v1.z + v1.w * v1.w;
#pragma unroll
    for (int d = 1; d < 64; d <<= 1) ss += __shfl_xor(ss, d);
    __shared__ float red[4];
    if ((t & 63) == 0) red[t >> 6] = ss;
    __syncthreads();
    float tot = red[0] + red[1] + red[2] + red[3];
    float rs = rsqrtf(tot * (1.0f / H) + 1e-6f);
    const float4* wr = reinterpret_cast<const float4*>(w);
    float4 w0 = wr[t * 2], w1 = wr[t * 2 + 1];
    uint4 o;
    o.x = pack2(v0.x * rs * w0.x, v0.y * rs * w0.y);
    o.y = pack2(v0.z * rs * w0.z, v0.w * rs * w0.w);
    o.z = pack2(v1.x * rs * w1.x, v1.y * rs * w1.y);
    o.w = pack2(v1.z * rs * w1.z, v1.w * rs * w1.w);
    reinterpret_cast<uint4*>(y + (size_t)r * H)[t] = o;
}

// ---------------- GEMM (m97 structure): C[M,N] = A_bf16[M,K] @ Bt_bf16[N,K]^T --------
// MODE 0: store bf16 C.  MODE 1: Cf = resid + sigmoid(*gate_p) * acc (f32 out).
template <int MODE>
__global__ __launch_bounds__(256)
void gemm_tn(const u16* __restrict__ A, const u16* __restrict__ Bt,
             u16* __restrict__ Cb, float* __restrict__ Cf,
             const float* __restrict__ resid, const float* __restrict__ gate_p,
             int M, int N, int K) {
    __shared__ u16 As[128 * 32];
    __shared__ u16 Bs[128 * 32];
    const int t = threadIdx.x;
    const int lane = t & 63, wid = t >> 6;
    const int wm = wid >> 1, wn = wid & 1;
    const int brow = blockIdx.y * 128, bcol = blockIdx.x * 128;
    const int l15 = lane & 15;
    const int k0 = (lane >> 4) * 8;

    f32x4 acc[4][4] = {};
    // staging: per wave, rows [wid*32, wid*32+32); 2 calls of 1KB each per operand
    const int srow = lane >> 2, sseg = (lane & 3) * 8;
    const u16* aBase = A  + (size_t)(brow + wid * 32 + srow) * K + sseg;
    const u16* bBase = Bt + (size_t)(bcol + wid * 32 + srow) * K + sseg;
    u16* aD0 = As + (wid * 32) * 32;
    u16* aD1 = As + (wid * 32 + 16) * 32;
    u16* bD0 = Bs + (wid * 32) * 32;
    u16* bD1 = Bs + (wid * 32 + 16) * 32;
    const size_t row16 = (size_t)16 * K;

    for (int kt = 0; kt < K; kt += 32) {
        GLD_LDS16(aBase + kt, aD0);
        GLD_LDS16(aBase + kt + row16, aD1);
        GLD_LDS16(bBase + kt, bD0);
        GLD_LDS16(bBase + kt + row16, bD1);
        __syncthreads();
        bf16x8 af[4], bfr[4];
#pragma unroll
        for (int i = 0; i < 4; ++i)
            af[i] = *reinterpret_cast<const bf16x8*>(&As[(wm * 64 + i * 16 + l15) * 32 + k0]);
#pragma unroll
        for (int j = 0; j < 4; ++j)
            bfr[j] = *reinterpret_cast<const bf16x8*>(&Bs[(wn * 64 + j * 16 + l15) * 32 + k0]);
#pragma unroll
        for (int i = 0; i < 4; ++i)
#pragma unroll
            for (int j = 0; j < 4; ++j)
                acc[i][j] = __builtin_amdgcn_mfma_f32_16x16x32_bf16(af[i], bfr[j], acc[i][j], 0, 0, 0);
        __syncthreads();
    }
    float g = 0.f;
    if (MODE == 1) g = 1.0f / (1.0f + expf(-gate_p[0]));
    const int r0 = (lane >> 4) * 4, c0 = l15;
#pragma unroll
    for (int i = 0; i < 4; ++i) {
#pragma unroll
        for (int j = 0; j < 4; ++j) {
            int col = bcol + wn * 64 + j * 16 + c0;
#pragma unroll
            for (int r = 0; r < 4; ++r) {
                int row = brow + wm * 64 + i * 16 + r0 + r;
                float v = acc[i][j][r];
                if (MODE == 0) Cb[(size_t)row * N + col] = f2bf(v);
                else Cf[(size_t)row * N + col] = resid[(size_t)row * N + col] + g * v;
            }
        }
    }
}

// ---------------- coarse attention (ND=64 keys, exact softmax) ----------------
__global__ __launch_bounds__(256)
void coarse_attn(const u16* __restrict__ q, const u16* __restrict__ kc,
                 const u16* __restrict__ vc, const float* __restrict__ mask,
                 float* __restrict__ doc_part, u16* __restrict__ attn_c) {
    constexpr int SC = 2048 / 64;
    int bid = blockIdx.x;
    int b = bid / (NH * SC);
    int rem = bid % (NH * SC);
    int h = rem / SC, sc = rem % SC;
    int kv = h >> 2;
    int t = threadIdx.x, lane = t & 63, wid = t >> 6;
    const int l15 = lane & 15, k0 = (lane >> 4) * 8;

    __shared__ u16 Kt[64 * 136];
    __shared__ u16 Vt[128 * 72];
    __shared__ u16 Pt[4][16 * 72];
    __shared__ float p_acc[64];

    {   // stage K [64 keys][128 d]
        int n = t >> 2, s2 = t & 3;
        const u16* src = kc + (size_t)(b * 64 + n) * 512 + kv * 128;
#pragma unroll
        for (int u = 0; u < 4; ++u) {
            int sg = s2 + u * 4;
            *reinterpret_cast<uint4*>(&Kt[n * 136 + sg * 8]) =
                *reinterpret_cast<const uint4*>(src + sg * 8);
        }
    }
    {   // stage V transposed: Vt[d][key]
        int n = t & 63, dblk = t >> 6;
        const u16* src = vc + (size_t)(b * 64 + n) * 512 + kv * 128 + dblk * 32;
#pragma unroll
        for (int u = 0; u < 4; ++u) {
            u16 tmp[8];
            *reinterpret_cast<uint4*>(tmp) = *reinterpret_cast<const uint4*>(src + u * 8);
#pragma unroll
            for (int e = 0; e < 8; ++e) Vt[(dblk * 32 + u * 8 + e) * 72 + n] = tmp[e];
        }
    }
    if (t < 64) p_acc[t] = 0.f;
    __syncthreads();

    int qrow = sc * 64 + wid * 16 + l15;
    const u16* qsrc = q + (size_t)(b * 2048 + qrow) * 2048 + h * 128;
    bf16x8 af[4];
#pragma unroll
    for (int kk = 0; kk < 4; ++kk)
        af[kk] = *reinterpret_cast<const bf16x8*>(qsrc + kk * 32 + k0);

    f32x4 sc4[4] = {};
#pragma unroll
    for (int kk = 0; kk < 4; ++kk)
#pragma unroll
        for (int j = 0; j < 4; ++j) {
            bf16x8 bfr = *reinterpret_cast<const bf16x8*>(&Kt[(j * 16 + l15) * 136 + kk * 32 + k0]);
            sc4[j] = __builtin_amdgcn_mfma_f32_16x16x32_bf16(af[kk], bfr, sc4[j], 0, 0, 0);
        }

    float s[4][4];
#pragma unroll
    for (int j = 0; j < 4; ++j) {
        float bia = (1.0f - mask[b * 64 + j * 16 + l15]) * -1e9f;
#pragma unroll
        for (int r = 0; r < 4; ++r) s[j][r] = sc4[j][r] * SCALE + bia;
    }
    float m4[4], l4[4];
#pragma unroll
    for (int r = 0; r < 4; ++r) {
        float m = fmaxf(fmaxf(s[0][r], s[1][r]), fmaxf(s[2][r], s[3][r]));
#pragma unroll
        for (int d = 1; d < 16; d <<= 1) m = fmaxf(m, __shfl_xor(m, d));
        m4[r] = m;
    }
#pragma unroll
    for (int r = 0; r < 4; ++r) {
        float l = 0.f;
#pragma unroll
        for (int j = 0; j < 4; ++j) { s[j][r] = expf(s[j][r] - m4[r]); l += s[j][r]; }
#pragma unroll
        for (int d = 1; d < 16; d <<= 1) l += __shfl_xor(l, d);
        l4[r] = l;
    }
#pragma unroll
    for (int j = 0; j < 4; ++j) {
        float cs = 0.f;
#pragma unroll
        for (int r = 0; r < 4; ++r) {
            float pr = s[j][r] / l4[r];
            Pt[wid][((lane >> 4) * 4 + r) * 72 + j * 16 + l15] = f2bf(pr);
            cs += pr;
        }
        cs += __shfl_xor(cs, 16);
        cs += __shfl_xor(cs, 32);
        if (lane < 16) atomicAdd(&p_acc[j * 16 + lane], cs);
    }
    __syncthreads();

    f32x4 o4[8] = {};
#pragma unroll
    for (int kk2 = 0; kk2 < 2; ++kk2) {
        bf16x8 a2 = *reinterpret_cast<const bf16x8*>(&Pt[wid][l15 * 72 + kk2 * 32 + k0]);
#pragma unroll
        for (int j2 = 0; j2 < 8; ++j2) {
            bf16x8 b2 = *reinterpret_cast<const bf16x8*>(&Vt[(j2 * 16 + l15) * 72 + kk2 * 32 + k0]);
            o4[j2] = __builtin_amdgcn_mfma_f32_16x16x32_bf16(a2, b2, o4[j2], 0, 0, 0);
        }
    }
#pragma unroll
    for (int j2 = 0; j2 < 8; ++j2)
#pragma unroll
        for (int r = 0; r < 4; ++r) {
            int row = sc * 64 + wid * 16 + (lane >> 4) * 4 + r;
            attn_c[(size_t)(b * 2048 + row) * 2048 + h * 128 + j2 * 16 + l15] = f2bf(o4[j2][r]);
        }
    if (t < 64) atomicAdd(&doc_part[(blockIdx.x & 7) * 128 + b * 64 + t], p_acc[t]);
}

// ---------------- doc-score finalize + fine bias ----------------
__global__ void doc_finalize(const float* __restrict__ doc_part, float* __restrict__ log_ds) {
    int t = threadIdx.x; // 128
    float s = 0.f;
#pragma unroll
    for (int i = 0; i < 8; ++i) s += doc_part[i * 128 + t];
    log_ds[t] = logf(s / 32768.0f + 1e-6f);
}

__global__ __launch_bounds__(256)
void bias_kernel(const float* __restrict__ log_ds, const int* __restrict__ map,
                 const float* __restrict__ tmask, float* __restrict__ bias) {
    int i = blockIdx.x * 256 + threadIdx.x;
    if (i >= 2 * 2048) return;
    int b = i >> 11;
    bias[i] = log_ds[b * 64 + map[i]] + (1.0f - tmask[i]) * -1e9f;
}

// ---------------- fine flash attention: KVBLK=64, swapped QK^T, defer-max --------
__global__ __launch_bounds__(256)
void flash_attn(const u16* __restrict__ q, const u16* __restrict__ kf,
                const u16* __restrict__ vf, const float* __restrict__ bias,
                u16* __restrict__ attn_f) {
    int bid = blockIdx.x;
    int b = bid >> 9;              // NH * 32 = 512 blocks per batch
    int rem = bid & 511;
    int h = rem >> 5, sc = rem & 31;
    int kv = h >> 2;
    int t = threadIdx.x, lane = t & 63, wid = t >> 6;
    const int l15 = lane & 15, hi = lane >> 4;
    const int k0 = hi * 8;

    __shared__ u16 Kt[64 * 136];       // [key][d], pad 8
    __shared__ u16 Vt[128 * 72];       // [d][key], pad 8
    __shared__ u16 Pt[4][16 * 72];     // per-wave P[q][key], pad 8
    __shared__ float bias_s[64];

    int qrow = sc * 64 + wid * 16 + l15;
    const u16* qsrc = q + (size_t)(b * 2048 + qrow) * 2048 + h * 128;
    bf16x8 qf4[4];
#pragma unroll
    for (int kk = 0; kk < 4; ++kk)
        qf4[kk] = *reinterpret_cast<const bf16x8*>(qsrc + kk * 32 + k0);

    float mstate = -1e30f, lstate = 0.f;
    f32x4 o4[8] = {};

    for (int t0 = 0; t0 < 2048; t0 += 64) {
        {   // stage K [64][128]
            int n = t >> 2, s4 = t & 3;
            const u16* src = kf + (size_t)(b * 2048 + t0 + n) * 512 + kv * 128;
#pragma unroll
            for (int u = 0; u < 4; ++u) {
                int e = (s4 + u * 4) * 8;
                *reinterpret_cast<uint4*>(&Kt[n * 136 + e]) =
                    *reinterpret_cast<const uint4*>(src + e);
            }
        }
        {   // stage V transposed: Vt[d][key]
            int n = t & 63, dblk = t >> 6;
            const u16* src = vf + (size_t)(b * 2048 + t0 + n) * 512 + kv * 128 + dblk * 32;
#pragma unroll
            for (int u = 0; u < 4; ++u) {
                u16 tmp[8];
                *reinterpret_cast<uint4*>(tmp) = *reinterpret_cast<const uint4*>(src + u * 8);
#pragma unroll
                for (int e = 0; e < 8; ++e) Vt[(dblk * 32 + u * 8 + e) * 72 + n] = tmp[e];
            }
        }
        if (t < 64) bias_s[t] = bias[b * 2048 + t0 + t];
        __syncthreads();

        // QK^T swapped: S^T[key][q] = K-frag (A) x Q-frag (B)
        f32x4 st[4] = {};
#pragma unroll
        for (int kk = 0; kk < 4; ++kk)
#pragma unroll
            for (int kb = 0; kb < 4; ++kb) {
                bf16x8 kfrag = *reinterpret_cast<const bf16x8*>(&Kt[(kb * 16 + l15) * 136 + kk * 32 + k0]);
                st[kb] = __builtin_amdgcn_mfma_f32_16x16x32_bf16(kfrag, qf4[kk], st[kb], 0, 0, 0);
            }

        // per-lane: q = l15, keys = kb*16 + hi*4 + r
        float p[4][4];
        float pmax = -1e30f;
#pragma unroll
        for (int kb = 0; kb < 4; ++kb) {
            float4 b4 = *reinterpret_cast<const float4*>(&bias_s[kb * 16 + hi * 4]);
            float bb[4] = {b4.x, b4.y, b4.z, b4.w};
#pragma unroll
            for (int r = 0; r < 4; ++r) {
                float v = st[kb][r] * SCALE + bb[r];
                p[kb][r] = v;
                pmax = fmaxf(pmax, v);
            }
        }
        pmax = fmaxf(pmax, __shfl_xor(pmax, 16));
        pmax = fmaxf(pmax, __shfl_xor(pmax, 32));

        // defer-max (T13): only rescale when the tile max grew past THR=8
        if (!__all(pmax <= mstate + 8.0f)) {
            float mnew = fmaxf(mstate, pmax);
            float sco = expf(mstate - mnew);
            float sco_out[4];
#pragma unroll
            for (int r = 0; r < 4; ++r) sco_out[r] = __shfl(sco, hi * 4 + r);
#pragma unroll
            for (int j2 = 0; j2 < 8; ++j2)
#pragma unroll
                for (int r = 0; r < 4; ++r) o4[j2][r] *= sco_out[r];
            lstate *= sco;
            mstate = mnew;
        }

        float lt = 0.f;
#pragma unroll
        for (int kb = 0; kb < 4; ++kb)
#pragma unroll
            for (int r = 0; r < 4; ++r) {
                p[kb][r] = expf(p[kb][r] - mstate);
                lt += p[kb][r];
            }
        lt += __shfl_xor(lt, 16);
        lt += __shfl_xor(lt, 32);
        lstate += lt;

        // write P[q][key] (per-wave buffer, no barrier needed: same-wave DS order)
#pragma unroll
        for (int kb = 0; kb < 4; ++kb) {
            uint2 w;
            w.x = pack2(p[kb][0], p[kb][1]);
            w.y = pack2(p[kb][2], p[kb][3]);
            *reinterpret_cast<uint2*>(&Pt[wid][l15 * 72 + kb * 16 + hi * 4]) = w;
        }

        // PV: O[q][d] += P (A) x V-frag (B)
#pragma unroll
        for (int kc = 0; kc < 2; ++kc) {
            bf16x8 pa = *reinterpret_cast<const bf16x8*>(&Pt[wid][l15 * 72 + kc * 32 + k0]);
#pragma unroll
            for (int j2 = 0; j2 < 8; ++j2) {
                bf16x8 vb = *reinterpret_cast<const bf16x8*>(&Vt[(j2 * 16 + l15) * 72 + kc * 32 + k0]);
                o4[j2] = __builtin_amdgcn_mfma_f32_16x16x32_bf16(pa, vb, o4[j2], 0, 0, 0);
            }
        }
        __syncthreads();
    }

    // l is in softmax layout (q = l15); outputs need q = hi*4+r
    float linv[4];
#pragma unroll
    for (int r = 0; r < 4; ++r) linv[r] = 1.0f / __shfl(lstate, hi * 4 + r);
#pragma unroll
    for (int j2 = 0; j2 < 8; ++j2)
#pragma unroll
        for (int r = 0; r < 4; ++r) {
            int row = sc * 64 + wid * 16 + hi * 4 + r;
            attn_f[(size_t)(b * 2048 + row) * 2048 + h * 128 + j2 * 16 + l15] =
                f2bf(o4[j2][r] * linv[r]);
        }
}

// ---------------- launch ----------------
extern "C" void kernel_launch(void* const* d_in, const int* in_sizes, int n_in,
                              void* d_out, int out_size, void* d_ws, size_t ws_size,
                              hipStream_t stream) {
    const float* hidden = (const float*)d_in[0];
    const float* dsk    = (const float*)d_in[1];
    const float* dsv    = (const float*)d_in[2];
    const float* dsmask = (const float*)d_in[3];
    const float* tk     = (const float*)d_in[4];
    const float* tv     = (const float*)d_in[5];
    const float* tmask  = (const float*)d_in[6];
    const float* cn_w   = (const float*)d_in[7];
    const float* cq_w   = (const float*)d_in[8];
    const float* ck_w   = (const float*)d_in[9];
    const float* cv_w   = (const float*)d_in[10];
    const float* co_w   = (const float*)d_in[11];
    const float* c_gate = (const float*)d_in[12];
    const float* fn_w   = (const float*)d_in[13];
    const float* fq_w   = (const float*)d_in[14];
    const float* fk_w   = (const float*)d_in[15];
    const float* fv_w   = (const float*)d_in[16];
    const float* fo_w   = (const float*)d_in[17];
    const float* f_gate = (const float*)d_in[18];
    const int*   map    = (const int*)d_in[19];
    float* out_f = (float*)d_out;   // also used as the f32 buffer for coarse residual

    char* ws = (char*)d_ws;
    size_t off = 0;
    auto alloc = [&](size_t bytes) {
        char* p = ws + off;
        off += (bytes + 255) & ~(size_t)255;
        return p;
    };
    u16*  normA = (u16*)alloc(4096ULL * 2048 * 2);
    u16*  qbuf  = (u16*)alloc(4096ULL * 2048 * 2);
    u16*  kc    = (u16*)alloc(128ULL * 512 * 2);
    u16*  vc    = (u16*)alloc(128ULL * 512 * 2);
    u16*  dskb  = (u16*)alloc(128ULL * 2048 * 2);
    u16*  dsvb  = (u16*)alloc(128ULL * 2048 * 2);
    u16*  kfb   = (u16*)alloc(4096ULL * 512 * 2);
    u16*  vfb   = (u16*)alloc(4096ULL * 512 * 2);
    u16*  cqT   = (u16*)alloc(2048ULL * 2048 * 2);
    u16*  ckT   = (u16*)alloc(512ULL * 2048 * 2);
    u16*  cvT   = (u16*)alloc(512ULL * 2048 * 2);
    u16*  coT   = (u16*)alloc(2048ULL * 2048 * 2);
    u16*  fqT   = (u16*)alloc(2048ULL * 2048 * 2);
    u16*  fkT   = (u16*)alloc(512ULL * 2048 * 2);
    u16*  fvT   = (u16*)alloc(512ULL * 2048 * 2);
    u16*  foT   = (u16*)alloc(2048ULL * 2048 * 2);
    float* doc_part = (float*)alloc(8 * 128 * 4);
    float* log_ds   = (float*)alloc(128 * 4);
    float* biasb    = (float*)alloc(4096 * 4);

    hipMemsetAsync(doc_part, 0, 8 * 128 * 4, stream);

    // weight transposes (f32 [K=2048][N] -> bf16 [N][2048])
    transpose_cvt<<<dim3(64, 64), 256, 0, stream>>>(cq_w, cqT, 2048, 2048);
    transpose_cvt<<<dim3(16, 64), 256, 0, stream>>>(ck_w, ckT, 2048, 512);
    transpose_cvt<<<dim3(16, 64), 256, 0, stream>>>(cv_w, cvT, 2048, 512);
    transpose_cvt<<<dim3(64, 64), 256, 0, stream>>>(co_w, coT, 2048, 2048);
    transpose_cvt<<<dim3(64, 64), 256, 0, stream>>>(fq_w, fqT, 2048, 2048);
    transpose_cvt<<<dim3(16, 64), 256, 0, stream>>>(fk_w, fkT, 2048, 512);
    transpose_cvt<<<dim3(16, 64), 256, 0, stream>>>(fv_w, fvT, 2048, 512);
    transpose_cvt<<<dim3(64, 64), 256, 0, stream>>>(fo_w, foT, 2048, 2048);

    cvt_f32_bf16<<<(128 * 2048 / 4 + 255) / 256, 256, 0, stream>>>(dsk, dskb, 128 * 2048 / 4);
    cvt_f32_bf16<<<(128 * 2048 / 4 + 255) / 256, 256, 0, stream>>>(dsv, dsvb, 128 * 2048 / 4);
    rmsnorm_kernel<<<4096, 256, 0, stream>>>(hidden, cn_w, normA);

    // coarse projections
    gemm_tn<0><<<dim3(16, 32), 256, 0, stream>>>(normA, cqT, qbuf, nullptr, nullptr, nullptr, 4096, 2048, 2048);
    gemm_tn<0><<<dim3(4, 1), 256, 0, stream>>>(dskb, ckT, kc, nullptr, nullptr, nullptr, 128, 512, 2048);
    gemm_tn<0><<<dim3(4, 1), 256, 0, stream>>>(dsvb, cvT, vc, nullptr, nullptr, nullptr, 128, 512, 2048);

    // coarse attention (attn_c into normA) + doc-score partials
    coarse_attn<<<1024, 256, 0, stream>>>(qbuf, kc, vc, dsmask, doc_part, normA);
    doc_finalize<<<1, 128, 0, stream>>>(doc_part, log_ds);
    bias_kernel<<<16, 256, 0, stream>>>(log_ds, map, tmask, biasb);

    // coarse o-proj + residual + gate -> d_out (f32)
    gemm_tn<1><<<dim3(16, 32), 256, 0, stream>>>(normA, coT, nullptr, out_f, hidden, c_gate, 4096, 2048, 2048);

    // fine stage
    rmsnorm_kernel<<<4096, 256, 0, stream>>>(out_f, fn_w, qbuf);
    gemm_tn<0><<<dim3(16, 32), 256, 0, stream>>>(qbuf, fqT, normA, nullptr, nullptr, nullptr, 4096, 2048, 2048);
    cvt_f32_bf16<<<(4096 * 2048 / 4 + 255) / 256, 256, 0, stream>>>(tk, qbuf, 4096 * 2048 / 4);
    gemm_tn<0><<<dim3(4, 32), 256, 0, stream>>>(qbuf, fkT, kfb, nullptr, nullptr, nullptr, 4096, 512, 2048);
    cvt_f32_bf16<<<(4096 * 2048 / 4 + 255) / 256, 256, 0, stream>>>(tv, qbuf, 4096 * 2048 / 4);
    gemm_tn<0><<<dim3(4, 32), 256, 0, stream>>>(qbuf, fvT, vfb, nullptr, nullptr, nullptr, 4096, 512, 2048);

    flash_attn<<<1024, 256, 0, stream>>>(normA, kfb, vfb, biasb, qbuf);

    // final o-proj + residual + gate -> d_out (in-place residual read is per-element safe)
    gemm_tn<1><<<dim3(16, 32), 256, 0, stream>>>(qbuf, foT, nullptr, out_f, out_f, f_gate, 4096, 2048, 2048);
}

// Round 4
// 661.573 us; speedup vs baseline: 1.5603x; 1.0569x over previous
//
#include <hip/hip_runtime.h>

typedef unsigned short u16;
typedef unsigned int u32;
typedef __attribute__((ext_vector_type(8))) short bf16x8;
typedef __attribute__((ext_vector_type(4))) float f32x4;

constexpr int NH = 16;
constexpr int H = 2048;
constexpr float SCALE = 0.08838834764831845f; // 1/sqrt(128)

__device__ __forceinline__ u16 f2bf(float f) {
    u32 u = __float_as_uint(f);
    u32 r = u + 0x7fffu + ((u >> 16) & 1u);   // RNE (finite inputs only)
    return (u16)(r >> 16);
}
__device__ __forceinline__ u32 pack2(float x, float y) {
    return (u32)f2bf(x) | ((u32)f2bf(y) << 16);
}

#define GLD_LDS16(gsrc, ldst)                                                  \
    __builtin_amdgcn_global_load_lds(                                          \
        (const __attribute__((address_space(1))) void*)(gsrc),                 \
        (__attribute__((address_space(3))) void*)(ldst), 16, 0, 0)

// ---------------- f32 -> bf16 convert (vectorized) ----------------
__global__ __launch_bounds__(256) void cvt_f32_bf16(const float* __restrict__ in,
                                                    u16* __restrict__ out, int n4) {
    int i = blockIdx.x * 256 + threadIdx.x;
    if (i >= n4) return;
    float4 v = reinterpret_cast<const float4*>(in)[i];
    uint2 o;
    o.x = pack2(v.x, v.y);
    o.y = pack2(v.z, v.w);
    reinterpret_cast<uint2*>(out)[i] = o;
}

// ---------------- weight transpose + convert: f32[K][N] -> bf16[N][K] ----------------
__global__ __launch_bounds__(256)
void transpose_cvt(const float* __restrict__ in, u16* __restrict__ out, int K, int N) {
    __shared__ u16 tile[32][33];
    int bn = blockIdx.x * 32, bk = blockIdx.y * 32;
    int tx = threadIdx.x & 31, ty = threadIdx.x >> 5;  // ty 0..7
#pragma unroll
    for (int r = 0; r < 32; r += 8)
        tile[tx][r + ty] = f2bf(in[(size_t)(bk + r + ty) * N + bn + tx]);
    __syncthreads();
#pragma unroll
    for (int r = 0; r < 32; r += 8)
        out[(size_t)(bn + r + ty) * K + bk + tx] = tile[r + ty][tx];
}

// ---------------- RMSNorm f32 -> bf16, H=2048, one block per row ----------------
__global__ __launch_bounds__(256) void rmsnorm_kernel(const float* __restrict__ x,
                                                      const float* __restrict__ w,
                                                      u16* __restrict__ y) {
    int r = blockIdx.x;
    const float4* xr = reinterpret_cast<const float4*>(x + (size_t)r * H);
    int t = threadIdx.x;
    float4 v0 = xr[t * 2], v1 = xr[t * 2 + 1];
    float ss = v0.x * v0.x + v0.y * v0.y + v0.z * v0.z + v0.w * v0.w
             + v1.x * v1.x + v1.y * v1.y + v1.z * v1.z + v1.w * v1.w;
#pragma unroll
    for (int d = 1; d < 64; d <<= 1) ss += __shfl_xor(ss, d);
    __shared__ float red[4];
    if ((t & 63) == 0) red[t >> 6] = ss;
    __syncthreads();
    float tot = red[0] + red[1] + red[2] + red[3];
    float rs = rsqrtf(tot * (1.0f / H) + 1e-6f);
    const float4* wr = reinterpret_cast<const float4*>(w);
    float4 w0 = wr[t * 2], w1 = wr[t * 2 + 1];
    uint4 o;
    o.x = pack2(v0.x * rs * w0.x, v0.y * rs * w0.y);
    o.y = pack2(v0.z * rs * w0.z, v0.w * rs * w0.w);
    o.z = pack2(v1.x * rs * w1.x, v1.y * rs * w1.y);
    o.w = pack2(v1.z * rs * w1.z, v1.w * rs * w1.w);
    reinterpret_cast<uint4*>(y + (size_t)r * H)[t] = o;
}

// ---------------- GEMM (m97 structure): C[M,N] = A_bf16[M,K] @ Bt_bf16[N,K]^T --------
// MODE 0: store bf16 C.  MODE 1: Cf = resid + sigmoid(*gate_p) * acc (f32 out).
template <int MODE>
__global__ __launch_bounds__(256)
void gemm_tn(const u16* __restrict__ A, const u16* __restrict__ Bt,
             u16* __restrict__ Cb, float* __restrict__ Cf,
             const float* __restrict__ resid, const float* __restrict__ gate_p,
             int M, int N, int K) {
    __shared__ u16 As[128 * 32];
    __shared__ u16 Bs[128 * 32];
    const int t = threadIdx.x;
    const int lane = t & 63, wid = t >> 6;
    const int wm = wid >> 1, wn = wid & 1;
    const int brow = blockIdx.y * 128, bcol = blockIdx.x * 128;
    const int l15 = lane & 15;
    const int k0 = (lane >> 4) * 8;

    f32x4 acc[4][4] = {};
    const int srow = lane >> 2, sseg = (lane & 3) * 8;
    const u16* aBase = A  + (size_t)(brow + wid * 32 + srow) * K + sseg;
    const u16* bBase = Bt + (size_t)(bcol + wid * 32 + srow) * K + sseg;
    u16* aD0 = As + (wid * 32) * 32;
    u16* aD1 = As + (wid * 32 + 16) * 32;
    u16* bD0 = Bs + (wid * 32) * 32;
    u16* bD1 = Bs + (wid * 32 + 16) * 32;
    const size_t row16 = (size_t)16 * K;

    for (int kt = 0; kt < K; kt += 32) {
        GLD_LDS16(aBase + kt, aD0);
        GLD_LDS16(aBase + kt + row16, aD1);
        GLD_LDS16(bBase + kt, bD0);
        GLD_LDS16(bBase + kt + row16, bD1);
        __syncthreads();
        bf16x8 af[4], bfr[4];
#pragma unroll
        for (int i = 0; i < 4; ++i)
            af[i] = *reinterpret_cast<const bf16x8*>(&As[(wm * 64 + i * 16 + l15) * 32 + k0]);
#pragma unroll
        for (int j = 0; j < 4; ++j)
            bfr[j] = *reinterpret_cast<const bf16x8*>(&Bs[(wn * 64 + j * 16 + l15) * 32 + k0]);
#pragma unroll
        for (int i = 0; i < 4; ++i)
#pragma unroll
            for (int j = 0; j < 4; ++j)
                acc[i][j] = __builtin_amdgcn_mfma_f32_16x16x32_bf16(af[i], bfr[j], acc[i][j], 0, 0, 0);
        __syncthreads();
    }
    float g = 0.f;
    if (MODE == 1) g = 1.0f / (1.0f + expf(-gate_p[0]));
    const int r0 = (lane >> 4) * 4, c0 = l15;
#pragma unroll
    for (int i = 0; i < 4; ++i) {
#pragma unroll
        for (int j = 0; j < 4; ++j) {
            int col = bcol + wn * 64 + j * 16 + c0;
#pragma unroll
            for (int r = 0; r < 4; ++r) {
                int row = brow + wm * 64 + i * 16 + r0 + r;
                float v = acc[i][j][r];
                if (MODE == 0) Cb[(size_t)row * N + col] = f2bf(v);
                else Cf[(size_t)row * N + col] = resid[(size_t)row * N + col] + g * v;
            }
        }
    }
}

// ---------------- coarse attention (ND=64 keys, exact softmax) ----------------
__global__ __launch_bounds__(256)
void coarse_attn(const u16* __restrict__ q, const u16* __restrict__ kc,
                 const u16* __restrict__ vc, const float* __restrict__ mask,
                 float* __restrict__ doc_part, u16* __restrict__ attn_c) {
    constexpr int SC = 2048 / 64;
    int bid = blockIdx.x;
    int b = bid / (NH * SC);
    int rem = bid % (NH * SC);
    int h = rem / SC, sc = rem % SC;
    int kv = h >> 2;
    int t = threadIdx.x, lane = t & 63, wid = t >> 6;
    const int l15 = lane & 15, k0 = (lane >> 4) * 8;

    __shared__ u16 Kt[64 * 136];
    __shared__ u16 Vt[128 * 72];
    __shared__ u16 Pt[4][16 * 72];
    __shared__ float p_acc[64];

    {   // stage K [64 keys][128 d]
        int n = t >> 2, s2 = t & 3;
        const u16* src = kc + (size_t)(b * 64 + n) * 512 + kv * 128;
#pragma unroll
        for (int u = 0; u < 4; ++u) {
            int sg = s2 + u * 4;
            *reinterpret_cast<uint4*>(&Kt[n * 136 + sg * 8]) =
                *reinterpret_cast<const uint4*>(src + sg * 8);
        }
    }
    {   // stage V transposed: Vt[d][key]
        int n = t & 63, dblk = t >> 6;
        const u16* src = vc + (size_t)(b * 64 + n) * 512 + kv * 128 + dblk * 32;
#pragma unroll
        for (int u = 0; u < 4; ++u) {
            u16 tmp[8];
            *reinterpret_cast<uint4*>(tmp) = *reinterpret_cast<const uint4*>(src + u * 8);
#pragma unroll
            for (int e = 0; e < 8; ++e) Vt[(dblk * 32 + u * 8 + e) * 72 + n] = tmp[e];
        }
    }
    if (t < 64) p_acc[t] = 0.f;
    __syncthreads();

    int qrow = sc * 64 + wid * 16 + l15;
    const u16* qsrc = q + (size_t)(b * 2048 + qrow) * 2048 + h * 128;
    bf16x8 af[4];
#pragma unroll
    for (int kk = 0; kk < 4; ++kk)
        af[kk] = *reinterpret_cast<const bf16x8*>(qsrc + kk * 32 + k0);

    f32x4 sc4[4] = {};
#pragma unroll
    for (int kk = 0; kk < 4; ++kk)
#pragma unroll
        for (int j = 0; j < 4; ++j) {
            bf16x8 bfr = *reinterpret_cast<const bf16x8*>(&Kt[(j * 16 + l15) * 136 + kk * 32 + k0]);
            sc4[j] = __builtin_amdgcn_mfma_f32_16x16x32_bf16(af[kk], bfr, sc4[j], 0, 0, 0);
        }

    float s[4][4];
#pragma unroll
    for (int j = 0; j < 4; ++j) {
        float bia = (1.0f - mask[b * 64 + j * 16 + l15]) * -1e9f;
#pragma unroll
        for (int r = 0; r < 4; ++r) s[j][r] = sc4[j][r] * SCALE + bia;
    }
    float m4[4], l4[4];
#pragma unroll
    for (int r = 0; r < 4; ++r) {
        float m = fmaxf(fmaxf(s[0][r], s[1][r]), fmaxf(s[2][r], s[3][r]));
#pragma unroll
        for (int d = 1; d < 16; d <<= 1) m = fmaxf(m, __shfl_xor(m, d));
        m4[r] = m;
    }
#pragma unroll
    for (int r = 0; r < 4; ++r) {
        float l = 0.f;
#pragma unroll
        for (int j = 0; j < 4; ++j) { s[j][r] = expf(s[j][r] - m4[r]); l += s[j][r]; }
#pragma unroll
        for (int d = 1; d < 16; d <<= 1) l += __shfl_xor(l, d);
        l4[r] = l;
    }
#pragma unroll
    for (int j = 0; j < 4; ++j) {
        float cs = 0.f;
#pragma unroll
        for (int r = 0; r < 4; ++r) {
            float pr = s[j][r] / l4[r];
            Pt[wid][((lane >> 4) * 4 + r) * 72 + j * 16 + l15] = f2bf(pr);
            cs += pr;
        }
        cs += __shfl_xor(cs, 16);
        cs += __shfl_xor(cs, 32);
        if (lane < 16) atomicAdd(&p_acc[j * 16 + lane], cs);
    }
    __syncthreads();

    f32x4 o4[8] = {};
#pragma unroll
    for (int kk2 = 0; kk2 < 2; ++kk2) {
        bf16x8 a2 = *reinterpret_cast<const bf16x8*>(&Pt[wid][l15 * 72 + kk2 * 32 + k0]);
#pragma unroll
        for (int j2 = 0; j2 < 8; ++j2) {
            bf16x8 b2 = *reinterpret_cast<const bf16x8*>(&Vt[(j2 * 16 + l15) * 72 + kk2 * 32 + k0]);
            o4[j2] = __builtin_amdgcn_mfma_f32_16x16x32_bf16(a2, b2, o4[j2], 0, 0, 0);
        }
    }
#pragma unroll
    for (int j2 = 0; j2 < 8; ++j2)
#pragma unroll
        for (int r = 0; r < 4; ++r) {
            int row = sc * 64 + wid * 16 + (lane >> 4) * 4 + r;
            attn_c[(size_t)(b * 2048 + row) * 2048 + h * 128 + j2 * 16 + l15] = f2bf(o4[j2][r]);
        }
    if (t < 64) atomicAdd(&doc_part[(blockIdx.x & 7) * 128 + b * 64 + t], p_acc[t]);
}

// ---------------- doc-score finalize + fine bias ----------------
__global__ void doc_finalize(const float* __restrict__ doc_part, float* __restrict__ log_ds) {
    int t = threadIdx.x; // 128
    float s = 0.f;
#pragma unroll
    for (int i = 0; i < 8; ++i) s += doc_part[i * 128 + t];
    log_ds[t] = logf(s / 32768.0f + 1e-6f);
}

__global__ __launch_bounds__(256)
void bias_kernel(const float* __restrict__ log_ds, const int* __restrict__ map,
                 const float* __restrict__ tmask, float* __restrict__ bias) {
    int i = blockIdx.x * 256 + threadIdx.x;
    if (i >= 2 * 2048) return;
    int b = i >> 11;
    bias[i] = log_ds[b * 64 + map[i]] + (1.0f - tmask[i]) * -1e9f;
}

// ---------------- fine flash attention v2 ----------------
// KVBLK=64, swapped QK^T, defer-max; K and pre-transposed V staged via
// global_load_lds into linear LDS with XOR-swizzled (slot ^ row&7) source,
// reads apply the same swizzle -> conflict-free (T2 / m173 pattern).
__global__ __launch_bounds__(256)
void flash_attn(const u16* __restrict__ q, const u16* __restrict__ kf,
                const u16* __restrict__ vT, const float* __restrict__ bias,
                u16* __restrict__ attn_f) {
    int bid = blockIdx.x;
    int b = bid >> 9;              // NH * 32 = 512 blocks per batch
    int rem = bid & 511;
    int h = rem >> 5, sc = rem & 31;
    int kv = h >> 2;
    int t = threadIdx.x, lane = t & 63, wid = t >> 6;
    const int l15 = lane & 15, hi = lane >> 4;
    const int k0 = hi * 8;

    __shared__ u16 Kt[64 * 128];       // [key][d] linear, swizzled 16B slots
    __shared__ u16 Vt[128 * 64];       // [d][key] linear, swizzled 16B slots
    __shared__ u16 Pt[4][16 * 72];     // per-wave P[q][key], pad 8
    __shared__ float bias_s[64];

    int qrow = sc * 64 + wid * 16 + l15;
    const u16* qsrc = q + (size_t)(b * 2048 + qrow) * 2048 + h * 128;
    bf16x8 qf4[4];
#pragma unroll
    for (int kk = 0; kk < 4; ++kk)
        qf4[kk] = *reinterpret_cast<const bf16x8*>(qsrc + kk * 32 + k0);

    // staging lane roles (constant over tiles)
    const int krl = lane >> 4, kslot = lane & 15;   // K: 4 rows x 16 slots per 1KB
    const int vrl = lane >> 3, vslot = lane & 7;    // V: 8 rows x 8 slots per 1KB
    const u16* kbase = kf + (size_t)(b * 2048) * 512 + kv * 128;
    const u16* vbase = vT + (size_t)(kv * 128) * 4096 + b * 2048;

    float mstate = -1e30f, lstate = 0.f;
    f32x4 o4[8] = {};

    for (int t0 = 0; t0 < 2048; t0 += 64) {
        // stage K: wave wid covers keys [wid*16, wid*16+16)
#pragma unroll
        for (int u = 0; u < 4; ++u) {
            int row = wid * 16 + u * 4 + krl;
            const u16* src = kbase + (size_t)(t0 + row) * 512 + ((kslot ^ (row & 7)) * 8);
            GLD_LDS16(src, &Kt[(wid * 16 + u * 4) * 128]);
        }
        // stage V^T: wave wid covers d in [wid*32, wid*32+32)
#pragma unroll
        for (int u = 0; u < 4; ++u) {
            int row = wid * 32 + u * 8 + vrl;
            const u16* src = vbase + (size_t)row * 4096 + t0 + ((vslot ^ (row & 7)) * 8);
            GLD_LDS16(src, &Vt[(wid * 32 + u * 8) * 64]);
        }
        if (t < 64) bias_s[t] = bias[b * 2048 + t0 + t];
        __syncthreads();

        // QK^T swapped: S^T[key][q] = K-frag (A) x Q-frag (B)
        f32x4 st[4] = {};
#pragma unroll
        for (int kk = 0; kk < 4; ++kk)
#pragma unroll
            for (int kb = 0; kb < 4; ++kb) {
                int row = kb * 16 + l15;
                bf16x8 kfrag = *reinterpret_cast<const bf16x8*>(
                    &Kt[row * 128 + (((kk * 4 + hi) ^ (row & 7)) * 8)]);
                st[kb] = __builtin_amdgcn_mfma_f32_16x16x32_bf16(kfrag, qf4[kk], st[kb], 0, 0, 0);
            }

        // per-lane: q = l15, keys = kb*16 + hi*4 + r
        float p[4][4];
        float pmax = -1e30f;
#pragma unroll
        for (int kb = 0; kb < 4; ++kb) {
            float4 b4 = *reinterpret_cast<const float4*>(&bias_s[kb * 16 + hi * 4]);
            float bb[4] = {b4.x, b4.y, b4.z, b4.w};
#pragma unroll
            for (int r = 0; r < 4; ++r) {
                float v = st[kb][r] * SCALE + bb[r];
                p[kb][r] = v;
                pmax = fmaxf(pmax, v);
            }
        }
        pmax = fmaxf(pmax, __shfl_xor(pmax, 16));
        pmax = fmaxf(pmax, __shfl_xor(pmax, 32));

        // defer-max (T13): only rescale when the tile max grew past THR=8
        if (!__all(pmax <= mstate + 8.0f)) {
            float mnew = fmaxf(mstate, pmax);
            float sco = expf(mstate - mnew);
            float sco_out[4];
#pragma unroll
            for (int r = 0; r < 4; ++r) sco_out[r] = __shfl(sco, hi * 4 + r);
#pragma unroll
            for (int j2 = 0; j2 < 8; ++j2)
#pragma unroll
                for (int r = 0; r < 4; ++r) o4[j2][r] *= sco_out[r];
            lstate *= sco;
            mstate = mnew;
        }

        float lt = 0.f;
#pragma unroll
        for (int kb = 0; kb < 4; ++kb)
#pragma unroll
            for (int r = 0; r < 4; ++r) {
                p[kb][r] = expf(p[kb][r] - mstate);
                lt += p[kb][r];
            }
        lt += __shfl_xor(lt, 16);
        lt += __shfl_xor(lt, 32);
        lstate += lt;

        // write P[q][key] (per-wave buffer; same-wave DS ordering)
#pragma unroll
        for (int kb = 0; kb < 4; ++kb) {
            uint2 w;
            w.x = pack2(p[kb][0], p[kb][1]);
            w.y = pack2(p[kb][2], p[kb][3]);
            *reinterpret_cast<uint2*>(&Pt[wid][l15 * 72 + kb * 16 + hi * 4]) = w;
        }

        // PV: O[q][d] += P (A) x V^T-frag (B)
#pragma unroll
        for (int kc = 0; kc < 2; ++kc) {
            bf16x8 pa = *reinterpret_cast<const bf16x8*>(&Pt[wid][l15 * 72 + kc * 32 + k0]);
#pragma unroll
            for (int j2 = 0; j2 < 8; ++j2) {
                int d = j2 * 16 + l15;
                bf16x8 vb = *reinterpret_cast<const bf16x8*>(
                    &Vt[d * 64 + (((kc * 4 + hi) ^ (d & 7)) * 8)]);
                o4[j2] = __builtin_amdgcn_mfma_f32_16x16x32_bf16(pa, vb, o4[j2], 0, 0, 0);
            }
        }
        __syncthreads();
    }

    // l is in softmax layout (q = l15); outputs need q = hi*4+r
    float linv[4];
#pragma unroll
    for (int r = 0; r < 4; ++r) linv[r] = 1.0f / __shfl(lstate, hi * 4 + r);
#pragma unroll
    for (int j2 = 0; j2 < 8; ++j2)
#pragma unroll
        for (int r = 0; r < 4; ++r) {
            int row = sc * 64 + wid * 16 + hi * 4 + r;
            attn_f[(size_t)(b * 2048 + row) * 2048 + h * 128 + j2 * 16 + l15] =
                f2bf(o4[j2][r] * linv[r]);
        }
}

// ---------------- launch ----------------
extern "C" void kernel_launch(void* const* d_in, const int* in_sizes, int n_in,
                              void* d_out, int out_size, void* d_ws, size_t ws_size,
                              hipStream_t stream) {
    const float* hidden = (const float*)d_in[0];
    const float* dsk    = (const float*)d_in[1];
    const float* dsv    = (const float*)d_in[2];
    const float* dsmask = (const float*)d_in[3];
    const float* tk     = (const float*)d_in[4];
    const float* tv     = (const float*)d_in[5];
    const float* tmask  = (const float*)d_in[6];
    const float* cn_w   = (const float*)d_in[7];
    const float* cq_w   = (const float*)d_in[8];
    const float* ck_w   = (const float*)d_in[9];
    const float* cv_w   = (const float*)d_in[10];
    const float* co_w   = (const float*)d_in[11];
    const float* c_gate = (const float*)d_in[12];
    const float* fn_w   = (const float*)d_in[13];
    const float* fq_w   = (const float*)d_in[14];
    const float* fk_w   = (const float*)d_in[15];
    const float* fv_w   = (const float*)d_in[16];
    const float* fo_w   = (const float*)d_in[17];
    const float* f_gate = (const float*)d_in[18];
    const int*   map    = (const int*)d_in[19];
    float* out_f = (float*)d_out;   // also the f32 buffer for coarse residual

    char* ws = (char*)d_ws;
    size_t off = 0;
    auto alloc = [&](size_t bytes) {
        char* p = ws + off;
        off += (bytes + 255) & ~(size_t)255;
        return p;
    };
    u16*  normA = (u16*)alloc(4096ULL * 2048 * 2);
    u16*  qbuf  = (u16*)alloc(4096ULL * 2048 * 2);
    u16*  kc    = (u16*)alloc(128ULL * 512 * 2);
    u16*  vc    = (u16*)alloc(128ULL * 512 * 2);
    u16*  dskb  = (u16*)alloc(128ULL * 2048 * 2);
    u16*  dsvb  = (u16*)alloc(128ULL * 2048 * 2);
    u16*  kfb   = (u16*)alloc(4096ULL * 512 * 2);
    u16*  vTb   = (u16*)alloc(512ULL * 4096 * 2);   // V^T [kv*128+d][b*2048+t]
    u16*  cqT   = (u16*)alloc(2048ULL * 2048 * 2);
    u16*  ckT   = (u16*)alloc(512ULL * 2048 * 2);
    u16*  cvT   = (u16*)alloc(512ULL * 2048 * 2);
    u16*  coT   = (u16*)alloc(2048ULL * 2048 * 2);
    u16*  fqT   = (u16*)alloc(2048ULL * 2048 * 2);
    u16*  fkT   = (u16*)alloc(512ULL * 2048 * 2);
    u16*  fvT   = (u16*)alloc(512ULL * 2048 * 2);
    u16*  foT   = (u16*)alloc(2048ULL * 2048 * 2);
    float* doc_part = (float*)alloc(8 * 128 * 4);
    float* log_ds   = (float*)alloc(128 * 4);
    float* biasb    = (float*)alloc(4096 * 4);

    hipMemsetAsync(doc_part, 0, 8 * 128 * 4, stream);

    // weight transposes (f32 [K=2048][N] -> bf16 [N][2048])
    transpose_cvt<<<dim3(64, 64), 256, 0, stream>>>(cq_w, cqT, 2048, 2048);
    transpose_cvt<<<dim3(16, 64), 256, 0, stream>>>(ck_w, ckT, 2048, 512);
    transpose_cvt<<<dim3(16, 64), 256, 0, stream>>>(cv_w, cvT, 2048, 512);
    transpose_cvt<<<dim3(64, 64), 256, 0, stream>>>(co_w, coT, 2048, 2048);
    transpose_cvt<<<dim3(64, 64), 256, 0, stream>>>(fq_w, fqT, 2048, 2048);
    transpose_cvt<<<dim3(16, 64), 256, 0, stream>>>(fk_w, fkT, 2048, 512);
    transpose_cvt<<<dim3(16, 64), 256, 0, stream>>>(fv_w, fvT, 2048, 512);
    transpose_cvt<<<dim3(64, 64), 256, 0, stream>>>(fo_w, foT, 2048, 2048);

    cvt_f32_bf16<<<(128 * 2048 / 4 + 255) / 256, 256, 0, stream>>>(dsk, dskb, 128 * 2048 / 4);
    cvt_f32_bf16<<<(128 * 2048 / 4 + 255) / 256, 256, 0, stream>>>(dsv, dsvb, 128 * 2048 / 4);
    rmsnorm_kernel<<<4096, 256, 0, stream>>>(hidden, cn_w, normA);

    // coarse projections
    gemm_tn<0><<<dim3(16, 32), 256, 0, stream>>>(normA, cqT, qbuf, nullptr, nullptr, nullptr, 4096, 2048, 2048);
    gemm_tn<0><<<dim3(4, 1), 256, 0, stream>>>(dskb, ckT, kc, nullptr, nullptr, nullptr, 128, 512, 2048);
    gemm_tn<0><<<dim3(4, 1), 256, 0, stream>>>(dsvb, cvT, vc, nullptr, nullptr, nullptr, 128, 512, 2048);

    // coarse attention (attn_c into normA) + doc-score partials
    coarse_attn<<<1024, 256, 0, stream>>>(qbuf, kc, vc, dsmask, doc_part, normA);
    doc_finalize<<<1, 128, 0, stream>>>(doc_part, log_ds);
    bias_kernel<<<16, 256, 0, stream>>>(log_ds, map, tmask, biasb);

    // coarse o-proj + residual + gate -> d_out (f32)
    gemm_tn<1><<<dim3(16, 32), 256, 0, stream>>>(normA, coT, nullptr, out_f, hidden, c_gate, 4096, 2048, 2048);

    // fine stage
    rmsnorm_kernel<<<4096, 256, 0, stream>>>(out_f, fn_w, qbuf);
    gemm_tn<0><<<dim3(16, 32), 256, 0, stream>>>(qbuf, fqT, normA, nullptr, nullptr, nullptr, 4096, 2048, 2048);
    cvt_f32_bf16<<<(4096 * 2048 / 4 + 255) / 256, 256, 0, stream>>>(tk, qbuf, 4096 * 2048 / 4);
    gemm_tn<0><<<dim3(4, 32), 256, 0, stream>>>(qbuf, fkT, kfb, nullptr, nullptr, nullptr, 4096, 512, 2048);
    cvt_f32_bf16<<<(4096 * 2048 / 4 + 255) / 256, 256, 0, stream>>>(tv, qbuf, 4096 * 2048 / 4);
    // V^T directly from the projection: vT[d][token] = fvT[d][:] . tv[token][:]
    gemm_tn<0><<<dim3(32, 4), 256, 0, stream>>>(fvT, qbuf, vTb, nullptr, nullptr, nullptr, 512, 4096, 2048);

    flash_attn<<<1024, 256, 0, stream>>>(normA, kfb, vTb, biasb, qbuf);

    // final o-proj + residual + gate -> d_out
    gemm_tn<1><<<dim3(16, 32), 256, 0, stream>>>(qbuf, foT, nullptr, out_f, out_f, f_gate, 4096, 2048, 2048);
}

// Round 5
// 644.543 us; speedup vs baseline: 1.6016x; 1.0264x over previous
//
#include <hip/hip_runtime.h>
#include <hip/hip_bf16.h>

typedef unsigned short u16;
typedef unsigned int u32;
typedef __attribute__((ext_vector_type(8))) short bf16x8;
typedef __attribute__((ext_vector_type(4))) float f32x4;

constexpr int NH = 16;
constexpr int H = 2048;
constexpr float SCALE = 0.08838834764831845f;   // 1/sqrt(128)
constexpr float L2E = 1.4426950408889634f;      // log2(e)
constexpr float SCALE2 = SCALE * L2E;           // QK scale in log2 domain
constexpr float THR2 = 8.0f * L2E;              // defer-max threshold (log2 units)

__device__ __forceinline__ u16 f2bf(float f) {
    u32 u = __float_as_uint(f);
    u32 r = u + 0x7fffu + ((u >> 16) & 1u);   // RNE (finite inputs only)
    return (u16)(r >> 16);
}
__device__ __forceinline__ u32 pack2(float x, float y) {
    return (u32)f2bf(x) | ((u32)f2bf(y) << 16);
}
__device__ __forceinline__ u32 pack2_cvt(float x, float y) {
    __hip_bfloat162 h = __float22bfloat162_rn(float2{x, y});
    return *reinterpret_cast<u32*>(&h);
}

#define GLD_LDS16(gsrc, ldst)                                                  \
    __builtin_amdgcn_global_load_lds(                                          \
        (const __attribute__((address_space(1))) void*)(gsrc),                 \
        (__attribute__((address_space(3))) void*)(ldst), 16, 0, 0)

// ---------------- f32 -> bf16 convert (vectorized) ----------------
__global__ __launch_bounds__(256) void cvt_f32_bf16(const float* __restrict__ in,
                                                    u16* __restrict__ out, int n4) {
    int i = blockIdx.x * 256 + threadIdx.x;
    if (i >= n4) return;
    float4 v = reinterpret_cast<const float4*>(in)[i];
    uint2 o;
    o.x = pack2(v.x, v.y);
    o.y = pack2(v.z, v.w);
    reinterpret_cast<uint2*>(out)[i] = o;
}

// ---------------- weight transpose + convert: f32[K][N] -> bf16[N][K] ----------------
__global__ __launch_bounds__(256)
void transpose_cvt(const float* __restrict__ in, u16* __restrict__ out, int K, int N) {
    __shared__ u16 tile[32][33];
    int bn = blockIdx.x * 32, bk = blockIdx.y * 32;
    int tx = threadIdx.x & 31, ty = threadIdx.x >> 5;  // ty 0..7
#pragma unroll
    for (int r = 0; r < 32; r += 8)
        tile[tx][r + ty] = f2bf(in[(size_t)(bk + r + ty) * N + bn + tx]);
    __syncthreads();
#pragma unroll
    for (int r = 0; r < 32; r += 8)
        out[(size_t)(bn + r + ty) * K + bk + tx] = tile[r + ty][tx];
}

// ---------------- RMSNorm f32 -> bf16, H=2048, one block per row ----------------
__global__ __launch_bounds__(256) void rmsnorm_kernel(const float* __restrict__ x,
                                                      const float* __restrict__ w,
                                                      u16* __restrict__ y) {
    int r = blockIdx.x;
    const float4* xr = reinterpret_cast<const float4*>(x + (size_t)r * H);
    int t = threadIdx.x;
    float4 v0 = xr[t * 2], v1 = xr[t * 2 + 1];
    float ss = v0.x * v0.x + v0.y * v0.y + v0.z * v0.z + v0.w * v0.w
             + v1.x * v1.x + v1.y * v1.y + v1.z * v1.z + v1.w * v1.w;
#pragma unroll
    for (int d = 1; d < 64; d <<= 1) ss += __shfl_xor(ss, d);
    __shared__ float red[4];
    if ((t & 63) == 0) red[t >> 6] = ss;
    __syncthreads();
    float tot = red[0] + red[1] + red[2] + red[3];
    float rs = rsqrtf(tot * (1.0f / H) + 1e-6f);
    const float4* wr = reinterpret_cast<const float4*>(w);
    float4 w0 = wr[t * 2], w1 = wr[t * 2 + 1];
    uint4 o;
    o.x = pack2(v0.x * rs * w0.x, v0.y * rs * w0.y);
    o.y = pack2(v0.z * rs * w0.z, v0.w * rs * w0.w);
    o.z = pack2(v1.x * rs * w1.x, v1.y * rs * w1.y);
    o.w = pack2(v1.z * rs * w1.z, v1.w * rs * w1.w);
    reinterpret_cast<uint4*>(y + (size_t)r * H)[t] = o;
}

// ---------------- GEMM (m97 structure): C[M,N] = A_bf16[M,K] @ Bt_bf16[N,K]^T --------
// MODE 0: store bf16 C.  MODE 1: Cf = resid + sigmoid(*gate_p) * acc (f32 out).
template <int MODE>
__global__ __launch_bounds__(256)
void gemm_tn(const u16* __restrict__ A, const u16* __restrict__ Bt,
             u16* __restrict__ Cb, float* __restrict__ Cf,
             const float* __restrict__ resid, const float* __restrict__ gate_p,
             int M, int N, int K) {
    __shared__ u16 As[128 * 32];
    __shared__ u16 Bs[128 * 32];
    const int t = threadIdx.x;
    const int lane = t & 63, wid = t >> 6;
    const int wm = wid >> 1, wn = wid & 1;
    const int brow = blockIdx.y * 128, bcol = blockIdx.x * 128;
    const int l15 = lane & 15;
    const int k0 = (lane >> 4) * 8;

    f32x4 acc[4][4] = {};
    const int srow = lane >> 2, sseg = (lane & 3) * 8;
    const u16* aBase = A  + (size_t)(brow + wid * 32 + srow) * K + sseg;
    const u16* bBase = Bt + (size_t)(bcol + wid * 32 + srow) * K + sseg;
    u16* aD0 = As + (wid * 32) * 32;
    u16* aD1 = As + (wid * 32 + 16) * 32;
    u16* bD0 = Bs + (wid * 32) * 32;
    u16* bD1 = Bs + (wid * 32 + 16) * 32;
    const size_t row16 = (size_t)16 * K;

    for (int kt = 0; kt < K; kt += 32) {
        GLD_LDS16(aBase + kt, aD0);
        GLD_LDS16(aBase + kt + row16, aD1);
        GLD_LDS16(bBase + kt, bD0);
        GLD_LDS16(bBase + kt + row16, bD1);
        __syncthreads();
        bf16x8 af[4], bfr[4];
#pragma unroll
        for (int i = 0; i < 4; ++i)
            af[i] = *reinterpret_cast<const bf16x8*>(&As[(wm * 64 + i * 16 + l15) * 32 + k0]);
#pragma unroll
        for (int j = 0; j < 4; ++j)
            bfr[j] = *reinterpret_cast<const bf16x8*>(&Bs[(wn * 64 + j * 16 + l15) * 32 + k0]);
#pragma unroll
        for (int i = 0; i < 4; ++i)
#pragma unroll
            for (int j = 0; j < 4; ++j)
                acc[i][j] = __builtin_amdgcn_mfma_f32_16x16x32_bf16(af[i], bfr[j], acc[i][j], 0, 0, 0);
        __syncthreads();
    }
    float g = 0.f;
    if (MODE == 1) g = 1.0f / (1.0f + expf(-gate_p[0]));
    const int r0 = (lane >> 4) * 4, c0 = l15;
#pragma unroll
    for (int i = 0; i < 4; ++i) {
#pragma unroll
        for (int j = 0; j < 4; ++j) {
            int col = bcol + wn * 64 + j * 16 + c0;
#pragma unroll
            for (int r = 0; r < 4; ++r) {
                int row = brow + wm * 64 + i * 16 + r0 + r;
                float v = acc[i][j][r];
                if (MODE == 0) Cb[(size_t)row * N + col] = f2bf(v);
                else Cf[(size_t)row * N + col] = resid[(size_t)row * N + col] + g * v;
            }
        }
    }
}

// ---------------- coarse attention (ND=64 keys, exact softmax, exp2 domain) --------
__global__ __launch_bounds__(256)
void coarse_attn(const u16* __restrict__ q, const u16* __restrict__ kc,
                 const u16* __restrict__ vc, const float* __restrict__ mask,
                 float* __restrict__ doc_part, u16* __restrict__ attn_c) {
    constexpr int SC = 2048 / 64;
    int bid = blockIdx.x;
    int b = bid / (NH * SC);
    int rem = bid % (NH * SC);
    int h = rem / SC, sc = rem % SC;
    int kv = h >> 2;
    int t = threadIdx.x, lane = t & 63, wid = t >> 6;
    const int l15 = lane & 15, k0 = (lane >> 4) * 8;

    __shared__ u16 Kt[64 * 136];
    __shared__ u16 Vt[128 * 72];
    __shared__ u16 Pt[4][16 * 72];
    __shared__ float p_acc[64];

    {   // stage K [64 keys][128 d]
        int n = t >> 2, s2 = t & 3;
        const u16* src = kc + (size_t)(b * 64 + n) * 512 + kv * 128;
#pragma unroll
        for (int u = 0; u < 4; ++u) {
            int sg = s2 + u * 4;
            *reinterpret_cast<uint4*>(&Kt[n * 136 + sg * 8]) =
                *reinterpret_cast<const uint4*>(src + sg * 8);
        }
    }
    {   // stage V transposed: Vt[d][key]
        int n = t & 63, dblk = t >> 6;
        const u16* src = vc + (size_t)(b * 64 + n) * 512 + kv * 128 + dblk * 32;
#pragma unroll
        for (int u = 0; u < 4; ++u) {
            u16 tmp[8];
            *reinterpret_cast<uint4*>(tmp) = *reinterpret_cast<const uint4*>(src + u * 8);
#pragma unroll
            for (int e = 0; e < 8; ++e) Vt[(dblk * 32 + u * 8 + e) * 72 + n] = tmp[e];
        }
    }
    if (t < 64) p_acc[t] = 0.f;
    __syncthreads();

    int qrow = sc * 64 + wid * 16 + l15;
    const u16* qsrc = q + (size_t)(b * 2048 + qrow) * 2048 + h * 128;
    bf16x8 af[4];
#pragma unroll
    for (int kk = 0; kk < 4; ++kk)
        af[kk] = *reinterpret_cast<const bf16x8*>(qsrc + kk * 32 + k0);

    f32x4 sc4[4] = {};
#pragma unroll
    for (int kk = 0; kk < 4; ++kk)
#pragma unroll
        for (int j = 0; j < 4; ++j) {
            bf16x8 bfr = *reinterpret_cast<const bf16x8*>(&Kt[(j * 16 + l15) * 136 + kk * 32 + k0]);
            sc4[j] = __builtin_amdgcn_mfma_f32_16x16x32_bf16(af[kk], bfr, sc4[j], 0, 0, 0);
        }

    float s[4][4];
#pragma unroll
    for (int j = 0; j < 4; ++j) {
        float bia = (1.0f - mask[b * 64 + j * 16 + l15]) * (-1e9f * L2E);
#pragma unroll
        for (int r = 0; r < 4; ++r) s[j][r] = sc4[j][r] * SCALE2 + bia;
    }
    float m4[4], l4[4];
#pragma unroll
    for (int r = 0; r < 4; ++r) {
        float m = fmaxf(fmaxf(s[0][r], s[1][r]), fmaxf(s[2][r], s[3][r]));
#pragma unroll
        for (int d = 1; d < 16; d <<= 1) m = fmaxf(m, __shfl_xor(m, d));
        m4[r] = m;
    }
#pragma unroll
    for (int r = 0; r < 4; ++r) {
        float l = 0.f;
#pragma unroll
        for (int j = 0; j < 4; ++j) { s[j][r] = exp2f(s[j][r] - m4[r]); l += s[j][r]; }
#pragma unroll
        for (int d = 1; d < 16; d <<= 1) l += __shfl_xor(l, d);
        l4[r] = l;
    }
#pragma unroll
    for (int j = 0; j < 4; ++j) {
        float cs = 0.f;
#pragma unroll
        for (int r = 0; r < 4; ++r) {
            float pr = s[j][r] / l4[r];
            Pt[wid][((lane >> 4) * 4 + r) * 72 + j * 16 + l15] = f2bf(pr);
            cs += pr;
        }
        cs += __shfl_xor(cs, 16);
        cs += __shfl_xor(cs, 32);
        if (lane < 16) atomicAdd(&p_acc[j * 16 + lane], cs);
    }
    __syncthreads();

    f32x4 o4[8] = {};
#pragma unroll
    for (int kk2 = 0; kk2 < 2; ++kk2) {
        bf16x8 a2 = *reinterpret_cast<const bf16x8*>(&Pt[wid][l15 * 72 + kk2 * 32 + k0]);
#pragma unroll
        for (int j2 = 0; j2 < 8; ++j2) {
            bf16x8 b2 = *reinterpret_cast<const bf16x8*>(&Vt[(j2 * 16 + l15) * 72 + kk2 * 32 + k0]);
            o4[j2] = __builtin_amdgcn_mfma_f32_16x16x32_bf16(a2, b2, o4[j2], 0, 0, 0);
        }
    }
#pragma unroll
    for (int j2 = 0; j2 < 8; ++j2)
#pragma unroll
        for (int r = 0; r < 4; ++r) {
            int row = sc * 64 + wid * 16 + (lane >> 4) * 4 + r;
            attn_c[(size_t)(b * 2048 + row) * 2048 + h * 128 + j2 * 16 + l15] = f2bf(o4[j2][r]);
        }
    if (t < 64) atomicAdd(&doc_part[(blockIdx.x & 7) * 128 + b * 64 + t], p_acc[t]);
}

// ---------------- doc-score finalize + fine bias (bias pre-scaled by log2e) --------
__global__ void doc_finalize(const float* __restrict__ doc_part, float* __restrict__ log_ds) {
    int t = threadIdx.x; // 128
    float s = 0.f;
#pragma unroll
    for (int i = 0; i < 8; ++i) s += doc_part[i * 128 + t];
    log_ds[t] = logf(s / 32768.0f + 1e-6f);
}

__global__ __launch_bounds__(256)
void bias_kernel(const float* __restrict__ log_ds, const int* __restrict__ map,
                 const float* __restrict__ tmask, float* __restrict__ bias) {
    int i = blockIdx.x * 256 + threadIdx.x;
    if (i >= 2 * 2048) return;
    int b = i >> 11;
    bias[i] = (log_ds[b * 64 + map[i]] + (1.0f - tmask[i]) * -1e9f) * L2E;
}

// ---------------- fine flash attention v3 (exp2 domain) ----------------
// KVBLK=64, swapped QK^T, defer-max; swizzled gload_lds staging for K and V^T.
__global__ __launch_bounds__(256)
void flash_attn(const u16* __restrict__ q, const u16* __restrict__ kf,
                const u16* __restrict__ vT, const float* __restrict__ bias,
                u16* __restrict__ attn_f) {
    int bid = blockIdx.x;
    int b = bid >> 9;              // NH * 32 = 512 blocks per batch
    int rem = bid & 511;
    int h = rem >> 5, sc = rem & 31;
    int kv = h >> 2;
    int t = threadIdx.x, lane = t & 63, wid = t >> 6;
    const int l15 = lane & 15, hi = lane >> 4;
    const int k0 = hi * 8;

    __shared__ u16 Kt[64 * 128];       // [key][d] linear, swizzled 16B slots
    __shared__ u16 Vt[128 * 64];       // [d][key] linear, swizzled 16B slots
    __shared__ u16 Pt[4][16 * 72];     // per-wave P[q][key], pad 8
    __shared__ float bias_s[64];

    int qrow = sc * 64 + wid * 16 + l15;
    const u16* qsrc = q + (size_t)(b * 2048 + qrow) * 2048 + h * 128;
    bf16x8 qf4[4];
#pragma unroll
    for (int kk = 0; kk < 4; ++kk)
        qf4[kk] = *reinterpret_cast<const bf16x8*>(qsrc + kk * 32 + k0);

    // staging lane roles (constant over tiles)
    const int krl = lane >> 4, kslot = lane & 15;   // K: 4 rows x 16 slots per 1KB
    const int vrl = lane >> 3, vslot = lane & 7;    // V: 8 rows x 8 slots per 1KB
    const u16* kbase = kf + (size_t)(b * 2048) * 512 + kv * 128;
    const u16* vbase = vT + (size_t)(kv * 128) * 4096 + b * 2048;

    float mstate = -1e30f, lstate = 0.f;   // mstate in log2 domain
    f32x4 o4[8] = {};

    for (int t0 = 0; t0 < 2048; t0 += 64) {
        // stage K: wave wid covers keys [wid*16, wid*16+16)
#pragma unroll
        for (int u = 0; u < 4; ++u) {
            int row = wid * 16 + u * 4 + krl;
            const u16* src = kbase + (size_t)(t0 + row) * 512 + ((kslot ^ (row & 7)) * 8);
            GLD_LDS16(src, &Kt[(wid * 16 + u * 4) * 128]);
        }
        // stage V^T: wave wid covers d in [wid*32, wid*32+32)
#pragma unroll
        for (int u = 0; u < 4; ++u) {
            int row = wid * 32 + u * 8 + vrl;
            const u16* src = vbase + (size_t)row * 4096 + t0 + ((vslot ^ (row & 7)) * 8);
            GLD_LDS16(src, &Vt[(wid * 32 + u * 8) * 64]);
        }
        if (t < 64) bias_s[t] = bias[b * 2048 + t0 + t];
        __syncthreads();

        // QK^T swapped: S^T[key][q] = K-frag (A) x Q-frag (B)
        f32x4 st[4] = {};
#pragma unroll
        for (int kk = 0; kk < 4; ++kk)
#pragma unroll
            for (int kb = 0; kb < 4; ++kb) {
                int row = kb * 16 + l15;
                bf16x8 kfrag = *reinterpret_cast<const bf16x8*>(
                    &Kt[row * 128 + (((kk * 4 + hi) ^ (row & 7)) * 8)]);
                st[kb] = __builtin_amdgcn_mfma_f32_16x16x32_bf16(kfrag, qf4[kk], st[kb], 0, 0, 0);
            }

        // per-lane: q = l15, keys = kb*16 + hi*4 + r ; all in log2 domain
        float p[4][4];
        float pmax = -1e30f;
#pragma unroll
        for (int kb = 0; kb < 4; ++kb) {
            float4 b4 = *reinterpret_cast<const float4*>(&bias_s[kb * 16 + hi * 4]);
            float bb[4] = {b4.x, b4.y, b4.z, b4.w};
#pragma unroll
            for (int r = 0; r < 4; ++r) {
                float v = st[kb][r] * SCALE2 + bb[r];
                p[kb][r] = v;
                pmax = fmaxf(pmax, v);
            }
        }
        pmax = fmaxf(pmax, __shfl_xor(pmax, 16));
        pmax = fmaxf(pmax, __shfl_xor(pmax, 32));

        // defer-max (T13): only rescale when the tile max grew past THR
        if (!__all(pmax <= mstate + THR2)) {
            float mnew = fmaxf(mstate, pmax);
            float sco = exp2f(mstate - mnew);
            float sco_out[4];
#pragma unroll
            for (int r = 0; r < 4; ++r) sco_out[r] = __shfl(sco, hi * 4 + r);
#pragma unroll
            for (int j2 = 0; j2 < 8; ++j2)
#pragma unroll
                for (int r = 0; r < 4; ++r) o4[j2][r] *= sco_out[r];
            lstate *= sco;
            mstate = mnew;
        }

        float lt = 0.f;
#pragma unroll
        for (int kb = 0; kb < 4; ++kb)
#pragma unroll
            for (int r = 0; r < 4; ++r) {
                p[kb][r] = exp2f(p[kb][r] - mstate);
                lt += p[kb][r];
            }
        lt += __shfl_xor(lt, 16);
        lt += __shfl_xor(lt, 32);
        lstate += lt;

        // write P[q][key] (per-wave buffer; same-wave DS ordering)
#pragma unroll
        for (int kb = 0; kb < 4; ++kb) {
            uint2 w;
            w.x = pack2_cvt(p[kb][0], p[kb][1]);
            w.y = pack2_cvt(p[kb][2], p[kb][3]);
            *reinterpret_cast<uint2*>(&Pt[wid][l15 * 72 + kb * 16 + hi * 4]) = w;
        }

        // PV: O[q][d] += P (A) x V^T-frag (B)
#pragma unroll
        for (int kc = 0; kc < 2; ++kc) {
            bf16x8 pa = *reinterpret_cast<const bf16x8*>(&Pt[wid][l15 * 72 + kc * 32 + k0]);
#pragma unroll
            for (int j2 = 0; j2 < 8; ++j2) {
                int d = j2 * 16 + l15;
                bf16x8 vb = *reinterpret_cast<const bf16x8*>(
                    &Vt[d * 64 + (((kc * 4 + hi) ^ (d & 7)) * 8)]);
                o4[j2] = __builtin_amdgcn_mfma_f32_16x16x32_bf16(pa, vb, o4[j2], 0, 0, 0);
            }
        }
        __syncthreads();
    }

    // l is in softmax layout (q = l15); outputs need q = hi*4+r
    float linv[4];
#pragma unroll
    for (int r = 0; r < 4; ++r) linv[r] = 1.0f / __shfl(lstate, hi * 4 + r);
#pragma unroll
    for (int j2 = 0; j2 < 8; ++j2)
#pragma unroll
        for (int r = 0; r < 4; ++r) {
            int row = sc * 64 + wid * 16 + hi * 4 + r;
            attn_f[(size_t)(b * 2048 + row) * 2048 + h * 128 + j2 * 16 + l15] =
                f2bf(o4[j2][r] * linv[r]);
        }
}

// ---------------- launch ----------------
extern "C" void kernel_launch(void* const* d_in, const int* in_sizes, int n_in,
                              void* d_out, int out_size, void* d_ws, size_t ws_size,
                              hipStream_t stream) {
    const float* hidden = (const float*)d_in[0];
    const float* dsk    = (const float*)d_in[1];
    const float* dsv    = (const float*)d_in[2];
    const float* dsmask = (const float*)d_in[3];
    const float* tk     = (const float*)d_in[4];
    const float* tv     = (const float*)d_in[5];
    const float* tmask  = (const float*)d_in[6];
    const float* cn_w   = (const float*)d_in[7];
    const float* cq_w   = (const float*)d_in[8];
    const float* ck_w   = (const float*)d_in[9];
    const float* cv_w   = (const float*)d_in[10];
    const float* co_w   = (const float*)d_in[11];
    const float* c_gate = (const float*)d_in[12];
    const float* fn_w   = (const float*)d_in[13];
    const float* fq_w   = (const float*)d_in[14];
    const float* fk_w   = (const float*)d_in[15];
    const float* fv_w   = (const float*)d_in[16];
    const float* fo_w   = (const float*)d_in[17];
    const float* f_gate = (const float*)d_in[18];
    const int*   map    = (const int*)d_in[19];
    float* out_f = (float*)d_out;   // also the f32 buffer for coarse residual

    char* ws = (char*)d_ws;
    size_t off = 0;
    auto alloc = [&](size_t bytes) {
        char* p = ws + off;
        off += (bytes + 255) & ~(size_t)255;
        return p;
    };
    u16*  normA = (u16*)alloc(4096ULL * 2048 * 2);
    u16*  qbuf  = (u16*)alloc(4096ULL * 2048 * 2);
    u16*  kc    = (u16*)alloc(128ULL * 512 * 2);
    u16*  vc    = (u16*)alloc(128ULL * 512 * 2);
    u16*  dskb  = (u16*)alloc(128ULL * 2048 * 2);
    u16*  dsvb  = (u16*)alloc(128ULL * 2048 * 2);
    u16*  kfb   = (u16*)alloc(4096ULL * 512 * 2);
    u16*  vTb   = (u16*)alloc(512ULL * 4096 * 2);   // V^T [kv*128+d][b*2048+t]
    u16*  cqT   = (u16*)alloc(2048ULL * 2048 * 2);
    u16*  ckT   = (u16*)alloc(512ULL * 2048 * 2);
    u16*  cvT   = (u16*)alloc(512ULL * 2048 * 2);
    u16*  coT   = (u16*)alloc(2048ULL * 2048 * 2);
    u16*  fqT   = (u16*)alloc(2048ULL * 2048 * 2);
    u16*  fkT   = (u16*)alloc(512ULL * 2048 * 2);
    u16*  fvT   = (u16*)alloc(512ULL * 2048 * 2);
    u16*  foT   = (u16*)alloc(2048ULL * 2048 * 2);
    float* doc_part = (float*)alloc(8 * 128 * 4);
    float* log_ds   = (float*)alloc(128 * 4);
    float* biasb    = (float*)alloc(4096 * 4);

    hipMemsetAsync(doc_part, 0, 8 * 128 * 4, stream);

    // weight transposes (f32 [K=2048][N] -> bf16 [N][2048])
    transpose_cvt<<<dim3(64, 64), 256, 0, stream>>>(cq_w, cqT, 2048, 2048);
    transpose_cvt<<<dim3(16, 64), 256, 0, stream>>>(ck_w, ckT, 2048, 512);
    transpose_cvt<<<dim3(16, 64), 256, 0, stream>>>(cv_w, cvT, 2048, 512);
    transpose_cvt<<<dim3(64, 64), 256, 0, stream>>>(co_w, coT, 2048, 2048);
    transpose_cvt<<<dim3(64, 64), 256, 0, stream>>>(fq_w, fqT, 2048, 2048);
    transpose_cvt<<<dim3(16, 64), 256, 0, stream>>>(fk_w, fkT, 2048, 512);
    transpose_cvt<<<dim3(16, 64), 256, 0, stream>>>(fv_w, fvT, 2048, 512);
    transpose_cvt<<<dim3(64, 64), 256, 0, stream>>>(fo_w, foT, 2048, 2048);

    cvt_f32_bf16<<<(128 * 2048 / 4 + 255) / 256, 256, 0, stream>>>(dsk, dskb, 128 * 2048 / 4);
    cvt_f32_bf16<<<(128 * 2048 / 4 + 255) / 256, 256, 0, stream>>>(dsv, dsvb, 128 * 2048 / 4);
    rmsnorm_kernel<<<4096, 256, 0, stream>>>(hidden, cn_w, normA);

    // coarse projections
    gemm_tn<0><<<dim3(16, 32), 256, 0, stream>>>(normA, cqT, qbuf, nullptr, nullptr, nullptr, 4096, 2048, 2048);
    gemm_tn<0><<<dim3(4, 1), 256, 0, stream>>>(dskb, ckT, kc, nullptr, nullptr, nullptr, 128, 512, 2048);
    gemm_tn<0><<<dim3(4, 1), 256, 0, stream>>>(dsvb, cvT, vc, nullptr, nullptr, nullptr, 128, 512, 2048);

    // coarse attention (attn_c into normA) + doc-score partials
    coarse_attn<<<1024, 256, 0, stream>>>(qbuf, kc, vc, dsmask, doc_part, normA);
    doc_finalize<<<1, 128, 0, stream>>>(doc_part, log_ds);
    bias_kernel<<<16, 256, 0, stream>>>(log_ds, map, tmask, biasb);

    // coarse o-proj + residual + gate -> d_out (f32)
    gemm_tn<1><<<dim3(16, 32), 256, 0, stream>>>(normA, coT, nullptr, out_f, hidden, c_gate, 4096, 2048, 2048);

    // fine stage
    rmsnorm_kernel<<<4096, 256, 0, stream>>>(out_f, fn_w, qbuf);
    gemm_tn<0><<<dim3(16, 32), 256, 0, stream>>>(qbuf, fqT, normA, nullptr, nullptr, nullptr, 4096, 2048, 2048);
    cvt_f32_bf16<<<(4096 * 2048 / 4 + 255) / 256, 256, 0, stream>>>(tk, qbuf, 4096 * 2048 / 4);
    gemm_tn<0><<<dim3(4, 32), 256, 0, stream>>>(qbuf, fkT, kfb, nullptr, nullptr, nullptr, 4096, 512, 2048);
    cvt_f32_bf16<<<(4096 * 2048 / 4 + 255) / 256, 256, 0, stream>>>(tv, qbuf, 4096 * 2048 / 4);
    // V^T directly from the projection: vT[d][token] = fvT[d][:] . tv[token][:]
    gemm_tn<0><<<dim3(32, 4), 256, 0, stream>>>(fvT, qbuf, vTb, nullptr, nullptr, nullptr, 512, 4096, 2048);

    flash_attn<<<1024, 256, 0, stream>>>(normA, kfb, vTb, biasb, qbuf);

    // final o-proj + residual + gate -> d_out
    gemm_tn<1><<<dim3(16, 32), 256, 0, stream>>>(qbuf, foT, nullptr, out_f, out_f, f_gate, 4096, 2048, 2048);
}

// Round 6
// 610.711 us; speedup vs baseline: 1.6903x; 1.0554x over previous
//
#include <hip/hip_runtime.h>
#include <hip/hip_bf16.h>

typedef unsigned short u16;
typedef unsigned int u32;
typedef __attribute__((ext_vector_type(8))) short bf16x8;
typedef __attribute__((ext_vector_type(4))) float f32x4;

constexpr int NH = 16;
constexpr int H = 2048;
constexpr float SCALE = 0.08838834764831845f;   // 1/sqrt(128)
constexpr float L2E = 1.4426950408889634f;      // log2(e)
constexpr float SCALE2 = SCALE * L2E;           // QK scale in log2 domain
constexpr float THR2 = 8.0f * L2E;              // defer-max threshold (log2 units)

__device__ __forceinline__ u16 f2bf(float f) {
    u32 u = __float_as_uint(f);
    u32 r = u + 0x7fffu + ((u >> 16) & 1u);   // RNE (finite inputs only)
    return (u16)(r >> 16);
}
__device__ __forceinline__ u32 pack2(float x, float y) {
    return (u32)f2bf(x) | ((u32)f2bf(y) << 16);
}
__device__ __forceinline__ u32 pack2_cvt(float x, float y) {
    __hip_bfloat162 h = __float22bfloat162_rn(float2{x, y});
    return *reinterpret_cast<u32*>(&h);
}

#define GLD_LDS16(gsrc, ldst)                                                  \
    __builtin_amdgcn_global_load_lds(                                          \
        (const __attribute__((address_space(1))) void*)(gsrc),                 \
        (__attribute__((address_space(3))) void*)(ldst), 16, 0, 0)

// ---------------- f32 -> bf16 convert (vectorized) ----------------
__global__ __launch_bounds__(256) void cvt_f32_bf16(const float* __restrict__ in,
                                                    u16* __restrict__ out, int n4) {
    int i = blockIdx.x * 256 + threadIdx.x;
    if (i >= n4) return;
    float4 v = reinterpret_cast<const float4*>(in)[i];
    uint2 o;
    o.x = pack2(v.x, v.y);
    o.y = pack2(v.z, v.w);
    reinterpret_cast<uint2*>(out)[i] = o;
}

// ---------------- weight transpose + convert: f32[K][N] -> bf16[N][K] ----------------
__global__ __launch_bounds__(256)
void transpose_cvt(const float* __restrict__ in, u16* __restrict__ out, int K, int N) {
    __shared__ u16 tile[32][33];
    int bn = blockIdx.x * 32, bk = blockIdx.y * 32;
    int tx = threadIdx.x & 31, ty = threadIdx.x >> 5;  // ty 0..7
#pragma unroll
    for (int r = 0; r < 32; r += 8)
        tile[tx][r + ty] = f2bf(in[(size_t)(bk + r + ty) * N + bn + tx]);
    __syncthreads();
#pragma unroll
    for (int r = 0; r < 32; r += 8)
        out[(size_t)(bn + r + ty) * K + bk + tx] = tile[r + ty][tx];
}

// ---------------- RMSNorm f32 -> bf16, H=2048, one block per row ----------------
__global__ __launch_bounds__(256) void rmsnorm_kernel(const float* __restrict__ x,
                                                      const float* __restrict__ w,
                                                      u16* __restrict__ y) {
    int r = blockIdx.x;
    const float4* xr = reinterpret_cast<const float4*>(x + (size_t)r * H);
    int t = threadIdx.x;
    float4 v0 = xr[t * 2], v1 = xr[t * 2 + 1];
    float ss = v0.x * v0.x + v0.y * v0.y + v0.z * v0.z + v0.w * v0.w
             + v1.x * v1.x + v1.y * v1.y + v1.z * v1.z + v1.w * v1.w;
#pragma unroll
    for (int d = 1; d < 64; d <<= 1) ss += __shfl_xor(ss, d);
    __shared__ float red[4];
    if ((t & 63) == 0) red[t >> 6] = ss;
    __syncthreads();
    float tot = red[0] + red[1] + red[2] + red[3];
    float rs = rsqrtf(tot * (1.0f / H) + 1e-6f);
    const float4* wr = reinterpret_cast<const float4*>(w);
    float4 w0 = wr[t * 2], w1 = wr[t * 2 + 1];
    uint4 o;
    o.x = pack2(v0.x * rs * w0.x, v0.y * rs * w0.y);
    o.y = pack2(v0.z * rs * w0.z, v0.w * rs * w0.w);
    o.z = pack2(v1.x * rs * w1.x, v1.y * rs * w1.y);
    o.w = pack2(v1.z * rs * w1.z, v1.w * rs * w1.w);
    reinterpret_cast<uint4*>(y + (size_t)r * H)[t] = o;
}

// ---------------- GEMM (m97 structure): C[M,N] = A_bf16[M,K] @ Bt_bf16[N,K]^T --------
// MODE 0: store bf16 C.  MODE 1: Cf = resid + sigmoid(*gate_p) * acc (f32 out).
// BN: 128 (big GEMMs) or 64 (thin GEMMs -> 2x grid for full-chip occupancy).
template <int MODE, int BN>
__global__ __launch_bounds__(256)
void gemm_tn(const u16* __restrict__ A, const u16* __restrict__ Bt,
             u16* __restrict__ Cb, float* __restrict__ Cf,
             const float* __restrict__ resid, const float* __restrict__ gate_p,
             int M, int N, int K) {
    constexpr int WN = BN / 32;          // N frags per wave: 4 or 2
    __shared__ u16 As[128 * 32];
    __shared__ u16 Bs[BN * 32];
    const int t = threadIdx.x;
    const int lane = t & 63, wid = t >> 6;
    const int wm = wid >> 1, wn = wid & 1;
    const int brow = blockIdx.y * 128, bcol = blockIdx.x * BN;
    const int l15 = lane & 15;
    const int k0 = (lane >> 4) * 8;

    f32x4 acc[4][WN] = {};
    const int srow = lane >> 2, sseg = (lane & 3) * 8;
    const u16* aBase = A + (size_t)(brow + wid * 32 + srow) * K + sseg;
    u16* aD0 = As + (wid * 32) * 32;
    u16* aD1 = As + (wid * 32 + 16) * 32;
    const size_t row16 = (size_t)16 * K;
    const u16* bBase;
    u16 *bD0, *bD1 = nullptr;
    if constexpr (BN == 128) {
        bBase = Bt + (size_t)(bcol + wid * 32 + srow) * K + sseg;
        bD0 = Bs + (wid * 32) * 32;
        bD1 = Bs + (wid * 32 + 16) * 32;
    } else {
        bBase = Bt + (size_t)(bcol + wid * 16 + srow) * K + sseg;
        bD0 = Bs + (wid * 16) * 32;
    }

    for (int kt = 0; kt < K; kt += 32) {
        GLD_LDS16(aBase + kt, aD0);
        GLD_LDS16(aBase + kt + row16, aD1);
        GLD_LDS16(bBase + kt, bD0);
        if constexpr (BN == 128) GLD_LDS16(bBase + kt + row16, bD1);
        __syncthreads();
        bf16x8 af[4], bfr[WN];
#pragma unroll
        for (int i = 0; i < 4; ++i)
            af[i] = *reinterpret_cast<const bf16x8*>(&As[(wm * 64 + i * 16 + l15) * 32 + k0]);
#pragma unroll
        for (int j = 0; j < WN; ++j)
            bfr[j] = *reinterpret_cast<const bf16x8*>(&Bs[(wn * (BN / 2) + j * 16 + l15) * 32 + k0]);
#pragma unroll
        for (int i = 0; i < 4; ++i)
#pragma unroll
            for (int j = 0; j < WN; ++j)
                acc[i][j] = __builtin_amdgcn_mfma_f32_16x16x32_bf16(af[i], bfr[j], acc[i][j], 0, 0, 0);
        __syncthreads();
    }
    float g = 0.f;
    if (MODE == 1) g = 1.0f / (1.0f + expf(-gate_p[0]));
    const int r0 = (lane >> 4) * 4, c0 = l15;
#pragma unroll
    for (int i = 0; i < 4; ++i) {
#pragma unroll
        for (int j = 0; j < WN; ++j) {
            int col = bcol + wn * (BN / 2) + j * 16 + c0;
#pragma unroll
            for (int r = 0; r < 4; ++r) {
                int row = brow + wm * 64 + i * 16 + r0 + r;
                float v = acc[i][j][r];
                if (MODE == 0) Cb[(size_t)row * N + col] = f2bf(v);
                else Cf[(size_t)row * N + col] = resid[(size_t)row * N + col] + g * v;
            }
        }
    }
}

// ---------------- coarse attention (ND=64 keys, exact softmax, exp2 domain) --------
__global__ __launch_bounds__(256)
void coarse_attn(const u16* __restrict__ q, const u16* __restrict__ kc,
                 const u16* __restrict__ vc, const float* __restrict__ mask,
                 float* __restrict__ doc_part, u16* __restrict__ attn_c) {
    constexpr int SC = 2048 / 64;
    int bid = blockIdx.x;
    int b = bid / (NH * SC);
    int rem = bid % (NH * SC);
    int h = rem / SC, sc = rem % SC;
    int kv = h >> 2;
    int t = threadIdx.x, lane = t & 63, wid = t >> 6;
    const int l15 = lane & 15, k0 = (lane >> 4) * 8;

    __shared__ u16 Kt[64 * 136];
    __shared__ u16 Vt[128 * 72];
    __shared__ u16 Pt[4][16 * 72];
    __shared__ float p_acc[64];

    {   // stage K [64 keys][128 d]
        int n = t >> 2, s2 = t & 3;
        const u16* src = kc + (size_t)(b * 64 + n) * 512 + kv * 128;
#pragma unroll
        for (int u = 0; u < 4; ++u) {
            int sg = s2 + u * 4;
            *reinterpret_cast<uint4*>(&Kt[n * 136 + sg * 8]) =
                *reinterpret_cast<const uint4*>(src + sg * 8);
        }
    }
    {   // stage V transposed: Vt[d][key]
        int n = t & 63, dblk = t >> 6;
        const u16* src = vc + (size_t)(b * 64 + n) * 512 + kv * 128 + dblk * 32;
#pragma unroll
        for (int u = 0; u < 4; ++u) {
            u16 tmp[8];
            *reinterpret_cast<uint4*>(tmp) = *reinterpret_cast<const uint4*>(src + u * 8);
#pragma unroll
            for (int e = 0; e < 8; ++e) Vt[(dblk * 32 + u * 8 + e) * 72 + n] = tmp[e];
        }
    }
    if (t < 64) p_acc[t] = 0.f;
    __syncthreads();

    int qrow = sc * 64 + wid * 16 + l15;
    const u16* qsrc = q + (size_t)(b * 2048 + qrow) * 2048 + h * 128;
    bf16x8 af[4];
#pragma unroll
    for (int kk = 0; kk < 4; ++kk)
        af[kk] = *reinterpret_cast<const bf16x8*>(qsrc + kk * 32 + k0);

    f32x4 sc4[4] = {};
#pragma unroll
    for (int kk = 0; kk < 4; ++kk)
#pragma unroll
        for (int j = 0; j < 4; ++j) {
            bf16x8 bfr = *reinterpret_cast<const bf16x8*>(&Kt[(j * 16 + l15) * 136 + kk * 32 + k0]);
            sc4[j] = __builtin_amdgcn_mfma_f32_16x16x32_bf16(af[kk], bfr, sc4[j], 0, 0, 0);
        }

    float s[4][4];
#pragma unroll
    for (int j = 0; j < 4; ++j) {
        float bia = (1.0f - mask[b * 64 + j * 16 + l15]) * (-1e9f * L2E);
#pragma unroll
        for (int r = 0; r < 4; ++r) s[j][r] = sc4[j][r] * SCALE2 + bia;
    }
    float m4[4], l4[4];
#pragma unroll
    for (int r = 0; r < 4; ++r) {
        float m = fmaxf(fmaxf(s[0][r], s[1][r]), fmaxf(s[2][r], s[3][r]));
#pragma unroll
        for (int d = 1; d < 16; d <<= 1) m = fmaxf(m, __shfl_xor(m, d));
        m4[r] = m;
    }
#pragma unroll
    for (int r = 0; r < 4; ++r) {
        float l = 0.f;
#pragma unroll
        for (int j = 0; j < 4; ++j) { s[j][r] = exp2f(s[j][r] - m4[r]); l += s[j][r]; }
#pragma unroll
        for (int d = 1; d < 16; d <<= 1) l += __shfl_xor(l, d);
        l4[r] = l;
    }
#pragma unroll
    for (int j = 0; j < 4; ++j) {
        float cs = 0.f;
#pragma unroll
        for (int r = 0; r < 4; ++r) {
            float pr = s[j][r] / l4[r];
            Pt[wid][((lane >> 4) * 4 + r) * 72 + j * 16 + l15] = f2bf(pr);
            cs += pr;
        }
        cs += __shfl_xor(cs, 16);
        cs += __shfl_xor(cs, 32);
        if (lane < 16) atomicAdd(&p_acc[j * 16 + lane], cs);
    }
    __syncthreads();

    f32x4 o4[8] = {};
#pragma unroll
    for (int kk2 = 0; kk2 < 2; ++kk2) {
        bf16x8 a2 = *reinterpret_cast<const bf16x8*>(&Pt[wid][l15 * 72 + kk2 * 32 + k0]);
#pragma unroll
        for (int j2 = 0; j2 < 8; ++j2) {
            bf16x8 b2 = *reinterpret_cast<const bf16x8*>(&Vt[(j2 * 16 + l15) * 72 + kk2 * 32 + k0]);
            o4[j2] = __builtin_amdgcn_mfma_f32_16x16x32_bf16(a2, b2, o4[j2], 0, 0, 0);
        }
    }
#pragma unroll
    for (int j2 = 0; j2 < 8; ++j2)
#pragma unroll
        for (int r = 0; r < 4; ++r) {
            int row = sc * 64 + wid * 16 + (lane >> 4) * 4 + r;
            attn_c[(size_t)(b * 2048 + row) * 2048 + h * 128 + j2 * 16 + l15] = f2bf(o4[j2][r]);
        }
    if (t < 64) atomicAdd(&doc_part[(blockIdx.x & 7) * 128 + b * 64 + t], p_acc[t]);
}

// ---------------- doc-score finalize + fine bias (bias pre-scaled by log2e) --------
__global__ void doc_finalize(const float* __restrict__ doc_part, float* __restrict__ log_ds) {
    int t = threadIdx.x; // 128
    float s = 0.f;
#pragma unroll
    for (int i = 0; i < 8; ++i) s += doc_part[i * 128 + t];
    log_ds[t] = logf(s / 32768.0f + 1e-6f);
}

__global__ __launch_bounds__(256)
void bias_kernel(const float* __restrict__ log_ds, const int* __restrict__ map,
                 const float* __restrict__ tmask, float* __restrict__ bias) {
    int i = blockIdx.x * 256 + threadIdx.x;
    if (i >= 2 * 2048) return;
    int b = i >> 11;
    bias[i] = (log_ds[b * 64 + map[i]] + (1.0f - tmask[i]) * -1e9f) * L2E;
}

// ---------------- fine flash attention v4 (exp2 domain, double-buffered) ----------
// KVBLK=64, swapped QK^T, defer-max; 2-phase pipeline: next tile's
// global_load_lds issued BEFORE current compute, single barrier per tile
// (compiler drains vmcnt at __syncthreads). T3 minimum recipe.
__global__ __launch_bounds__(256)
void flash_attn(const u16* __restrict__ q, const u16* __restrict__ kf,
                const u16* __restrict__ vT, const float* __restrict__ bias,
                u16* __restrict__ attn_f) {
    int bid = blockIdx.x;
    int b = bid >> 9;              // NH * 32 = 512 blocks per batch
    int rem = bid & 511;
    int h = rem >> 5, sc = rem & 31;
    int kv = h >> 2;
    int t = threadIdx.x, lane = t & 63, wid = t >> 6;
    const int l15 = lane & 15, hi = lane >> 4;
    const int k0 = hi * 8;

    __shared__ u16 Kt[2][64 * 128];    // [key][d] linear, swizzled 16B slots
    __shared__ u16 Vt[2][128 * 64];    // [d][key] linear, swizzled 16B slots
    __shared__ u16 Pt[4][16 * 72];     // per-wave P[q][key], pad 8
    __shared__ float bias_s[2][64];

    int qrow = sc * 64 + wid * 16 + l15;
    const u16* qsrc = q + (size_t)(b * 2048 + qrow) * 2048 + h * 128;
    bf16x8 qf4[4];
#pragma unroll
    for (int kk = 0; kk < 4; ++kk)
        qf4[kk] = *reinterpret_cast<const bf16x8*>(qsrc + kk * 32 + k0);

    // staging lane roles (constant over tiles)
    const int krl = lane >> 4, kslot = lane & 15;   // K: 4 rows x 16 slots per 1KB
    const int vrl = lane >> 3, vslot = lane & 7;    // V: 8 rows x 8 slots per 1KB
    const u16* kbase = kf + (size_t)(b * 2048) * 512 + kv * 128;
    const u16* vbase = vT + (size_t)(kv * 128) * 4096 + b * 2048;

#define STAGE_TILE(TT, BUF)                                                        \
    do {                                                                           \
        _Pragma("unroll")                                                          \
        for (int u = 0; u < 4; ++u) {                                              \
            int row = wid * 16 + u * 4 + krl;                                      \
            const u16* src = kbase + (size_t)((TT) + row) * 512                    \
                             + ((kslot ^ (row & 7)) * 8);                          \
            GLD_LDS16(src, &Kt[BUF][(wid * 16 + u * 4) * 128]);                    \
        }                                                                          \
        _Pragma("unroll")                                                          \
        for (int u = 0; u < 4; ++u) {                                              \
            int row = wid * 32 + u * 8 + vrl;                                      \
            const u16* src = vbase + (size_t)row * 4096 + (TT)                     \
                             + ((vslot ^ (row & 7)) * 8);                          \
            GLD_LDS16(src, &Vt[BUF][(wid * 32 + u * 8) * 64]);                     \
        }                                                                          \
        if (t < 64) bias_s[BUF][t] = bias[b * 2048 + (TT) + t];                    \
    } while (0)

    float mstate = -1e30f, lstate = 0.f;   // mstate in log2 domain
    f32x4 o4[8] = {};

    STAGE_TILE(0, 0);
    __syncthreads();
    int cur = 0;

    for (int t0 = 0; t0 < 2048; t0 += 64) {
        int t1 = (t0 + 64) & 2047;          // wrap-around prefetch (last iter harmless)
        STAGE_TILE(t1, cur ^ 1);

        // QK^T swapped: S^T[key][q] = K-frag (A) x Q-frag (B)
        f32x4 st[4] = {};
#pragma unroll
        for (int kk = 0; kk < 4; ++kk)
#pragma unroll
            for (int kb = 0; kb < 4; ++kb) {
                int row = kb * 16 + l15;
                bf16x8 kfrag = *reinterpret_cast<const bf16x8*>(
                    &Kt[cur][row * 128 + (((kk * 4 + hi) ^ (row & 7)) * 8)]);
                st[kb] = __builtin_amdgcn_mfma_f32_16x16x32_bf16(kfrag, qf4[kk], st[kb], 0, 0, 0);
            }

        // per-lane: q = l15, keys = kb*16 + hi*4 + r ; all in log2 domain
        float p[4][4];
        float pmax = -1e30f;
#pragma unroll
        for (int kb = 0; kb < 4; ++kb) {
            float4 b4 = *reinterpret_cast<const float4*>(&bias_s[cur][kb * 16 + hi * 4]);
            float bb[4] = {b4.x, b4.y, b4.z, b4.w};
#pragma unroll
            for (int r = 0; r < 4; ++r) {
                float v = st[kb][r] * SCALE2 + bb[r];
                p[kb][r] = v;
                pmax = fmaxf(pmax, v);
            }
        }
        pmax = fmaxf(pmax, __shfl_xor(pmax, 16));
        pmax = fmaxf(pmax, __shfl_xor(pmax, 32));

        // defer-max (T13): only rescale when the tile max grew past THR
        if (!__all(pmax <= mstate + THR2)) {
            float mnew = fmaxf(mstate, pmax);
            float sco = exp2f(mstate - mnew);
            float sco_out[4];
#pragma unroll
            for (int r = 0; r < 4; ++r) sco_out[r] = __shfl(sco, hi * 4 + r);
#pragma unroll
            for (int j2 = 0; j2 < 8; ++j2)
#pragma unroll
                for (int r = 0; r < 4; ++r) o4[j2][r] *= sco_out[r];
            lstate *= sco;
            mstate = mnew;
        }

        float lt = 0.f;
#pragma unroll
        for (int kb = 0; kb < 4; ++kb)
#pragma unroll
            for (int r = 0; r < 4; ++r) {
                p[kb][r] = exp2f(p[kb][r] - mstate);
                lt += p[kb][r];
            }
        lt += __shfl_xor(lt, 16);
        lt += __shfl_xor(lt, 32);
        lstate += lt;

        // write P[q][key] (per-wave buffer; same-wave DS ordering)
#pragma unroll
        for (int kb = 0; kb < 4; ++kb) {
            uint2 w;
            w.x = pack2_cvt(p[kb][0], p[kb][1]);
            w.y = pack2_cvt(p[kb][2], p[kb][3]);
            *reinterpret_cast<uint2*>(&Pt[wid][l15 * 72 + kb * 16 + hi * 4]) = w;
        }

        // PV: O[q][d] += P (A) x V^T-frag (B)
#pragma unroll
        for (int kc = 0; kc < 2; ++kc) {
            bf16x8 pa = *reinterpret_cast<const bf16x8*>(&Pt[wid][l15 * 72 + kc * 32 + k0]);
#pragma unroll
            for (int j2 = 0; j2 < 8; ++j2) {
                int d = j2 * 16 + l15;
                bf16x8 vb = *reinterpret_cast<const bf16x8*>(
                    &Vt[cur][d * 64 + (((kc * 4 + hi) ^ (d & 7)) * 8)]);
                o4[j2] = __builtin_amdgcn_mfma_f32_16x16x32_bf16(pa, vb, o4[j2], 0, 0, 0);
            }
        }
        __syncthreads();   // drains my prefetch (vmcnt) + all waves done with buf[cur]
        cur ^= 1;
    }
#undef STAGE_TILE

    // l is in softmax layout (q = l15); outputs need q = hi*4+r
    float linv[4];
#pragma unroll
    for (int r = 0; r < 4; ++r) linv[r] = 1.0f / __shfl(lstate, hi * 4 + r);
#pragma unroll
    for (int j2 = 0; j2 < 8; ++j2)
#pragma unroll
        for (int r = 0; r < 4; ++r) {
            int row = sc * 64 + wid * 16 + hi * 4 + r;
            attn_f[(size_t)(b * 2048 + row) * 2048 + h * 128 + j2 * 16 + l15] =
                f2bf(o4[j2][r] * linv[r]);
        }
}

// ---------------- launch ----------------
extern "C" void kernel_launch(void* const* d_in, const int* in_sizes, int n_in,
                              void* d_out, int out_size, void* d_ws, size_t ws_size,
                              hipStream_t stream) {
    const float* hidden = (const float*)d_in[0];
    const float* dsk    = (const float*)d_in[1];
    const float* dsv    = (const float*)d_in[2];
    const float* dsmask = (const float*)d_in[3];
    const float* tk     = (const float*)d_in[4];
    const float* tv     = (const float*)d_in[5];
    const float* tmask  = (const float*)d_in[6];
    const float* cn_w   = (const float*)d_in[7];
    const float* cq_w   = (const float*)d_in[8];
    const float* ck_w   = (const float*)d_in[9];
    const float* cv_w   = (const float*)d_in[10];
    const float* co_w   = (const float*)d_in[11];
    const float* c_gate = (const float*)d_in[12];
    const float* fn_w   = (const float*)d_in[13];
    const float* fq_w   = (const float*)d_in[14];
    const float* fk_w   = (const float*)d_in[15];
    const float* fv_w   = (const float*)d_in[16];
    const float* fo_w   = (const float*)d_in[17];
    const float* f_gate = (const float*)d_in[18];
    const int*   map    = (const int*)d_in[19];
    float* out_f = (float*)d_out;   // also the f32 buffer for coarse residual

    char* ws = (char*)d_ws;
    size_t off = 0;
    auto alloc = [&](size_t bytes) {
        char* p = ws + off;
        off += (bytes + 255) & ~(size_t)255;
        return p;
    };
    u16*  normA = (u16*)alloc(4096ULL * 2048 * 2);
    u16*  qbuf  = (u16*)alloc(4096ULL * 2048 * 2);
    u16*  kc    = (u16*)alloc(128ULL * 512 * 2);
    u16*  vc    = (u16*)alloc(128ULL * 512 * 2);
    u16*  dskb  = (u16*)alloc(128ULL * 2048 * 2);
    u16*  dsvb  = (u16*)alloc(128ULL * 2048 * 2);
    u16*  kfb   = (u16*)alloc(4096ULL * 512 * 2);
    u16*  vTb   = (u16*)alloc(512ULL * 4096 * 2);   // V^T [kv*128+d][b*2048+t]
    u16*  cqT   = (u16*)alloc(2048ULL * 2048 * 2);
    u16*  ckT   = (u16*)alloc(512ULL * 2048 * 2);
    u16*  cvT   = (u16*)alloc(512ULL * 2048 * 2);
    u16*  coT   = (u16*)alloc(2048ULL * 2048 * 2);
    u16*  fqT   = (u16*)alloc(2048ULL * 2048 * 2);
    u16*  fkT   = (u16*)alloc(512ULL * 2048 * 2);
    u16*  fvT   = (u16*)alloc(512ULL * 2048 * 2);
    u16*  foT   = (u16*)alloc(2048ULL * 2048 * 2);
    float* doc_part = (float*)alloc(8 * 128 * 4);
    float* log_ds   = (float*)alloc(128 * 4);
    float* biasb    = (float*)alloc(4096 * 4);

    hipMemsetAsync(doc_part, 0, 8 * 128 * 4, stream);

    // weight transposes (f32 [K=2048][N] -> bf16 [N][2048])
    transpose_cvt<<<dim3(64, 64), 256, 0, stream>>>(cq_w, cqT, 2048, 2048);
    transpose_cvt<<<dim3(16, 64), 256, 0, stream>>>(ck_w, ckT, 2048, 512);
    transpose_cvt<<<dim3(16, 64), 256, 0, stream>>>(cv_w, cvT, 2048, 512);
    transpose_cvt<<<dim3(64, 64), 256, 0, stream>>>(co_w, coT, 2048, 2048);
    transpose_cvt<<<dim3(64, 64), 256, 0, stream>>>(fq_w, fqT, 2048, 2048);
    transpose_cvt<<<dim3(16, 64), 256, 0, stream>>>(fk_w, fkT, 2048, 512);
    transpose_cvt<<<dim3(16, 64), 256, 0, stream>>>(fv_w, fvT, 2048, 512);
    transpose_cvt<<<dim3(64, 64), 256, 0, stream>>>(fo_w, foT, 2048, 2048);

    cvt_f32_bf16<<<(128 * 2048 / 4 + 255) / 256, 256, 0, stream>>>(dsk, dskb, 128 * 2048 / 4);
    cvt_f32_bf16<<<(128 * 2048 / 4 + 255) / 256, 256, 0, stream>>>(dsv, dsvb, 128 * 2048 / 4);
    rmsnorm_kernel<<<4096, 256, 0, stream>>>(hidden, cn_w, normA);

    // coarse projections
    gemm_tn<0, 128><<<dim3(16, 32), 256, 0, stream>>>(normA, cqT, qbuf, nullptr, nullptr, nullptr, 4096, 2048, 2048);
    gemm_tn<0, 64><<<dim3(8, 1), 256, 0, stream>>>(dskb, ckT, kc, nullptr, nullptr, nullptr, 128, 512, 2048);
    gemm_tn<0, 64><<<dim3(8, 1), 256, 0, stream>>>(dsvb, cvT, vc, nullptr, nullptr, nullptr, 128, 512, 2048);

    // coarse attention (attn_c into normA) + doc-score partials
    coarse_attn<<<1024, 256, 0, stream>>>(qbuf, kc, vc, dsmask, doc_part, normA);
    doc_finalize<<<1, 128, 0, stream>>>(doc_part, log_ds);
    bias_kernel<<<16, 256, 0, stream>>>(log_ds, map, tmask, biasb);

    // coarse o-proj + residual + gate -> d_out (f32)
    gemm_tn<1, 128><<<dim3(16, 32), 256, 0, stream>>>(normA, coT, nullptr, out_f, hidden, c_gate, 4096, 2048, 2048);

    // fine stage
    rmsnorm_kernel<<<4096, 256, 0, stream>>>(out_f, fn_w, qbuf);
    gemm_tn<0, 128><<<dim3(16, 32), 256, 0, stream>>>(qbuf, fqT, normA, nullptr, nullptr, nullptr, 4096, 2048, 2048);
    cvt_f32_bf16<<<(4096 * 2048 / 4 + 255) / 256, 256, 0, stream>>>(tk, qbuf, 4096 * 2048 / 4);
    gemm_tn<0, 64><<<dim3(8, 32), 256, 0, stream>>>(qbuf, fkT, kfb, nullptr, nullptr, nullptr, 4096, 512, 2048);
    cvt_f32_bf16<<<(4096 * 2048 / 4 + 255) / 256, 256, 0, stream>>>(tv, qbuf, 4096 * 2048 / 4);
    // V^T directly from the projection: vT[d][token] = fvT[d][:] . tv[token][:]
    gemm_tn<0, 64><<<dim3(64, 4), 256, 0, stream>>>(fvT, qbuf, vTb, nullptr, nullptr, nullptr, 512, 4096, 2048);

    flash_attn<<<1024, 256, 0, stream>>>(normA, kfb, vTb, biasb, qbuf);

    // final o-proj + residual + gate -> d_out
    gemm_tn<1, 128><<<dim3(16, 32), 256, 0, stream>>>(qbuf, foT, nullptr, out_f, out_f, f_gate, 4096, 2048, 2048);
}

// Round 7
// 568.932 us; speedup vs baseline: 1.8144x; 1.0734x over previous
//
#include <hip/hip_runtime.h>
#include <hip/hip_bf16.h>

typedef unsigned short u16;
typedef unsigned int u32;
typedef __attribute__((ext_vector_type(8))) short bf16x8;
typedef __attribute__((ext_vector_type(4))) float f32x4;

constexpr int NH = 16;
constexpr int H = 2048;
constexpr float SCALE = 0.08838834764831845f;   // 1/sqrt(128)
constexpr float L2E = 1.4426950408889634f;      // log2(e)
constexpr float SCALE2 = SCALE * L2E;           // QK scale in log2 domain
constexpr float THR2 = 8.0f * L2E;              // defer-max threshold (log2 units)

__device__ __forceinline__ u16 f2bf(float f) {
    u32 u = __float_as_uint(f);
    u32 r = u + 0x7fffu + ((u >> 16) & 1u);   // RNE (finite inputs only)
    return (u16)(r >> 16);
}
__device__ __forceinline__ u32 pack2(float x, float y) {
    return (u32)f2bf(x) | ((u32)f2bf(y) << 16);
}
__device__ __forceinline__ u32 pack2_cvt(float x, float y) {
    __hip_bfloat162 h = __float22bfloat162_rn(float2{x, y});
    return *reinterpret_cast<u32*>(&h);
}

#define GLD_LDS16(gsrc, ldst)                                                  \
    __builtin_amdgcn_global_load_lds(                                          \
        (const __attribute__((address_space(1))) void*)(gsrc),                 \
        (__attribute__((address_space(3))) void*)(ldst), 16, 0, 0)

// ---------------- f32 -> bf16 convert (vectorized) ----------------
__global__ __launch_bounds__(256) void cvt_f32_bf16(const float* __restrict__ in,
                                                    u16* __restrict__ out, int n4) {
    int i = blockIdx.x * 256 + threadIdx.x;
    if (i >= n4) return;
    float4 v = reinterpret_cast<const float4*>(in)[i];
    uint2 o;
    o.x = pack2(v.x, v.y);
    o.y = pack2(v.z, v.w);
    reinterpret_cast<uint2*>(out)[i] = o;
}

// ---------------- weight transpose + convert: f32[K][N] -> bf16[N][K] ----------------
__global__ __launch_bounds__(256)
void transpose_cvt(const float* __restrict__ in, u16* __restrict__ out, int K, int N) {
    __shared__ u16 tile[32][33];
    int bn = blockIdx.x * 32, bk = blockIdx.y * 32;
    int tx = threadIdx.x & 31, ty = threadIdx.x >> 5;  // ty 0..7
#pragma unroll
    for (int r = 0; r < 32; r += 8)
        tile[tx][r + ty] = f2bf(in[(size_t)(bk + r + ty) * N + bn + tx]);
    __syncthreads();
#pragma unroll
    for (int r = 0; r < 32; r += 8)
        out[(size_t)(bn + r + ty) * K + bk + tx] = tile[r + ty][tx];
}

// ---------------- RMSNorm f32 -> bf16, H=2048, one block per row ----------------
__global__ __launch_bounds__(256) void rmsnorm_kernel(const float* __restrict__ x,
                                                      const float* __restrict__ w,
                                                      u16* __restrict__ y) {
    int r = blockIdx.x;
    const float4* xr = reinterpret_cast<const float4*>(x + (size_t)r * H);
    int t = threadIdx.x;
    float4 v0 = xr[t * 2], v1 = xr[t * 2 + 1];
    float ss = v0.x * v0.x + v0.y * v0.y + v0.z * v0.z + v0.w * v0.w
             + v1.x * v1.x + v1.y * v1.y + v1.z * v1.z + v1.w * v1.w;
#pragma unroll
    for (int d = 1; d < 64; d <<= 1) ss += __shfl_xor(ss, d);
    __shared__ float red[4];
    if ((t & 63) == 0) red[t >> 6] = ss;
    __syncthreads();
    float tot = red[0] + red[1] + red[2] + red[3];
    float rs = rsqrtf(tot * (1.0f / H) + 1e-6f);
    const float4* wr = reinterpret_cast<const float4*>(w);
    float4 w0 = wr[t * 2], w1 = wr[t * 2 + 1];
    uint4 o;
    o.x = pack2(v0.x * rs * w0.x, v0.y * rs * w0.y);
    o.y = pack2(v0.z * rs * w0.z, v0.w * rs * w0.w);
    o.z = pack2(v1.x * rs * w1.x, v1.y * rs * w1.y);
    o.w = pack2(v1.z * rs * w1.z, v1.w * rs * w1.w);
    reinterpret_cast<uint4*>(y + (size_t)r * H)[t] = o;
}

// ---------------- GEMM (m97 structure): C[M,N] = A_bf16[M,K] @ Bt_bf16[N,K]^T --------
// MODE 0: store bf16 C.  MODE 1: Cf = resid + sigmoid(*gate_p) * acc (f32 out).
// BN: 128 (big GEMMs) or 64 (thin GEMMs -> 2x grid for full-chip occupancy).
template <int MODE, int BN>
__global__ __launch_bounds__(256)
void gemm_tn(const u16* __restrict__ A, const u16* __restrict__ Bt,
             u16* __restrict__ Cb, float* __restrict__ Cf,
             const float* __restrict__ resid, const float* __restrict__ gate_p,
             int M, int N, int K) {
    constexpr int WN = BN / 32;          // N frags per wave: 4 or 2
    __shared__ u16 As[128 * 32];
    __shared__ u16 Bs[BN * 32];
    const int t = threadIdx.x;
    const int lane = t & 63, wid = t >> 6;
    const int wm = wid >> 1, wn = wid & 1;
    const int brow = blockIdx.y * 128, bcol = blockIdx.x * BN;
    const int l15 = lane & 15;
    const int k0 = (lane >> 4) * 8;

    f32x4 acc[4][WN] = {};
    const int srow = lane >> 2, sseg = (lane & 3) * 8;
    const u16* aBase = A + (size_t)(brow + wid * 32 + srow) * K + sseg;
    u16* aD0 = As + (wid * 32) * 32;
    u16* aD1 = As + (wid * 32 + 16) * 32;
    const size_t row16 = (size_t)16 * K;
    const u16* bBase;
    u16 *bD0, *bD1 = nullptr;
    if constexpr (BN == 128) {
        bBase = Bt + (size_t)(bcol + wid * 32 + srow) * K + sseg;
        bD0 = Bs + (wid * 32) * 32;
        bD1 = Bs + (wid * 32 + 16) * 32;
    } else {
        bBase = Bt + (size_t)(bcol + wid * 16 + srow) * K + sseg;
        bD0 = Bs + (wid * 16) * 32;
    }

    for (int kt = 0; kt < K; kt += 32) {
        GLD_LDS16(aBase + kt, aD0);
        GLD_LDS16(aBase + kt + row16, aD1);
        GLD_LDS16(bBase + kt, bD0);
        if constexpr (BN == 128) GLD_LDS16(bBase + kt + row16, bD1);
        __syncthreads();
        bf16x8 af[4], bfr[WN];
#pragma unroll
        for (int i = 0; i < 4; ++i)
            af[i] = *reinterpret_cast<const bf16x8*>(&As[(wm * 64 + i * 16 + l15) * 32 + k0]);
#pragma unroll
        for (int j = 0; j < WN; ++j)
            bfr[j] = *reinterpret_cast<const bf16x8*>(&Bs[(wn * (BN / 2) + j * 16 + l15) * 32 + k0]);
#pragma unroll
        for (int i = 0; i < 4; ++i)
#pragma unroll
            for (int j = 0; j < WN; ++j)
                acc[i][j] = __builtin_amdgcn_mfma_f32_16x16x32_bf16(af[i], bfr[j], acc[i][j], 0, 0, 0);
        __syncthreads();
    }
    float g = 0.f;
    if (MODE == 1) g = 1.0f / (1.0f + expf(-gate_p[0]));
    const int r0 = (lane >> 4) * 4, c0 = l15;
#pragma unroll
    for (int i = 0; i < 4; ++i) {
#pragma unroll
        for (int j = 0; j < WN; ++j) {
            int col = bcol + wn * (BN / 2) + j * 16 + c0;
#pragma unroll
            for (int r = 0; r < 4; ++r) {
                int row = brow + wm * 64 + i * 16 + r0 + r;
                float v = acc[i][j][r];
                if (MODE == 0) Cb[(size_t)row * N + col] = f2bf(v);
                else Cf[(size_t)row * N + col] = resid[(size_t)row * N + col] + g * v;
            }
        }
    }
}

// ---------------- coarse attention (ND=64 keys, exact softmax, exp2 domain) --------
__global__ __launch_bounds__(256)
void coarse_attn(const u16* __restrict__ q, const u16* __restrict__ kc,
                 const u16* __restrict__ vc, const float* __restrict__ mask,
                 float* __restrict__ doc_part, u16* __restrict__ attn_c) {
    constexpr int SC = 2048 / 64;
    int bid = blockIdx.x;
    int b = bid / (NH * SC);
    int rem = bid % (NH * SC);
    int h = rem / SC, sc = rem % SC;
    int kv = h >> 2;
    int t = threadIdx.x, lane = t & 63, wid = t >> 6;
    const int l15 = lane & 15, k0 = (lane >> 4) * 8;

    __shared__ u16 Kt[64 * 136];
    __shared__ u16 Vt[128 * 72];
    __shared__ u16 Pt[4][16 * 72];
    __shared__ float p_acc[64];

    {   // stage K [64 keys][128 d]
        int n = t >> 2, s2 = t & 3;
        const u16* src = kc + (size_t)(b * 64 + n) * 512 + kv * 128;
#pragma unroll
        for (int u = 0; u < 4; ++u) {
            int sg = s2 + u * 4;
            *reinterpret_cast<uint4*>(&Kt[n * 136 + sg * 8]) =
                *reinterpret_cast<const uint4*>(src + sg * 8);
        }
    }
    {   // stage V transposed: Vt[d][key]
        int n = t & 63, dblk = t >> 6;
        const u16* src = vc + (size_t)(b * 64 + n) * 512 + kv * 128 + dblk * 32;
#pragma unroll
        for (int u = 0; u < 4; ++u) {
            u16 tmp[8];
            *reinterpret_cast<uint4*>(tmp) = *reinterpret_cast<const uint4*>(src + u * 8);
#pragma unroll
            for (int e = 0; e < 8; ++e) Vt[(dblk * 32 + u * 8 + e) * 72 + n] = tmp[e];
        }
    }
    if (t < 64) p_acc[t] = 0.f;
    __syncthreads();

    int qrow = sc * 64 + wid * 16 + l15;
    const u16* qsrc = q + (size_t)(b * 2048 + qrow) * 2048 + h * 128;
    bf16x8 af[4];
#pragma unroll
    for (int kk = 0; kk < 4; ++kk)
        af[kk] = *reinterpret_cast<const bf16x8*>(qsrc + kk * 32 + k0);

    f32x4 sc4[4] = {};
#pragma unroll
    for (int kk = 0; kk < 4; ++kk)
#pragma unroll
        for (int j = 0; j < 4; ++j) {
            bf16x8 bfr = *reinterpret_cast<const bf16x8*>(&Kt[(j * 16 + l15) * 136 + kk * 32 + k0]);
            sc4[j] = __builtin_amdgcn_mfma_f32_16x16x32_bf16(af[kk], bfr, sc4[j], 0, 0, 0);
        }

    float s[4][4];
#pragma unroll
    for (int j = 0; j < 4; ++j) {
        float bia = (1.0f - mask[b * 64 + j * 16 + l15]) * (-1e9f * L2E);
#pragma unroll
        for (int r = 0; r < 4; ++r) s[j][r] = sc4[j][r] * SCALE2 + bia;
    }
    float m4[4], l4[4];
#pragma unroll
    for (int r = 0; r < 4; ++r) {
        float m = fmaxf(fmaxf(s[0][r], s[1][r]), fmaxf(s[2][r], s[3][r]));
#pragma unroll
        for (int d = 1; d < 16; d <<= 1) m = fmaxf(m, __shfl_xor(m, d));
        m4[r] = m;
    }
#pragma unroll
    for (int r = 0; r < 4; ++r) {
        float l = 0.f;
#pragma unroll
        for (int j = 0; j < 4; ++j) { s[j][r] = exp2f(s[j][r] - m4[r]); l += s[j][r]; }
#pragma unroll
        for (int d = 1; d < 16; d <<= 1) l += __shfl_xor(l, d);
        l4[r] = l;
    }
#pragma unroll
    for (int j = 0; j < 4; ++j) {
        float cs = 0.f;
#pragma unroll
        for (int r = 0; r < 4; ++r) {
            float pr = s[j][r] / l4[r];
            Pt[wid][((lane >> 4) * 4 + r) * 72 + j * 16 + l15] = f2bf(pr);
            cs += pr;
        }
        cs += __shfl_xor(cs, 16);
        cs += __shfl_xor(cs, 32);
        if (lane < 16) atomicAdd(&p_acc[j * 16 + lane], cs);
    }
    __syncthreads();

    f32x4 o4[8] = {};
#pragma unroll
    for (int kk2 = 0; kk2 < 2; ++kk2) {
        bf16x8 a2 = *reinterpret_cast<const bf16x8*>(&Pt[wid][l15 * 72 + kk2 * 32 + k0]);
#pragma unroll
        for (int j2 = 0; j2 < 8; ++j2) {
            bf16x8 b2 = *reinterpret_cast<const bf16x8*>(&Vt[(j2 * 16 + l15) * 72 + kk2 * 32 + k0]);
            o4[j2] = __builtin_amdgcn_mfma_f32_16x16x32_bf16(a2, b2, o4[j2], 0, 0, 0);
        }
    }
#pragma unroll
    for (int j2 = 0; j2 < 8; ++j2)
#pragma unroll
        for (int r = 0; r < 4; ++r) {
            int row = sc * 64 + wid * 16 + (lane >> 4) * 4 + r;
            attn_c[(size_t)(b * 2048 + row) * 2048 + h * 128 + j2 * 16 + l15] = f2bf(o4[j2][r]);
        }
    if (t < 64) atomicAdd(&doc_part[(blockIdx.x & 7) * 128 + b * 64 + t], p_acc[t]);
}

// ---------------- doc-score finalize + fine bias (bias pre-scaled by log2e) --------
__global__ void doc_finalize(const float* __restrict__ doc_part, float* __restrict__ log_ds) {
    int t = threadIdx.x; // 128
    float s = 0.f;
#pragma unroll
    for (int i = 0; i < 8; ++i) s += doc_part[i * 128 + t];
    log_ds[t] = logf(s / 32768.0f + 1e-6f);
}

__global__ __launch_bounds__(256)
void bias_kernel(const float* __restrict__ log_ds, const int* __restrict__ map,
                 const float* __restrict__ tmask, float* __restrict__ bias) {
    int i = blockIdx.x * 256 + threadIdx.x;
    if (i >= 2 * 2048) return;
    int b = i >> 11;
    bias[i] = (log_ds[b * 64 + map[i]] + (1.0f - tmask[i]) * -1e9f) * L2E;
}

// ---------------- fine flash attention v5 (exp2 domain, QBLK=32/wave) --------------
// 512 blocks, 4 waves x 32 q-rows = 128 q/block. Each K/V LDS fragment read
// feeds TWO MFMAs (2 q-frags in registers) -> LDS cycles per q-row halved.
// Single-buffered staging (r6 dbuf cost occupancy: 75KB -> 2 blocks/CU).
__global__ __launch_bounds__(256, 2)
void flash_attn(const u16* __restrict__ q, const u16* __restrict__ kf,
                const u16* __restrict__ vT, const float* __restrict__ bias,
                u16* __restrict__ attn_f) {
    int bid = blockIdx.x;
    int b = bid >> 8;              // NH * 16 = 256 blocks per batch
    int rem = bid & 255;
    int h = rem >> 4, sc = rem & 15;
    int kv = h >> 2;
    int t = threadIdx.x, lane = t & 63, wid = t >> 6;
    const int l15 = lane & 15, hi = lane >> 4;
    const int k0 = hi * 8;

    __shared__ u16 Kt[64 * 128];       // [key][d] linear, swizzled 16B slots
    __shared__ u16 Vt[128 * 64];       // [d][key] linear, swizzled 16B slots
    __shared__ u16 Pt[4][32 * 72];     // per-wave P[32 q][64 key], pad 8
    __shared__ float bias_s[64];

    // Q fragments: 2 q-frags of 16 rows each; wave rows = sc*128 + wid*32 + f*16 + l15
    bf16x8 qf4[2][4];
#pragma unroll
    for (int f = 0; f < 2; ++f) {
        int qrow = sc * 128 + wid * 32 + f * 16 + l15;
        const u16* qsrc = q + (size_t)(b * 2048 + qrow) * 2048 + h * 128;
#pragma unroll
        for (int kk = 0; kk < 4; ++kk)
            qf4[f][kk] = *reinterpret_cast<const bf16x8*>(qsrc + kk * 32 + k0);
    }

    // staging lane roles (constant over tiles)
    const int krl = lane >> 4, kslot = lane & 15;   // K: 4 rows x 16 slots per 1KB
    const int vrl = lane >> 3, vslot = lane & 7;    // V: 8 rows x 8 slots per 1KB
    const u16* kbase = kf + (size_t)(b * 2048) * 512 + kv * 128;
    const u16* vbase = vT + (size_t)(kv * 128) * 4096 + b * 2048;

    float mstate[2] = {-1e30f, -1e30f}, lstate[2] = {0.f, 0.f};   // log2 domain
    f32x4 o4[2][8] = {};

    for (int t0 = 0; t0 < 2048; t0 += 64) {
        // stage K: wave wid covers keys [wid*16, wid*16+16)
#pragma unroll
        for (int u = 0; u < 4; ++u) {
            int row = wid * 16 + u * 4 + krl;
            const u16* src = kbase + (size_t)(t0 + row) * 512 + ((kslot ^ (row & 7)) * 8);
            GLD_LDS16(src, &Kt[(wid * 16 + u * 4) * 128]);
        }
        // stage V^T: wave wid covers d in [wid*32, wid*32+32)
#pragma unroll
        for (int u = 0; u < 4; ++u) {
            int row = wid * 32 + u * 8 + vrl;
            const u16* src = vbase + (size_t)row * 4096 + t0 + ((vslot ^ (row & 7)) * 8);
            GLD_LDS16(src, &Vt[(wid * 32 + u * 8) * 64]);
        }
        if (t < 64) bias_s[t] = bias[b * 2048 + t0 + t];
        __syncthreads();

        // QK^T swapped: S^T[key][q] = K-frag (A) x Q-frag (B); each K-frag feeds 2 MFMAs
        f32x4 st0[4] = {}, st1[4] = {};
#pragma unroll
        for (int kk = 0; kk < 4; ++kk)
#pragma unroll
            for (int kb = 0; kb < 4; ++kb) {
                int row = kb * 16 + l15;
                bf16x8 kfrag = *reinterpret_cast<const bf16x8*>(
                    &Kt[row * 128 + (((kk * 4 + hi) ^ (row & 7)) * 8)]);
                st0[kb] = __builtin_amdgcn_mfma_f32_16x16x32_bf16(kfrag, qf4[0][kk], st0[kb], 0, 0, 0);
                st1[kb] = __builtin_amdgcn_mfma_f32_16x16x32_bf16(kfrag, qf4[1][kk], st1[kb], 0, 0, 0);
            }

        // per-lane: q = f*16 + l15, keys = kb*16 + hi*4 + r ; log2 domain
        float p[2][4][4];
        float pmax[2] = {-1e30f, -1e30f};
#pragma unroll
        for (int kb = 0; kb < 4; ++kb) {
            float4 b4 = *reinterpret_cast<const float4*>(&bias_s[kb * 16 + hi * 4]);
            float bb[4] = {b4.x, b4.y, b4.z, b4.w};
#pragma unroll
            for (int r = 0; r < 4; ++r) {
                float v0 = st0[kb][r] * SCALE2 + bb[r];
                float v1 = st1[kb][r] * SCALE2 + bb[r];
                p[0][kb][r] = v0;
                p[1][kb][r] = v1;
                pmax[0] = fmaxf(pmax[0], v0);
                pmax[1] = fmaxf(pmax[1], v1);
            }
        }
#pragma unroll
        for (int f = 0; f < 2; ++f) {
            pmax[f] = fmaxf(pmax[f], __shfl_xor(pmax[f], 16));
            pmax[f] = fmaxf(pmax[f], __shfl_xor(pmax[f], 32));
        }

        // defer-max (T13): combined branch; rescale both frags when either needs it
        bool need = (pmax[0] > mstate[0] + THR2) || (pmax[1] > mstate[1] + THR2);
        if (__any(need)) {
#pragma unroll
            for (int f = 0; f < 2; ++f) {
                float mnew = fmaxf(mstate[f], pmax[f]);
                float sco = exp2f(mstate[f] - mnew);
                float sco_out[4];
#pragma unroll
                for (int r = 0; r < 4; ++r) sco_out[r] = __shfl(sco, hi * 4 + r);
#pragma unroll
                for (int j2 = 0; j2 < 8; ++j2)
#pragma unroll
                    for (int r = 0; r < 4; ++r) o4[f][j2][r] *= sco_out[r];
                lstate[f] *= sco;
                mstate[f] = mnew;
            }
        }

#pragma unroll
        for (int f = 0; f < 2; ++f) {
            float lt = 0.f;
#pragma unroll
            for (int kb = 0; kb < 4; ++kb)
#pragma unroll
                for (int r = 0; r < 4; ++r) {
                    p[f][kb][r] = exp2f(p[f][kb][r] - mstate[f]);
                    lt += p[f][kb][r];
                }
            lt += __shfl_xor(lt, 16);
            lt += __shfl_xor(lt, 32);
            lstate[f] += lt;
        }

        // write P[q][key] (per-wave buffer; same-wave DS ordering)
#pragma unroll
        for (int f = 0; f < 2; ++f)
#pragma unroll
            for (int kb = 0; kb < 4; ++kb) {
                uint2 w;
                w.x = pack2_cvt(p[f][kb][0], p[f][kb][1]);
                w.y = pack2_cvt(p[f][kb][2], p[f][kb][3]);
                *reinterpret_cast<uint2*>(&Pt[wid][(f * 16 + l15) * 72 + kb * 16 + hi * 4]) = w;
            }

        // PV: O[q][d] += P (A) x V^T-frag (B); each V-frag feeds 2 MFMAs
#pragma unroll
        for (int kc = 0; kc < 2; ++kc) {
            bf16x8 pa0 = *reinterpret_cast<const bf16x8*>(&Pt[wid][l15 * 72 + kc * 32 + k0]);
            bf16x8 pa1 = *reinterpret_cast<const bf16x8*>(&Pt[wid][(16 + l15) * 72 + kc * 32 + k0]);
#pragma unroll
            for (int j2 = 0; j2 < 8; ++j2) {
                int d = j2 * 16 + l15;
                bf16x8 vb = *reinterpret_cast<const bf16x8*>(
                    &Vt[d * 64 + (((kc * 4 + hi) ^ (d & 7)) * 8)]);
                o4[0][j2] = __builtin_amdgcn_mfma_f32_16x16x32_bf16(pa0, vb, o4[0][j2], 0, 0, 0);
                o4[1][j2] = __builtin_amdgcn_mfma_f32_16x16x32_bf16(pa1, vb, o4[1][j2], 0, 0, 0);
            }
        }
        __syncthreads();
    }

    // l is in softmax layout (q = l15 per frag); outputs need q = hi*4+r
#pragma unroll
    for (int f = 0; f < 2; ++f) {
        float linv[4];
#pragma unroll
        for (int r = 0; r < 4; ++r) linv[r] = 1.0f / __shfl(lstate[f], hi * 4 + r);
#pragma unroll
        for (int j2 = 0; j2 < 8; ++j2)
#pragma unroll
            for (int r = 0; r < 4; ++r) {
                int row = sc * 128 + wid * 32 + f * 16 + hi * 4 + r;
                attn_f[(size_t)(b * 2048 + row) * 2048 + h * 128 + j2 * 16 + l15] =
                    f2bf(o4[f][j2][r] * linv[r]);
            }
    }
}

// ---------------- launch ----------------
extern "C" void kernel_launch(void* const* d_in, const int* in_sizes, int n_in,
                              void* d_out, int out_size, void* d_ws, size_t ws_size,
                              hipStream_t stream) {
    const float* hidden = (const float*)d_in[0];
    const float* dsk    = (const float*)d_in[1];
    const float* dsv    = (const float*)d_in[2];
    const float* dsmask = (const float*)d_in[3];
    const float* tk     = (const float*)d_in[4];
    const float* tv     = (const float*)d_in[5];
    const float* tmask  = (const float*)d_in[6];
    const float* cn_w   = (const float*)d_in[7];
    const float* cq_w   = (const float*)d_in[8];
    const float* ck_w   = (const float*)d_in[9];
    const float* cv_w   = (const float*)d_in[10];
    const float* co_w   = (const float*)d_in[11];
    const float* c_gate = (const float*)d_in[12];
    const float* fn_w   = (const float*)d_in[13];
    const float* fq_w   = (const float*)d_in[14];
    const float* fk_w   = (const float*)d_in[15];
    const float* fv_w   = (const float*)d_in[16];
    const float* fo_w   = (const float*)d_in[17];
    const float* f_gate = (const float*)d_in[18];
    const int*   map    = (const int*)d_in[19];
    float* out_f = (float*)d_out;   // also the f32 buffer for coarse residual

    char* ws = (char*)d_ws;
    size_t off = 0;
    auto alloc = [&](size_t bytes) {
        char* p = ws + off;
        off += (bytes + 255) & ~(size_t)255;
        return p;
    };
    u16*  normA = (u16*)alloc(4096ULL * 2048 * 2);
    u16*  qbuf  = (u16*)alloc(4096ULL * 2048 * 2);
    u16*  kc    = (u16*)alloc(128ULL * 512 * 2);
    u16*  vc    = (u16*)alloc(128ULL * 512 * 2);
    u16*  dskb  = (u16*)alloc(128ULL * 2048 * 2);
    u16*  dsvb  = (u16*)alloc(128ULL * 2048 * 2);
    u16*  kfb   = (u16*)alloc(4096ULL * 512 * 2);
    u16*  vTb   = (u16*)alloc(512ULL * 4096 * 2);   // V^T [kv*128+d][b*2048+t]
    u16*  cqT   = (u16*)alloc(2048ULL * 2048 * 2);
    u16*  ckT   = (u16*)alloc(512ULL * 2048 * 2);
    u16*  cvT   = (u16*)alloc(512ULL * 2048 * 2);
    u16*  coT   = (u16*)alloc(2048ULL * 2048 * 2);
    u16*  fqT   = (u16*)alloc(2048ULL * 2048 * 2);
    u16*  fkT   = (u16*)alloc(512ULL * 2048 * 2);
    u16*  fvT   = (u16*)alloc(512ULL * 2048 * 2);
    u16*  foT   = (u16*)alloc(2048ULL * 2048 * 2);
    float* doc_part = (float*)alloc(8 * 128 * 4);
    float* log_ds   = (float*)alloc(128 * 4);
    float* biasb    = (float*)alloc(4096 * 4);

    hipMemsetAsync(doc_part, 0, 8 * 128 * 4, stream);

    // weight transposes (f32 [K=2048][N] -> bf16 [N][2048])
    transpose_cvt<<<dim3(64, 64), 256, 0, stream>>>(cq_w, cqT, 2048, 2048);
    transpose_cvt<<<dim3(16, 64), 256, 0, stream>>>(ck_w, ckT, 2048, 512);
    transpose_cvt<<<dim3(16, 64), 256, 0, stream>>>(cv_w, cvT, 2048, 512);
    transpose_cvt<<<dim3(64, 64), 256, 0, stream>>>(co_w, coT, 2048, 2048);
    transpose_cvt<<<dim3(64, 64), 256, 0, stream>>>(fq_w, fqT, 2048, 2048);
    transpose_cvt<<<dim3(16, 64), 256, 0, stream>>>(fk_w, fkT, 2048, 512);
    transpose_cvt<<<dim3(16, 64), 256, 0, stream>>>(fv_w, fvT, 2048, 512);
    transpose_cvt<<<dim3(64, 64), 256, 0, stream>>>(fo_w, foT, 2048, 2048);

    cvt_f32_bf16<<<(128 * 2048 / 4 + 255) / 256, 256, 0, stream>>>(dsk, dskb, 128 * 2048 / 4);
    cvt_f32_bf16<<<(128 * 2048 / 4 + 255) / 256, 256, 0, stream>>>(dsv, dsvb, 128 * 2048 / 4);
    rmsnorm_kernel<<<4096, 256, 0, stream>>>(hidden, cn_w, normA);

    // coarse projections
    gemm_tn<0, 128><<<dim3(16, 32), 256, 0, stream>>>(normA, cqT, qbuf, nullptr, nullptr, nullptr, 4096, 2048, 2048);
    gemm_tn<0, 64><<<dim3(8, 1), 256, 0, stream>>>(dskb, ckT, kc, nullptr, nullptr, nullptr, 128, 512, 2048);
    gemm_tn<0, 64><<<dim3(8, 1), 256, 0, stream>>>(dsvb, cvT, vc, nullptr, nullptr, nullptr, 128, 512, 2048);

    // coarse attention (attn_c into normA) + doc-score partials
    coarse_attn<<<1024, 256, 0, stream>>>(qbuf, kc, vc, dsmask, doc_part, normA);
    doc_finalize<<<1, 128, 0, stream>>>(doc_part, log_ds);
    bias_kernel<<<16, 256, 0, stream>>>(log_ds, map, tmask, biasb);

    // coarse o-proj + residual + gate -> d_out (f32)
    gemm_tn<1, 128><<<dim3(16, 32), 256, 0, stream>>>(normA, coT, nullptr, out_f, hidden, c_gate, 4096, 2048, 2048);

    // fine stage
    rmsnorm_kernel<<<4096, 256, 0, stream>>>(out_f, fn_w, qbuf);
    gemm_tn<0, 128><<<dim3(16, 32), 256, 0, stream>>>(qbuf, fqT, normA, nullptr, nullptr, nullptr, 4096, 2048, 2048);
    cvt_f32_bf16<<<(4096 * 2048 / 4 + 255) / 256, 256, 0, stream>>>(tk, qbuf, 4096 * 2048 / 4);
    gemm_tn<0, 64><<<dim3(8, 32), 256, 0, stream>>>(qbuf, fkT, kfb, nullptr, nullptr, nullptr, 4096, 512, 2048);
    cvt_f32_bf16<<<(4096 * 2048 / 4 + 255) / 256, 256, 0, stream>>>(tv, qbuf, 4096 * 2048 / 4);
    // V^T directly from the projection: vT[d][token] = fvT[d][:] . tv[token][:]
    gemm_tn<0, 64><<<dim3(64, 4), 256, 0, stream>>>(fvT, qbuf, vTb, nullptr, nullptr, nullptr, 512, 4096, 2048);

    flash_attn<<<512, 256, 0, stream>>>(normA, kfb, vTb, biasb, qbuf);

    // final o-proj + residual + gate -> d_out
    gemm_tn<1, 128><<<dim3(16, 32), 256, 0, stream>>>(qbuf, foT, nullptr, out_f, out_f, f_gate, 4096, 2048, 2048);
}

// Round 8
// 499.881 us; speedup vs baseline: 2.0650x; 1.1381x over previous
//
#include <hip/hip_runtime.h>
#include <hip/hip_bf16.h>

typedef unsigned short u16;
typedef unsigned int u32;
typedef __attribute__((ext_vector_type(8))) short bf16x8;
typedef __attribute__((ext_vector_type(4))) float f32x4;

constexpr int NH = 16;
constexpr int H = 2048;
constexpr float SCALE = 0.08838834764831845f;   // 1/sqrt(128)
constexpr float L2E = 1.4426950408889634f;      // log2(e)
constexpr float SCALE2 = SCALE * L2E;           // QK scale in log2 domain
constexpr float THR2 = 8.0f * L2E;              // defer-max threshold (log2 units)

__device__ __forceinline__ u16 f2bf(float f) {
    u32 u = __float_as_uint(f);
    u32 r = u + 0x7fffu + ((u >> 16) & 1u);   // RNE (finite inputs only)
    return (u16)(r >> 16);
}
__device__ __forceinline__ u32 pack2(float x, float y) {
    return (u32)f2bf(x) | ((u32)f2bf(y) << 16);
}
__device__ __forceinline__ u32 pack2_cvt(float x, float y) {
    __hip_bfloat162 h = __float22bfloat162_rn(float2{x, y});
    return *reinterpret_cast<u32*>(&h);
}

#define GLD_LDS16(gsrc, ldst)                                                  \
    __builtin_amdgcn_global_load_lds(                                          \
        (const __attribute__((address_space(1))) void*)(gsrc),                 \
        (__attribute__((address_space(3))) void*)(ldst), 16, 0, 0)

// ---------------- f32 -> bf16 convert (vectorized) ----------------
__global__ __launch_bounds__(256) void cvt_f32_bf16(const float* __restrict__ in,
                                                    u16* __restrict__ out, int n4) {
    int i = blockIdx.x * 256 + threadIdx.x;
    if (i >= n4) return;
    float4 v = reinterpret_cast<const float4*>(in)[i];
    uint2 o;
    o.x = pack2(v.x, v.y);
    o.y = pack2(v.z, v.w);
    reinterpret_cast<uint2*>(out)[i] = o;
}

// ---------------- weight transpose + convert: f32[K][N] -> bf16[N][K] ----------------
__global__ __launch_bounds__(256)
void transpose_cvt(const float* __restrict__ in, u16* __restrict__ out, int K, int N) {
    __shared__ u16 tile[32][33];
    int bn = blockIdx.x * 32, bk = blockIdx.y * 32;
    int tx = threadIdx.x & 31, ty = threadIdx.x >> 5;  // ty 0..7
#pragma unroll
    for (int r = 0; r < 32; r += 8)
        tile[tx][r + ty] = f2bf(in[(size_t)(bk + r + ty) * N + bn + tx]);
    __syncthreads();
#pragma unroll
    for (int r = 0; r < 32; r += 8)
        out[(size_t)(bn + r + ty) * K + bk + tx] = tile[r + ty][tx];
}

// ---------------- RMSNorm f32 -> bf16, H=2048, one block per row ----------------
__global__ __launch_bounds__(256) void rmsnorm_kernel(const float* __restrict__ x,
                                                      const float* __restrict__ w,
                                                      u16* __restrict__ y) {
    int r = blockIdx.x;
    const float4* xr = reinterpret_cast<const float4*>(x + (size_t)r * H);
    int t = threadIdx.x;
    float4 v0 = xr[t * 2], v1 = xr[t * 2 + 1];
    float ss = v0.x * v0.x + v0.y * v0.y + v0.z * v0.z + v0.w * v0.w
             + v1.x * v1.x + v1.y * v1.y + v1.z * v1.z + v1.w * v1.w;
#pragma unroll
    for (int d = 1; d < 64; d <<= 1) ss += __shfl_xor(ss, d);
    __shared__ float red[4];
    if ((t & 63) == 0) red[t >> 6] = ss;
    __syncthreads();
    float tot = red[0] + red[1] + red[2] + red[3];
    float rs = rsqrtf(tot * (1.0f / H) + 1e-6f);
    const float4* wr = reinterpret_cast<const float4*>(w);
    float4 w0 = wr[t * 2], w1 = wr[t * 2 + 1];
    uint4 o;
    o.x = pack2(v0.x * rs * w0.x, v0.y * rs * w0.y);
    o.y = pack2(v0.z * rs * w0.z, v0.w * rs * w0.w);
    o.z = pack2(v1.x * rs * w1.x, v1.y * rs * w1.y);
    o.w = pack2(v1.z * rs * w1.z, v1.w * rs * w1.w);
    reinterpret_cast<uint4*>(y + (size_t)r * H)[t] = o;
}

// ---------------- GEMM v2: BK=64, double-buffered, swizzled LDS ----------------
// C[M,N] = A_bf16[M,K] @ Bt_bf16[N,K]^T
// MODE 0: store bf16 C.  MODE 1: Cf = resid + sigmoid(*gate_p) * acc (f32 out).
// One barrier per K-step; prefetch issued before compute (full step of flight time).
template <int MODE, int BN>
__global__ __launch_bounds__(256)
void gemm_tn(const u16* __restrict__ A, const u16* __restrict__ Bt,
             u16* __restrict__ Cb, float* __restrict__ Cf,
             const float* __restrict__ resid, const float* __restrict__ gate_p,
             int M, int N, int K) {
    constexpr int WN = BN / 32;          // N frags per wave: 4 or 2
    constexpr int BWROWS = BN / 4;       // B rows staged per wave: 32 or 16
    __shared__ u16 As[2][128 * 64];
    __shared__ u16 Bs[2][BN * 64];
    const int t = threadIdx.x;
    const int lane = t & 63, wid = t >> 6;
    const int wm = wid >> 1, wn = wid & 1;
    const int brow = blockIdx.y * 128, bcol = blockIdx.x * BN;
    const int l15 = lane & 15, hi = lane >> 4;
    const int rsw = l15 & 7;

    f32x4 acc[4][WN] = {};
    // staging: each gload_lds covers 8 rows x 64 cols; source segment pre-swizzled
    const int srow = lane >> 3;
    const int sseg = ((lane & 7) ^ srow) * 8;
    const u16* aBase = A + (size_t)(brow + wid * 32 + srow) * K + sseg;
    const u16* bBase = Bt + (size_t)(bcol + wid * BWROWS + srow) * K + sseg;

#define GSTAGE(KT, BF)                                                          \
    do {                                                                        \
        _Pragma("unroll")                                                       \
        for (int u = 0; u < 4; ++u)                                             \
            GLD_LDS16(aBase + (size_t)(u * 8) * K + (KT),                       \
                      &As[BF][(wid * 32 + u * 8) * 64]);                        \
        _Pragma("unroll")                                                       \
        for (int u = 0; u < BWROWS / 8; ++u)                                    \
            GLD_LDS16(bBase + (size_t)(u * 8) * K + (KT),                       \
                      &Bs[BF][(wid * BWROWS + u * 8) * 64]);                    \
    } while (0)

    GSTAGE(0, 0);
    __syncthreads();
    int buf = 0;
    for (int kt = 0; kt < K; kt += 64) {
        if (kt + 64 < K) GSTAGE(kt + 64, buf ^ 1);
        bf16x8 af[4][2], bfr[WN][2];
#pragma unroll
        for (int i = 0; i < 4; ++i) {
            int row = wm * 64 + i * 16 + l15;
#pragma unroll
            for (int ko = 0; ko < 2; ++ko)
                af[i][ko] = *reinterpret_cast<const bf16x8*>(
                    &As[buf][row * 64 + (((ko * 4 + hi) ^ rsw) * 8)]);
        }
#pragma unroll
        for (int j = 0; j < WN; ++j) {
            int row = wn * (BN / 2) + j * 16 + l15;
#pragma unroll
            for (int ko = 0; ko < 2; ++ko)
                bfr[j][ko] = *reinterpret_cast<const bf16x8*>(
                    &Bs[buf][row * 64 + (((ko * 4 + hi) ^ rsw) * 8)]);
        }
#pragma unroll
        for (int ko = 0; ko < 2; ++ko)
#pragma unroll
            for (int i = 0; i < 4; ++i)
#pragma unroll
                for (int j = 0; j < WN; ++j)
                    acc[i][j] = __builtin_amdgcn_mfma_f32_16x16x32_bf16(
                        af[i][ko], bfr[j][ko], acc[i][j], 0, 0, 0);
        __syncthreads();   // drains prefetch vmcnt; all waves done reading buf
        buf ^= 1;
    }
#undef GSTAGE

    float g = 0.f;
    if (MODE == 1) g = 1.0f / (1.0f + expf(-gate_p[0]));
    const int r0 = hi * 4, c0 = l15;
#pragma unroll
    for (int i = 0; i < 4; ++i) {
#pragma unroll
        for (int j = 0; j < WN; ++j) {
            int col = bcol + wn * (BN / 2) + j * 16 + c0;
#pragma unroll
            for (int r = 0; r < 4; ++r) {
                int row = brow + wm * 64 + i * 16 + r0 + r;
                float v = acc[i][j][r];
                if (MODE == 0) Cb[(size_t)row * N + col] = f2bf(v);
                else Cf[(size_t)row * N + col] = resid[(size_t)row * N + col] + g * v;
            }
        }
    }
}

// ---------------- coarse attention (ND=64 keys, exact softmax, exp2 domain) --------
__global__ __launch_bounds__(256)
void coarse_attn(const u16* __restrict__ q, const u16* __restrict__ kc,
                 const u16* __restrict__ vc, const float* __restrict__ mask,
                 float* __restrict__ doc_part, u16* __restrict__ attn_c) {
    constexpr int SC = 2048 / 64;
    int bid = blockIdx.x;
    int b = bid / (NH * SC);
    int rem = bid % (NH * SC);
    int h = rem / SC, sc = rem % SC;
    int kv = h >> 2;
    int t = threadIdx.x, lane = t & 63, wid = t >> 6;
    const int l15 = lane & 15, k0 = (lane >> 4) * 8;

    __shared__ u16 Kt[64 * 136];
    __shared__ u16 Vt[128 * 72];
    __shared__ u16 Pt[4][16 * 72];
    __shared__ float p_acc[64];

    {   // stage K [64 keys][128 d]
        int n = t >> 2, s2 = t & 3;
        const u16* src = kc + (size_t)(b * 64 + n) * 512 + kv * 128;
#pragma unroll
        for (int u = 0; u < 4; ++u) {
            int sg = s2 + u * 4;
            *reinterpret_cast<uint4*>(&Kt[n * 136 + sg * 8]) =
                *reinterpret_cast<const uint4*>(src + sg * 8);
        }
    }
    {   // stage V transposed: Vt[d][key]
        int n = t & 63, dblk = t >> 6;
        const u16* src = vc + (size_t)(b * 64 + n) * 512 + kv * 128 + dblk * 32;
#pragma unroll
        for (int u = 0; u < 4; ++u) {
            u16 tmp[8];
            *reinterpret_cast<uint4*>(tmp) = *reinterpret_cast<const uint4*>(src + u * 8);
#pragma unroll
            for (int e = 0; e < 8; ++e) Vt[(dblk * 32 + u * 8 + e) * 72 + n] = tmp[e];
        }
    }
    if (t < 64) p_acc[t] = 0.f;
    __syncthreads();

    int qrow = sc * 64 + wid * 16 + l15;
    const u16* qsrc = q + (size_t)(b * 2048 + qrow) * 2048 + h * 128;
    bf16x8 af[4];
#pragma unroll
    for (int kk = 0; kk < 4; ++kk)
        af[kk] = *reinterpret_cast<const bf16x8*>(qsrc + kk * 32 + k0);

    f32x4 sc4[4] = {};
#pragma unroll
    for (int kk = 0; kk < 4; ++kk)
#pragma unroll
        for (int j = 0; j < 4; ++j) {
            bf16x8 bfr = *reinterpret_cast<const bf16x8*>(&Kt[(j * 16 + l15) * 136 + kk * 32 + k0]);
            sc4[j] = __builtin_amdgcn_mfma_f32_16x16x32_bf16(af[kk], bfr, sc4[j], 0, 0, 0);
        }

    float s[4][4];
#pragma unroll
    for (int j = 0; j < 4; ++j) {
        float bia = (1.0f - mask[b * 64 + j * 16 + l15]) * (-1e9f * L2E);
#pragma unroll
        for (int r = 0; r < 4; ++r) s[j][r] = sc4[j][r] * SCALE2 + bia;
    }
    float m4[4], l4[4];
#pragma unroll
    for (int r = 0; r < 4; ++r) {
        float m = fmaxf(fmaxf(s[0][r], s[1][r]), fmaxf(s[2][r], s[3][r]));
#pragma unroll
        for (int d = 1; d < 16; d <<= 1) m = fmaxf(m, __shfl_xor(m, d));
        m4[r] = m;
    }
#pragma unroll
    for (int r = 0; r < 4; ++r) {
        float l = 0.f;
#pragma unroll
        for (int j = 0; j < 4; ++j) { s[j][r] = exp2f(s[j][r] - m4[r]); l += s[j][r]; }
#pragma unroll
        for (int d = 1; d < 16; d <<= 1) l += __shfl_xor(l, d);
        l4[r] = l;
    }
#pragma unroll
    for (int j = 0; j < 4; ++j) {
        float cs = 0.f;
#pragma unroll
        for (int r = 0; r < 4; ++r) {
            float pr = s[j][r] / l4[r];
            Pt[wid][((lane >> 4) * 4 + r) * 72 + j * 16 + l15] = f2bf(pr);
            cs += pr;
        }
        cs += __shfl_xor(cs, 16);
        cs += __shfl_xor(cs, 32);
        if (lane < 16) atomicAdd(&p_acc[j * 16 + lane], cs);
    }
    __syncthreads();

    f32x4 o4[8] = {};
#pragma unroll
    for (int kk2 = 0; kk2 < 2; ++kk2) {
        bf16x8 a2 = *reinterpret_cast<const bf16x8*>(&Pt[wid][l15 * 72 + kk2 * 32 + k0]);
#pragma unroll
        for (int j2 = 0; j2 < 8; ++j2) {
            bf16x8 b2 = *reinterpret_cast<const bf16x8*>(&Vt[(j2 * 16 + l15) * 72 + kk2 * 32 + k0]);
            o4[j2] = __builtin_amdgcn_mfma_f32_16x16x32_bf16(a2, b2, o4[j2], 0, 0, 0);
        }
    }
#pragma unroll
    for (int j2 = 0; j2 < 8; ++j2)
#pragma unroll
        for (int r = 0; r < 4; ++r) {
            int row = sc * 64 + wid * 16 + (lane >> 4) * 4 + r;
            attn_c[(size_t)(b * 2048 + row) * 2048 + h * 128 + j2 * 16 + l15] = f2bf(o4[j2][r]);
        }
    if (t < 64) atomicAdd(&doc_part[(blockIdx.x & 7) * 128 + b * 64 + t], p_acc[t]);
}

// ---------------- doc-score finalize + fine bias (bias pre-scaled by log2e) --------
__global__ void doc_finalize(const float* __restrict__ doc_part, float* __restrict__ log_ds) {
    int t = threadIdx.x; // 128
    float s = 0.f;
#pragma unroll
    for (int i = 0; i < 8; ++i) s += doc_part[i * 128 + t];
    log_ds[t] = logf(s / 32768.0f + 1e-6f);
}

__global__ __launch_bounds__(256)
void bias_kernel(const float* __restrict__ log_ds, const int* __restrict__ map,
                 const float* __restrict__ tmask, float* __restrict__ bias) {
    int i = blockIdx.x * 256 + threadIdx.x;
    if (i >= 2 * 2048) return;
    int b = i >> 11;
    bias[i] = (log_ds[b * 64 + map[i]] + (1.0f - tmask[i]) * -1e9f) * L2E;
}

// ---------------- fine flash attention v6 ----------------
// QBLK=32/wave; K double-buffered (prefetch t+1 at tile start -> full tile of
// flight), V single-buffered staged at tile start (hidden under QK+softmax),
// bias direct from global, Pt [32][64] XOR-swizzled. LDS = 64 KB exactly.
__global__ __launch_bounds__(256, 2)
void flash_attn(const u16* __restrict__ q, const u16* __restrict__ kf,
                const u16* __restrict__ vT, const float* __restrict__ bias,
                u16* __restrict__ attn_f) {
    int bid = blockIdx.x;
    int b = bid >> 8;              // NH * 16 = 256 blocks per batch
    int rem = bid & 255;
    int h = rem >> 4, sc = rem & 15;
    int kv = h >> 2;
    int t = threadIdx.x, lane = t & 63, wid = t >> 6;
    const int l15 = lane & 15, hi = lane >> 4;
    const int k0 = hi * 8;
    const int rswp = l15 & 7;

    __shared__ u16 Kt[2][64 * 128];    // [key][d] linear, swizzled 16B slots (32 KB)
    __shared__ u16 Vt[128 * 64];       // [d][key] linear, swizzled 16B slots (16 KB)
    __shared__ u16 Pt[4][32 * 64];     // per-wave P[q][key], XOR-swizzled (16 KB)

    // Q fragments: 2 q-frags of 16 rows each
    bf16x8 qf4[2][4];
#pragma unroll
    for (int f = 0; f < 2; ++f) {
        int qrow = sc * 128 + wid * 32 + f * 16 + l15;
        const u16* qsrc = q + (size_t)(b * 2048 + qrow) * 2048 + h * 128;
#pragma unroll
        for (int kk = 0; kk < 4; ++kk)
            qf4[f][kk] = *reinterpret_cast<const bf16x8*>(qsrc + kk * 32 + k0);
    }

    // staging lane roles (constant over tiles)
    const int krl = lane >> 4, kslot = lane & 15;   // K: 4 rows x 16 slots per 1KB
    const int vrl = lane >> 3, vslot = lane & 7;    // V: 8 rows x 8 slots per 1KB
    const u16* kbase = kf + (size_t)(b * 2048) * 512 + kv * 128;
    const u16* vbase = vT + (size_t)(kv * 128) * 4096 + b * 2048;
    const float* bbase = bias + b * 2048;

#define STAGE_K(TT, BF)                                                            \
    do {                                                                           \
        _Pragma("unroll")                                                          \
        for (int u = 0; u < 4; ++u) {                                              \
            int row = wid * 16 + u * 4 + krl;                                      \
            const u16* src = kbase + (size_t)((TT) + row) * 512                    \
                             + ((kslot ^ (row & 7)) * 8);                          \
            GLD_LDS16(src, &Kt[BF][(wid * 16 + u * 4) * 128]);                     \
        }                                                                          \
    } while (0)
#define STAGE_V(TT)                                                                \
    do {                                                                           \
        _Pragma("unroll")                                                          \
        for (int u = 0; u < 4; ++u) {                                              \
            int row = wid * 32 + u * 8 + vrl;                                      \
            const u16* src = vbase + (size_t)row * 4096 + (TT)                     \
                             + ((vslot ^ (row & 7)) * 8);                          \
            GLD_LDS16(src, &Vt[(wid * 32 + u * 8) * 64]);                          \
        }                                                                          \
    } while (0)

    float mstate[2] = {-1e30f, -1e30f}, lstate[2] = {0.f, 0.f};   // log2 domain
    f32x4 o4[2][8] = {};

    STAGE_K(0, 0);
    __syncthreads();
    int kbuf = 0;

    for (int t0 = 0; t0 < 2048; t0 += 64) {
        int t1 = (t0 + 64) & 2047;          // wrap-around prefetch (last iter harmless)
        STAGE_K(t1, kbuf ^ 1);
        STAGE_V(t0);

        // QK^T swapped: S^T[key][q] = K-frag (A) x Q-frag (B); K-frag feeds 2 MFMAs
        f32x4 st0[4] = {}, st1[4] = {};
        __builtin_amdgcn_s_setprio(1);
#pragma unroll
        for (int kk = 0; kk < 4; ++kk)
#pragma unroll
            for (int kb = 0; kb < 4; ++kb) {
                int row = kb * 16 + l15;
                bf16x8 kfrag = *reinterpret_cast<const bf16x8*>(
                    &Kt[kbuf][row * 128 + (((kk * 4 + hi) ^ (row & 7)) * 8)]);
                st0[kb] = __builtin_amdgcn_mfma_f32_16x16x32_bf16(kfrag, qf4[0][kk], st0[kb], 0, 0, 0);
                st1[kb] = __builtin_amdgcn_mfma_f32_16x16x32_bf16(kfrag, qf4[1][kk], st1[kb], 0, 0, 0);
            }
        __builtin_amdgcn_s_setprio(0);

        // per-lane: q = f*16 + l15, keys = kb*16 + hi*4 + r ; log2 domain
        float p[2][4][4];
        float pmax[2] = {-1e30f, -1e30f};
#pragma unroll
        for (int kb = 0; kb < 4; ++kb) {
            float4 b4 = *reinterpret_cast<const float4*>(bbase + t0 + kb * 16 + hi * 4);
            float bb[4] = {b4.x, b4.y, b4.z, b4.w};
#pragma unroll
            for (int r = 0; r < 4; ++r) {
                float v0 = st0[kb][r] * SCALE2 + bb[r];
                float v1 = st1[kb][r] * SCALE2 + bb[r];
                p[0][kb][r] = v0;
                p[1][kb][r] = v1;
                pmax[0] = fmaxf(pmax[0], v0);
                pmax[1] = fmaxf(pmax[1], v1);
            }
        }
#pragma unroll
        for (int f = 0; f < 2; ++f) {
            pmax[f] = fmaxf(pmax[f], __shfl_xor(pmax[f], 16));
            pmax[f] = fmaxf(pmax[f], __shfl_xor(pmax[f], 32));
        }

        // defer-max (T13): combined branch; rescale both frags when either needs it
        bool need = (pmax[0] > mstate[0] + THR2) || (pmax[1] > mstate[1] + THR2);
        if (__any(need)) {
#pragma unroll
            for (int f = 0; f < 2; ++f) {
                float mnew = fmaxf(mstate[f], pmax[f]);
                float sco = exp2f(mstate[f] - mnew);
                float sco_out[4];
#pragma unroll
                for (int r = 0; r < 4; ++r) sco_out[r] = __shfl(sco, hi * 4 + r);
#pragma unroll
                for (int j2 = 0; j2 < 8; ++j2)
#pragma unroll
                    for (int r = 0; r < 4; ++r) o4[f][j2][r] *= sco_out[r];
                lstate[f] *= sco;
                mstate[f] = mnew;
            }
        }

#pragma unroll
        for (int f = 0; f < 2; ++f) {
            float lt = 0.f;
#pragma unroll
            for (int kb = 0; kb < 4; ++kb)
#pragma unroll
                for (int r = 0; r < 4; ++r) {
                    p[f][kb][r] = exp2f(p[f][kb][r] - mstate[f]);
                    lt += p[f][kb][r];
                }
            lt += __shfl_xor(lt, 16);
            lt += __shfl_xor(lt, 32);
            lstate[f] += lt;
        }

        // write P[q][key] (per-wave, swizzled b64 writes; same-wave DS ordering)
#pragma unroll
        for (int f = 0; f < 2; ++f)
#pragma unroll
            for (int kb = 0; kb < 4; ++kb) {
                uint2 w;
                w.x = pack2_cvt(p[f][kb][0], p[f][kb][1]);
                w.y = pack2_cvt(p[f][kb][2], p[f][kb][3]);
                int idx = (f * 16 + l15) * 64
                        + (((kb * 2 + (hi >> 1)) ^ rswp) * 8) + (hi & 1) * 4;
                *reinterpret_cast<uint2*>(&Pt[wid][idx]) = w;
            }

        __syncthreads();   // BAR1: V(t0) staged+drained; all waves see it

        // PV: O[q][d] += P (A) x V^T-frag (B); V-frag feeds 2 MFMAs
        __builtin_amdgcn_s_setprio(1);
#pragma unroll
        for (int kc = 0; kc < 2; ++kc) {
            bf16x8 pa0 = *reinterpret_cast<const bf16x8*>(
                &Pt[wid][l15 * 64 + (((kc * 4 + hi) ^ rswp) * 8)]);
            bf16x8 pa1 = *reinterpret_cast<const bf16x8*>(
                &Pt[wid][(16 + l15) * 64 + (((kc * 4 + hi) ^ rswp) * 8)]);
#pragma unroll
            for (int j2 = 0; j2 < 8; ++j2) {
                int d = j2 * 16 + l15;
                bf16x8 vb = *reinterpret_cast<const bf16x8*>(
                    &Vt[d * 64 + (((kc * 4 + hi) ^ (d & 7)) * 8)]);
                o4[0][j2] = __builtin_amdgcn_mfma_f32_16x16x32_bf16(pa0, vb, o4[0][j2], 0, 0, 0);
                o4[1][j2] = __builtin_amdgcn_mfma_f32_16x16x32_bf16(pa1, vb, o4[1][j2], 0, 0, 0);
            }
        }
        __builtin_amdgcn_s_setprio(0);
        __syncthreads();   // BAR2: protect Vt (next STAGE_V) and Kt[kbuf^1] reads
        kbuf ^= 1;
    }
#undef STAGE_K
#undef STAGE_V

    // l is in softmax layout (q = l15 per frag); outputs need q = hi*4+r
#pragma unroll
    for (int f = 0; f < 2; ++f) {
        float linv[4];
#pragma unroll
        for (int r = 0; r < 4; ++r) linv[r] = 1.0f / __shfl(lstate[f], hi * 4 + r);
#pragma unroll
        for (int j2 = 0; j2 < 8; ++j2)
#pragma unroll
            for (int r = 0; r < 4; ++r) {
                int row = sc * 128 + wid * 32 + f * 16 + hi * 4 + r;
                attn_f[(size_t)(b * 2048 + row) * 2048 + h * 128 + j2 * 16 + l15] =
                    f2bf(o4[f][j2][r] * linv[r]);
            }
    }
}

// ---------------- launch ----------------
extern "C" void kernel_launch(void* const* d_in, const int* in_sizes, int n_in,
                              void* d_out, int out_size, void* d_ws, size_t ws_size,
                              hipStream_t stream) {
    const float* hidden = (const float*)d_in[0];
    const float* dsk    = (const float*)d_in[1];
    const float* dsv    = (const float*)d_in[2];
    const float* dsmask = (const float*)d_in[3];
    const float* tk     = (const float*)d_in[4];
    const float* tv     = (const float*)d_in[5];
    const float* tmask  = (const float*)d_in[6];
    const float* cn_w   = (const float*)d_in[7];
    const float* cq_w   = (const float*)d_in[8];
    const float* ck_w   = (const float*)d_in[9];
    const float* cv_w   = (const float*)d_in[10];
    const float* co_w   = (const float*)d_in[11];
    const float* c_gate = (const float*)d_in[12];
    const float* fn_w   = (const float*)d_in[13];
    const float* fq_w   = (const float*)d_in[14];
    const float* fk_w   = (const float*)d_in[15];
    const float* fv_w   = (const float*)d_in[16];
    const float* fo_w   = (const float*)d_in[17];
    const float* f_gate = (const float*)d_in[18];
    const int*   map    = (const int*)d_in[19];
    float* out_f = (float*)d_out;   // also the f32 buffer for coarse residual

    char* ws = (char*)d_ws;
    size_t off = 0;
    auto alloc = [&](size_t bytes) {
        char* p = ws + off;
        off += (bytes + 255) & ~(size_t)255;
        return p;
    };
    u16*  normA = (u16*)alloc(4096ULL * 2048 * 2);
    u16*  qbuf  = (u16*)alloc(4096ULL * 2048 * 2);
    u16*  kc    = (u16*)alloc(128ULL * 512 * 2);
    u16*  vc    = (u16*)alloc(128ULL * 512 * 2);
    u16*  dskb  = (u16*)alloc(128ULL * 2048 * 2);
    u16*  dsvb  = (u16*)alloc(128ULL * 2048 * 2);
    u16*  kfb   = (u16*)alloc(4096ULL * 512 * 2);
    u16*  vTb   = (u16*)alloc(512ULL * 4096 * 2);   // V^T [kv*128+d][b*2048+t]
    u16*  cqT   = (u16*)alloc(2048ULL * 2048 * 2);
    u16*  ckT   = (u16*)alloc(512ULL * 2048 * 2);
    u16*  cvT   = (u16*)alloc(512ULL * 2048 * 2);
    u16*  coT   = (u16*)alloc(2048ULL * 2048 * 2);
    u16*  fqT   = (u16*)alloc(2048ULL * 2048 * 2);
    u16*  fkT   = (u16*)alloc(512ULL * 2048 * 2);
    u16*  fvT   = (u16*)alloc(512ULL * 2048 * 2);
    u16*  foT   = (u16*)alloc(2048ULL * 2048 * 2);
    float* doc_part = (float*)alloc(8 * 128 * 4);
    float* log_ds   = (float*)alloc(128 * 4);
    float* biasb    = (float*)alloc(4096 * 4);

    hipMemsetAsync(doc_part, 0, 8 * 128 * 4, stream);

    // weight transposes (f32 [K=2048][N] -> bf16 [N][2048])
    transpose_cvt<<<dim3(64, 64), 256, 0, stream>>>(cq_w, cqT, 2048, 2048);
    transpose_cvt<<<dim3(16, 64), 256, 0, stream>>>(ck_w, ckT, 2048, 512);
    transpose_cvt<<<dim3(16, 64), 256, 0, stream>>>(cv_w, cvT, 2048, 512);
    transpose_cvt<<<dim3(64, 64), 256, 0, stream>>>(co_w, coT, 2048, 2048);
    transpose_cvt<<<dim3(64, 64), 256, 0, stream>>>(fq_w, fqT, 2048, 2048);
    transpose_cvt<<<dim3(16, 64), 256, 0, stream>>>(fk_w, fkT, 2048, 512);
    transpose_cvt<<<dim3(16, 64), 256, 0, stream>>>(fv_w, fvT, 2048, 512);
    transpose_cvt<<<dim3(64, 64), 256, 0, stream>>>(fo_w, foT, 2048, 2048);

    cvt_f32_bf16<<<(128 * 2048 / 4 + 255) / 256, 256, 0, stream>>>(dsk, dskb, 128 * 2048 / 4);
    cvt_f32_bf16<<<(128 * 2048 / 4 + 255) / 256, 256, 0, stream>>>(dsv, dsvb, 128 * 2048 / 4);
    rmsnorm_kernel<<<4096, 256, 0, stream>>>(hidden, cn_w, normA);

    // coarse projections
    gemm_tn<0, 128><<<dim3(16, 32), 256, 0, stream>>>(normA, cqT, qbuf, nullptr, nullptr, nullptr, 4096, 2048, 2048);
    gemm_tn<0, 64><<<dim3(8, 1), 256, 0, stream>>>(dskb, ckT, kc, nullptr, nullptr, nullptr, 128, 512, 2048);
    gemm_tn<0, 64><<<dim3(8, 1), 256, 0, stream>>>(dsvb, cvT, vc, nullptr, nullptr, nullptr, 128, 512, 2048);

    // coarse attention (attn_c into normA) + doc-score partials
    coarse_attn<<<1024, 256, 0, stream>>>(qbuf, kc, vc, dsmask, doc_part, normA);
    doc_finalize<<<1, 128, 0, stream>>>(doc_part, log_ds);
    bias_kernel<<<16, 256, 0, stream>>>(log_ds, map, tmask, biasb);

    // coarse o-proj + residual + gate -> d_out (f32)
    gemm_tn<1, 128><<<dim3(16, 32), 256, 0, stream>>>(normA, coT, nullptr, out_f, hidden, c_gate, 4096, 2048, 2048);

    // fine stage
    rmsnorm_kernel<<<4096, 256, 0, stream>>>(out_f, fn_w, qbuf);
    gemm_tn<0, 128><<<dim3(16, 32), 256, 0, stream>>>(qbuf, fqT, normA, nullptr, nullptr, nullptr, 4096, 2048, 2048);
    cvt_f32_bf16<<<(4096 * 2048 / 4 + 255) / 256, 256, 0, stream>>>(tk, qbuf, 4096 * 2048 / 4);
    gemm_tn<0, 64><<<dim3(8, 32), 256, 0, stream>>>(qbuf, fkT, kfb, nullptr, nullptr, nullptr, 4096, 512, 2048);
    cvt_f32_bf16<<<(4096 * 2048 / 4 + 255) / 256, 256, 0, stream>>>(tv, qbuf, 4096 * 2048 / 4);
    // V^T directly from the projection: vT[d][token] = fvT[d][:] . tv[token][:]
    gemm_tn<0, 64><<<dim3(64, 4), 256, 0, stream>>>(fvT, qbuf, vTb, nullptr, nullptr, nullptr, 512, 4096, 2048);

    flash_attn<<<512, 256, 0, stream>>>(normA, kfb, vTb, biasb, qbuf);

    // final o-proj + residual + gate -> d_out
    gemm_tn<1, 128><<<dim3(16, 32), 256, 0, stream>>>(qbuf, foT, nullptr, out_f, out_f, f_gate, 4096, 2048, 2048);
}

// Round 9
// 448.947 us; speedup vs baseline: 2.2993x; 1.1135x over previous
//
#include <hip/hip_runtime.h>
#include <hip/hip_bf16.h>

typedef unsigned short u16;
typedef unsigned int u32;
typedef __attribute__((ext_vector_type(8))) short bf16x8;
typedef __attribute__((ext_vector_type(4))) float f32x4;

constexpr int NH = 16;
constexpr int H = 2048;
constexpr float SCALE = 0.08838834764831845f;   // 1/sqrt(128)
constexpr float L2E = 1.4426950408889634f;      // log2(e)
constexpr float SCALE2 = SCALE * L2E;           // QK scale in log2 domain
constexpr float THR2 = 8.0f * L2E;              // defer-max threshold (log2 units)

__device__ __forceinline__ u16 f2bf(float f) {
    u32 u = __float_as_uint(f);
    u32 r = u + 0x7fffu + ((u >> 16) & 1u);   // RNE (finite inputs only)
    return (u16)(r >> 16);
}
__device__ __forceinline__ u32 pack2(float x, float y) {
    return (u32)f2bf(x) | ((u32)f2bf(y) << 16);
}
__device__ __forceinline__ u32 pack2_cvt(float x, float y) {
    __hip_bfloat162 h = __float22bfloat162_rn(float2{x, y});
    return *reinterpret_cast<u32*>(&h);
}

#define GLD_LDS16(gsrc, ldst)                                                  \
    __builtin_amdgcn_global_load_lds(                                          \
        (const __attribute__((address_space(1))) void*)(gsrc),                 \
        (__attribute__((address_space(3))) void*)(ldst), 16, 0, 0)

// ---------------- fused f32 -> bf16 convert, two arrays ----------------
__global__ __launch_bounds__(256) void cvt_f32_bf16_2(const float* __restrict__ a,
                                                      u16* __restrict__ oa,
                                                      const float* __restrict__ b,
                                                      u16* __restrict__ ob, int n4) {
    int i = blockIdx.x * 256 + threadIdx.x;
    const float* in;
    u16* out;
    if (i < n4) { in = a; out = oa; }
    else if (i < 2 * n4) { i -= n4; in = b; out = ob; }
    else return;
    float4 v = reinterpret_cast<const float4*>(in)[i];
    uint2 o;
    o.x = pack2(v.x, v.y);
    o.y = pack2(v.z, v.w);
    reinterpret_cast<uint2*>(out)[i] = o;
}

__global__ __launch_bounds__(256) void cvt_f32_bf16(const float* __restrict__ in,
                                                    u16* __restrict__ out, int n4) {
    int i = blockIdx.x * 256 + threadIdx.x;
    if (i >= n4) return;
    float4 v = reinterpret_cast<const float4*>(in)[i];
    uint2 o;
    o.x = pack2(v.x, v.y);
    o.y = pack2(v.z, v.w);
    reinterpret_cast<uint2*>(out)[i] = o;
}

// ---------------- batched weight transpose + convert: f32[K][N] -> bf16[N][K] -------
// blockIdx.z selects one of 4 (input,output) pairs; all share (K,N).
__global__ __launch_bounds__(256)
void transpose_cvt4(const float* __restrict__ i0, const float* __restrict__ i1,
                    const float* __restrict__ i2, const float* __restrict__ i3,
                    u16* __restrict__ o0, u16* __restrict__ o1,
                    u16* __restrict__ o2, u16* __restrict__ o3, int K, int N) {
    const float* in = (blockIdx.z == 0) ? i0 : (blockIdx.z == 1) ? i1
                    : (blockIdx.z == 2) ? i2 : i3;
    u16* out = (blockIdx.z == 0) ? o0 : (blockIdx.z == 1) ? o1
             : (blockIdx.z == 2) ? o2 : o3;
    __shared__ u16 tile[32][33];
    int bn = blockIdx.x * 32, bk = blockIdx.y * 32;
    int tx = threadIdx.x & 31, ty = threadIdx.x >> 5;  // ty 0..7
#pragma unroll
    for (int r = 0; r < 32; r += 8)
        tile[tx][r + ty] = f2bf(in[(size_t)(bk + r + ty) * N + bn + tx]);
    __syncthreads();
#pragma unroll
    for (int r = 0; r < 32; r += 8)
        out[(size_t)(bn + r + ty) * K + bk + tx] = tile[r + ty][tx];
}

// ---------------- RMSNorm f32 -> bf16, H=2048, one block per row ----------------
__global__ __launch_bounds__(256) void rmsnorm_kernel(const float* __restrict__ x,
                                                      const float* __restrict__ w,
                                                      u16* __restrict__ y) {
    int r = blockIdx.x;
    const float4* xr = reinterpret_cast<const float4*>(x + (size_t)r * H);
    int t = threadIdx.x;
    float4 v0 = xr[t * 2], v1 = xr[t * 2 + 1];
    float ss = v0.x * v0.x + v0.y * v0.y + v0.z * v0.z + v0.w * v0.w
             + v1.x * v1.x + v1.y * v1.y + v1.z * v1.z + v1.w * v1.w;
#pragma unroll
    for (int d = 1; d < 64; d <<= 1) ss += __shfl_xor(ss, d);
    __shared__ float red[4];
    if ((t & 63) == 0) red[t >> 6] = ss;
    __syncthreads();
    float tot = red[0] + red[1] + red[2] + red[3];
    float rs = rsqrtf(tot * (1.0f / H) + 1e-6f);
    const float4* wr = reinterpret_cast<const float4*>(w);
    float4 w0 = wr[t * 2], w1 = wr[t * 2 + 1];
    uint4 o;
    o.x = pack2(v0.x * rs * w0.x, v0.y * rs * w0.y);
    o.y = pack2(v0.z * rs * w0.z, v0.w * rs * w0.w);
    o.z = pack2(v1.x * rs * w1.x, v1.y * rs * w1.y);
    o.w = pack2(v1.z * rs * w1.z, v1.w * rs * w1.w);
    reinterpret_cast<uint4*>(y + (size_t)r * H)[t] = o;
}

// ---------------- GEMM body v2: BK=64, double-buffered, swizzled LDS ----------------
// C[M,N] = A_bf16[M,K] @ Bt_bf16[N,K]^T
// MODE 0: store bf16 C.  MODE 1: Cf = resid + sigmoid(*gate_p) * acc (f32 out).
template <int MODE, int BN>
__device__ __forceinline__
void gemm_body(const u16* __restrict__ A, const u16* __restrict__ Bt,
               u16* __restrict__ Cb, float* __restrict__ Cf,
               const float* __restrict__ resid, const float* __restrict__ gate_p,
               int N, int K, int brow, int bcol) {
    constexpr int WN = BN / 32;          // N frags per wave: 4 or 2
    constexpr int BWROWS = BN / 4;       // B rows staged per wave: 32 or 16
    __shared__ u16 As[2][128 * 64];
    __shared__ u16 Bs[2][BN * 64];
    const int t = threadIdx.x;
    const int lane = t & 63, wid = t >> 6;
    const int wm = wid >> 1, wn = wid & 1;
    const int l15 = lane & 15, hi = lane >> 4;
    const int rsw = l15 & 7;

    f32x4 acc[4][WN] = {};
    // staging: each gload_lds covers 8 rows x 64 cols; source segment pre-swizzled
    const int srow = lane >> 3;
    const int sseg = ((lane & 7) ^ srow) * 8;
    const u16* aBase = A + (size_t)(brow + wid * 32 + srow) * K + sseg;
    const u16* bBase = Bt + (size_t)(bcol + wid * BWROWS + srow) * K + sseg;

#define GSTAGE(KT, BF)                                                          \
    do {                                                                        \
        _Pragma("unroll")                                                       \
        for (int u = 0; u < 4; ++u)                                             \
            GLD_LDS16(aBase + (size_t)(u * 8) * K + (KT),                       \
                      &As[BF][(wid * 32 + u * 8) * 64]);                        \
        _Pragma("unroll")                                                       \
        for (int u = 0; u < BWROWS / 8; ++u)                                    \
            GLD_LDS16(bBase + (size_t)(u * 8) * K + (KT),                       \
                      &Bs[BF][(wid * BWROWS + u * 8) * 64]);                    \
    } while (0)

    GSTAGE(0, 0);
    __syncthreads();
    int buf = 0;
    for (int kt = 0; kt < K; kt += 64) {
        if (kt + 64 < K) GSTAGE(kt + 64, buf ^ 1);
        bf16x8 af[4][2], bfr[WN][2];
#pragma unroll
        for (int i = 0; i < 4; ++i) {
            int row = wm * 64 + i * 16 + l15;
#pragma unroll
            for (int ko = 0; ko < 2; ++ko)
                af[i][ko] = *reinterpret_cast<const bf16x8*>(
                    &As[buf][row * 64 + (((ko * 4 + hi) ^ rsw) * 8)]);
        }
#pragma unroll
        for (int j = 0; j < WN; ++j) {
            int row = wn * (BN / 2) + j * 16 + l15;
#pragma unroll
            for (int ko = 0; ko < 2; ++ko)
                bfr[j][ko] = *reinterpret_cast<const bf16x8*>(
                    &Bs[buf][row * 64 + (((ko * 4 + hi) ^ rsw) * 8)]);
        }
#pragma unroll
        for (int ko = 0; ko < 2; ++ko)
#pragma unroll
            for (int i = 0; i < 4; ++i)
#pragma unroll
                for (int j = 0; j < WN; ++j)
                    acc[i][j] = __builtin_amdgcn_mfma_f32_16x16x32_bf16(
                        af[i][ko], bfr[j][ko], acc[i][j], 0, 0, 0);
        __syncthreads();   // drains prefetch vmcnt; all waves done reading buf
        buf ^= 1;
    }
#undef GSTAGE

    float g = 0.f;
    if (MODE == 1) g = 1.0f / (1.0f + expf(-gate_p[0]));
    const int r0 = hi * 4, c0 = l15;
#pragma unroll
    for (int i = 0; i < 4; ++i) {
#pragma unroll
        for (int j = 0; j < WN; ++j) {
            int col = bcol + wn * (BN / 2) + j * 16 + c0;
#pragma unroll
            for (int r = 0; r < 4; ++r) {
                int row = brow + wm * 64 + i * 16 + r0 + r;
                float v = acc[i][j][r];
                if (MODE == 0) Cb[(size_t)row * N + col] = f2bf(v);
                else Cf[(size_t)row * N + col] = resid[(size_t)row * N + col] + g * v;
            }
        }
    }
}

// wrapper with XCD-aware bijective swizzle (active only when nwg % 8 == 0)
template <int MODE, int BN>
__global__ __launch_bounds__(256)
void gemm_tn(const u16* __restrict__ A, const u16* __restrict__ Bt,
             u16* __restrict__ Cb, float* __restrict__ Cf,
             const float* __restrict__ resid, const float* __restrict__ gate_p,
             int M, int N, int K) {
    int nbx = gridDim.x;
    int nwg = nbx * gridDim.y;
    int lin = blockIdx.y * nbx + blockIdx.x;
    if (!(nwg & 7)) { int q = nwg >> 3; lin = (lin & 7) * q + (lin >> 3); }
    gemm_body<MODE, BN>(A, Bt, Cb, Cf, resid, gate_p, N, K,
                        (lin / nbx) * 128, (lin % nbx) * BN);
}

// dual-problem wrapper (kc/vc fused): blockIdx.z selects the pointer set
template <int MODE, int BN>
__global__ __launch_bounds__(256)
void gemm_tn_z2(const u16* __restrict__ A0, const u16* __restrict__ B0, u16* __restrict__ C0,
                const u16* __restrict__ A1, const u16* __restrict__ B1, u16* __restrict__ C1,
                int N, int K) {
    const u16* A = blockIdx.z ? A1 : A0;
    const u16* B = blockIdx.z ? B1 : B0;
    u16* C = blockIdx.z ? C1 : C0;
    gemm_body<MODE, BN>(A, B, C, nullptr, nullptr, nullptr, N, K,
                        blockIdx.y * 128, blockIdx.x * BN);
}

// ---------------- coarse attention (ND=64 keys, exact softmax, exp2 domain) --------
__global__ __launch_bounds__(256)
void coarse_attn(const u16* __restrict__ q, const u16* __restrict__ kc,
                 const u16* __restrict__ vc, const float* __restrict__ mask,
                 float* __restrict__ doc_part, u16* __restrict__ attn_c) {
    constexpr int SC = 2048 / 64;
    int bid = blockIdx.x;
    int b = bid / (NH * SC);
    int rem = bid % (NH * SC);
    int h = rem / SC, sc = rem % SC;
    int kv = h >> 2;
    int t = threadIdx.x, lane = t & 63, wid = t >> 6;
    const int l15 = lane & 15, k0 = (lane >> 4) * 8;

    __shared__ u16 Kt[64 * 136];
    __shared__ u16 Vt[128 * 72];
    __shared__ u16 Pt[4][16 * 72];
    __shared__ float p_acc[64];

    {   // stage K [64 keys][128 d]
        int n = t >> 2, s2 = t & 3;
        const u16* src = kc + (size_t)(b * 64 + n) * 512 + kv * 128;
#pragma unroll
        for (int u = 0; u < 4; ++u) {
            int sg = s2 + u * 4;
            *reinterpret_cast<uint4*>(&Kt[n * 136 + sg * 8]) =
                *reinterpret_cast<const uint4*>(src + sg * 8);
        }
    }
    {   // stage V transposed: Vt[d][key]
        int n = t & 63, dblk = t >> 6;
        const u16* src = vc + (size_t)(b * 64 + n) * 512 + kv * 128 + dblk * 32;
#pragma unroll
        for (int u = 0; u < 4; ++u) {
            u16 tmp[8];
            *reinterpret_cast<uint4*>(tmp) = *reinterpret_cast<const uint4*>(src + u * 8);
#pragma unroll
            for (int e = 0; e < 8; ++e) Vt[(dblk * 32 + u * 8 + e) * 72 + n] = tmp[e];
        }
    }
    if (t < 64) p_acc[t] = 0.f;
    __syncthreads();

    int qrow = sc * 64 + wid * 16 + l15;
    const u16* qsrc = q + (size_t)(b * 2048 + qrow) * 2048 + h * 128;
    bf16x8 af[4];
#pragma unroll
    for (int kk = 0; kk < 4; ++kk)
        af[kk] = *reinterpret_cast<const bf16x8*>(qsrc + kk * 32 + k0);

    f32x4 sc4[4] = {};
#pragma unroll
    for (int kk = 0; kk < 4; ++kk)
#pragma unroll
        for (int j = 0; j < 4; ++j) {
            bf16x8 bfr = *reinterpret_cast<const bf16x8*>(&Kt[(j * 16 + l15) * 136 + kk * 32 + k0]);
            sc4[j] = __builtin_amdgcn_mfma_f32_16x16x32_bf16(af[kk], bfr, sc4[j], 0, 0, 0);
        }

    float s[4][4];
#pragma unroll
    for (int j = 0; j < 4; ++j) {
        float bia = (1.0f - mask[b * 64 + j * 16 + l15]) * (-1e9f * L2E);
#pragma unroll
        for (int r = 0; r < 4; ++r) s[j][r] = sc4[j][r] * SCALE2 + bia;
    }
    float m4[4], l4[4];
#pragma unroll
    for (int r = 0; r < 4; ++r) {
        float m = fmaxf(fmaxf(s[0][r], s[1][r]), fmaxf(s[2][r], s[3][r]));
#pragma unroll
        for (int d = 1; d < 16; d <<= 1) m = fmaxf(m, __shfl_xor(m, d));
        m4[r] = m;
    }
#pragma unroll
    for (int r = 0; r < 4; ++r) {
        float l = 0.f;
#pragma unroll
        for (int j = 0; j < 4; ++j) { s[j][r] = exp2f(s[j][r] - m4[r]); l += s[j][r]; }
#pragma unroll
        for (int d = 1; d < 16; d <<= 1) l += __shfl_xor(l, d);
        l4[r] = l;
    }
#pragma unroll
    for (int j = 0; j < 4; ++j) {
        float cs = 0.f;
#pragma unroll
        for (int r = 0; r < 4; ++r) {
            float pr = s[j][r] / l4[r];
            Pt[wid][((lane >> 4) * 4 + r) * 72 + j * 16 + l15] = f2bf(pr);
            cs += pr;
        }
        cs += __shfl_xor(cs, 16);
        cs += __shfl_xor(cs, 32);
        if (lane < 16) atomicAdd(&p_acc[j * 16 + lane], cs);
    }
    __syncthreads();

    f32x4 o4[8] = {};
#pragma unroll
    for (int kk2 = 0; kk2 < 2; ++kk2) {
        bf16x8 a2 = *reinterpret_cast<const bf16x8*>(&Pt[wid][l15 * 72 + kk2 * 32 + k0]);
#pragma unroll
        for (int j2 = 0; j2 < 8; ++j2) {
            bf16x8 b2 = *reinterpret_cast<const bf16x8*>(&Vt[(j2 * 16 + l15) * 72 + kk2 * 32 + k0]);
            o4[j2] = __builtin_amdgcn_mfma_f32_16x16x32_bf16(a2, b2, o4[j2], 0, 0, 0);
        }
    }
#pragma unroll
    for (int j2 = 0; j2 < 8; ++j2)
#pragma unroll
        for (int r = 0; r < 4; ++r) {
            int row = sc * 64 + wid * 16 + (lane >> 4) * 4 + r;
            attn_c[(size_t)(b * 2048 + row) * 2048 + h * 128 + j2 * 16 + l15] = f2bf(o4[j2][r]);
        }
    if (t < 64) atomicAdd(&doc_part[(blockIdx.x & 7) * 128 + b * 64 + t], p_acc[t]);
}

// ---------------- fine bias (doc-score finalize fused; bias pre-scaled by log2e) ----
__global__ __launch_bounds__(256)
void bias_kernel(const float* __restrict__ doc_part, const int* __restrict__ map,
                 const float* __restrict__ tmask, float* __restrict__ bias) {
    __shared__ float lg[128];
    int t = threadIdx.x;
    if (t < 128) {
        float s = 0.f;
#pragma unroll
        for (int i = 0; i < 8; ++i) s += doc_part[i * 128 + t];
        lg[t] = logf(s / 32768.0f + 1e-6f);
    }
    __syncthreads();
    int i = blockIdx.x * 256 + t;
    if (i >= 2 * 2048) return;
    int b = i >> 11;
    bias[i] = (lg[b * 64 + map[i]] + (1.0f - tmask[i]) * -1e9f) * L2E;
}

// ---------------- fine flash attention v7 ----------------
// QBLK=32/wave; K AND V double-buffered, prefetch(t+1) at tile start,
// SINGLE barrier per tile (at tile end -> vmcnt drain ~1000cyc after issue =
// cheap; r8's mid-tile BAR1 drained the prefetch prematurely). LDS = 80 KB.
__global__ __launch_bounds__(256, 2)
void flash_attn(const u16* __restrict__ q, const u16* __restrict__ kf,
                const u16* __restrict__ vT, const float* __restrict__ bias,
                u16* __restrict__ attn_f) {
    int bid = blockIdx.x;
    int b = bid >> 8;              // NH * 16 = 256 blocks per batch
    int rem = bid & 255;
    int h = rem >> 4, sc = rem & 15;
    int kv = h >> 2;
    int t = threadIdx.x, lane = t & 63, wid = t >> 6;
    const int l15 = lane & 15, hi = lane >> 4;
    const int k0 = hi * 8;
    const int rswp = l15 & 7;

    __shared__ u16 Kt[2][64 * 128];    // [key][d], swizzled 16B slots (32 KB)
    __shared__ u16 Vt[2][128 * 64];    // [d][key], swizzled 16B slots (32 KB)
    __shared__ u16 Pt[4][32 * 64];     // per-wave P[q][key], XOR-swizzled (16 KB)

    // Q fragments: 2 q-frags of 16 rows each
    bf16x8 qf4[2][4];
#pragma unroll
    for (int f = 0; f < 2; ++f) {
        int qrow = sc * 128 + wid * 32 + f * 16 + l15;
        const u16* qsrc = q + (size_t)(b * 2048 + qrow) * 2048 + h * 128;
#pragma unroll
        for (int kk = 0; kk < 4; ++kk)
            qf4[f][kk] = *reinterpret_cast<const bf16x8*>(qsrc + kk * 32 + k0);
    }

    // staging lane roles (constant over tiles)
    const int krl = lane >> 4, kslot = lane & 15;   // K: 4 rows x 16 slots per 1KB
    const int vrl = lane >> 3, vslot = lane & 7;    // V: 8 rows x 8 slots per 1KB
    const u16* kbase = kf + (size_t)(b * 2048) * 512 + kv * 128;
    const u16* vbase = vT + (size_t)(kv * 128) * 4096 + b * 2048;
    const float* bbase = bias + b * 2048;

#define STAGE_K(TT, BF)                                                            \
    do {                                                                           \
        _Pragma("unroll")                                                          \
        for (int u = 0; u < 4; ++u) {                                              \
            int row = wid * 16 + u * 4 + krl;                                      \
            const u16* src = kbase + (size_t)((TT) + row) * 512                    \
                             + ((kslot ^ (row & 7)) * 8);                          \
            GLD_LDS16(src, &Kt[BF][(wid * 16 + u * 4) * 128]);                     \
        }                                                                          \
    } while (0)
#define STAGE_V(TT, BF)                                                            \
    do {                                                                           \
        _Pragma("unroll")                                                          \
        for (int u = 0; u < 4; ++u) {                                              \
            int row = wid * 32 + u * 8 + vrl;                                      \
            const u16* src = vbase + (size_t)row * 4096 + (TT)                     \
                             + ((vslot ^ (row & 7)) * 8);                          \
            GLD_LDS16(src, &Vt[BF][(wid * 32 + u * 8) * 64]);                      \
        }                                                                          \
    } while (0)

    float mstate[2] = {-1e30f, -1e30f}, lstate[2] = {0.f, 0.f};   // log2 domain
    f32x4 o4[2][8] = {};

    STAGE_K(0, 0);
    STAGE_V(0, 0);
    __syncthreads();
    int par = 0;

    for (int t0 = 0; t0 < 2048; t0 += 64) {
        int t1 = (t0 + 64) & 2047;          // wrap-around prefetch (last iter harmless)
        STAGE_K(t1, par ^ 1);
        STAGE_V(t1, par ^ 1);

        // QK^T swapped: S^T[key][q] = K-frag (A) x Q-frag (B); K-frag feeds 2 MFMAs
        f32x4 st0[4] = {}, st1[4] = {};
        __builtin_amdgcn_s_setprio(1);
#pragma unroll
        for (int kk = 0; kk < 4; ++kk)
#pragma unroll
            for (int kb = 0; kb < 4; ++kb) {
                int row = kb * 16 + l15;
                bf16x8 kfrag = *reinterpret_cast<const bf16x8*>(
                    &Kt[par][row * 128 + (((kk * 4 + hi) ^ (row & 7)) * 8)]);
                st0[kb] = __builtin_amdgcn_mfma_f32_16x16x32_bf16(kfrag, qf4[0][kk], st0[kb], 0, 0, 0);
                st1[kb] = __builtin_amdgcn_mfma_f32_16x16x32_bf16(kfrag, qf4[1][kk], st1[kb], 0, 0, 0);
            }
        __builtin_amdgcn_s_setprio(0);

        // per-lane: q = f*16 + l15, keys = kb*16 + hi*4 + r ; log2 domain
        float p[2][4][4];
        float pmax[2] = {-1e30f, -1e30f};
#pragma unroll
        for (int kb = 0; kb < 4; ++kb) {
            float4 b4 = *reinterpret_cast<const float4*>(bbase + t0 + kb * 16 + hi * 4);
            float bb[4] = {b4.x, b4.y, b4.z, b4.w};
#pragma unroll
            for (int r = 0; r < 4; ++r) {
                float v0 = st0[kb][r] * SCALE2 + bb[r];
                float v1 = st1[kb][r] * SCALE2 + bb[r];
                p[0][kb][r] = v0;
                p[1][kb][r] = v1;
                pmax[0] = fmaxf(pmax[0], v0);
                pmax[1] = fmaxf(pmax[1], v1);
            }
        }
#pragma unroll
        for (int f = 0; f < 2; ++f) {
            pmax[f] = fmaxf(pmax[f], __shfl_xor(pmax[f], 16));
            pmax[f] = fmaxf(pmax[f], __shfl_xor(pmax[f], 32));
        }

        // defer-max (T13): combined branch; rescale both frags when either needs it
        bool need = (pmax[0] > mstate[0] + THR2) || (pmax[1] > mstate[1] + THR2);
        if (__any(need)) {
#pragma unroll
            for (int f = 0; f < 2; ++f) {
                float mnew = fmaxf(mstate[f], pmax[f]);
                float sco = exp2f(mstate[f] - mnew);
                float sco_out[4];
#pragma unroll
                for (int r = 0; r < 4; ++r) sco_out[r] = __shfl(sco, hi * 4 + r);
#pragma unroll
                for (int j2 = 0; j2 < 8; ++j2)
#pragma unroll
                    for (int r = 0; r < 4; ++r) o4[f][j2][r] *= sco_out[r];
                lstate[f] *= sco;
                mstate[f] = mnew;
            }
        }

#pragma unroll
        for (int f = 0; f < 2; ++f) {
            float lt = 0.f;
#pragma unroll
            for (int kb = 0; kb < 4; ++kb)
#pragma unroll
                for (int r = 0; r < 4; ++r) {
                    p[f][kb][r] = exp2f(p[f][kb][r] - mstate[f]);
                    lt += p[f][kb][r];
                }
            lt += __shfl_xor(lt, 16);
            lt += __shfl_xor(lt, 32);
            lstate[f] += lt;
        }

        // write P[q][key] (per-wave, swizzled b64 writes; same-wave DS ordering)
#pragma unroll
        for (int f = 0; f < 2; ++f)
#pragma unroll
            for (int kb = 0; kb < 4; ++kb) {
                uint2 w;
                w.x = pack2_cvt(p[f][kb][0], p[f][kb][1]);
                w.y = pack2_cvt(p[f][kb][2], p[f][kb][3]);
                int idx = (f * 16 + l15) * 64
                        + (((kb * 2 + (hi >> 1)) ^ rswp) * 8) + (hi & 1) * 4;
                *reinterpret_cast<uint2*>(&Pt[wid][idx]) = w;
            }

        // PV: O[q][d] += P (A) x V^T-frag (B); V-frag feeds 2 MFMAs
        // (no barrier: Pt is per-wave RAW; Vt[par] was staged a full tile ago)
        __builtin_amdgcn_s_setprio(1);
#pragma unroll
        for (int kc = 0; kc < 2; ++kc) {
            bf16x8 pa0 = *reinterpret_cast<const bf16x8*>(
                &Pt[wid][l15 * 64 + (((kc * 4 + hi) ^ rswp) * 8)]);
            bf16x8 pa1 = *reinterpret_cast<const bf16x8*>(
                &Pt[wid][(16 + l15) * 64 + (((kc * 4 + hi) ^ rswp) * 8)]);
#pragma unroll
            for (int j2 = 0; j2 < 8; ++j2) {
                int d = j2 * 16 + l15;
                bf16x8 vb = *reinterpret_cast<const bf16x8*>(
                    &Vt[par][d * 64 + (((kc * 4 + hi) ^ (d & 7)) * 8)]);
                o4[0][j2] = __builtin_amdgcn_mfma_f32_16x16x32_bf16(pa0, vb, o4[0][j2], 0, 0, 0);
                o4[1][j2] = __builtin_amdgcn_mfma_f32_16x16x32_bf16(pa1, vb, o4[1][j2], 0, 0, 0);
            }
        }
        __builtin_amdgcn_s_setprio(0);
        __syncthreads();   // single drain point: prefetches landed, waves joined
        par ^= 1;
    }
#undef STAGE_K
#undef STAGE_V

    // l is in softmax layout (q = l15 per frag); outputs need q = hi*4+r
#pragma unroll
    for (int f = 0; f < 2; ++f) {
        float linv[4];
#pragma unroll
        for (int r = 0; r < 4; ++r) linv[r] = 1.0f / __shfl(lstate[f], hi * 4 + r);
#pragma unroll
        for (int j2 = 0; j2 < 8; ++j2)
#pragma unroll
            for (int r = 0; r < 4; ++r) {
                int row = sc * 128 + wid * 32 + f * 16 + hi * 4 + r;
                attn_f[(size_t)(b * 2048 + row) * 2048 + h * 128 + j2 * 16 + l15] =
                    f2bf(o4[f][j2][r] * linv[r]);
            }
    }
}

// ---------------- launch ----------------
extern "C" void kernel_launch(void* const* d_in, const int* in_sizes, int n_in,
                              void* d_out, int out_size, void* d_ws, size_t ws_size,
                              hipStream_t stream) {
    const float* hidden = (const float*)d_in[0];
    const float* dsk    = (const float*)d_in[1];
    const float* dsv    = (const float*)d_in[2];
    const float* dsmask = (const float*)d_in[3];
    const float* tk     = (const float*)d_in[4];
    const float* tv     = (const float*)d_in[5];
    const float* tmask  = (const float*)d_in[6];
    const float* cn_w   = (const float*)d_in[7];
    const float* cq_w   = (const float*)d_in[8];
    const float* ck_w   = (const float*)d_in[9];
    const float* cv_w   = (const float*)d_in[10];
    const float* co_w   = (const float*)d_in[11];
    const float* c_gate = (const float*)d_in[12];
    const float* fn_w   = (const float*)d_in[13];
    const float* fq_w   = (const float*)d_in[14];
    const float* fk_w   = (const float*)d_in[15];
    const float* fv_w   = (const float*)d_in[16];
    const float* fo_w   = (const float*)d_in[17];
    const float* f_gate = (const float*)d_in[18];
    const int*   map    = (const int*)d_in[19];
    float* out_f = (float*)d_out;   // also the f32 buffer for coarse residual

    char* ws = (char*)d_ws;
    size_t off = 0;
    auto alloc = [&](size_t bytes) {
        char* p = ws + off;
        off += (bytes + 255) & ~(size_t)255;
        return p;
    };
    u16*  normA = (u16*)alloc(4096ULL * 2048 * 2);
    u16*  qbuf  = (u16*)alloc(4096ULL * 2048 * 2);
    u16*  kc    = (u16*)alloc(128ULL * 512 * 2);
    u16*  vc    = (u16*)alloc(128ULL * 512 * 2);
    u16*  dskb  = (u16*)alloc(128ULL * 2048 * 2);
    u16*  dsvb  = (u16*)alloc(128ULL * 2048 * 2);
    u16*  kfb   = (u16*)alloc(4096ULL * 512 * 2);
    u16*  vTb   = (u16*)alloc(512ULL * 4096 * 2);   // V^T [kv*128+d][b*2048+t]
    u16*  cqT   = (u16*)alloc(2048ULL * 2048 * 2);
    u16*  ckT   = (u16*)alloc(512ULL * 2048 * 2);
    u16*  cvT   = (u16*)alloc(512ULL * 2048 * 2);
    u16*  coT   = (u16*)alloc(2048ULL * 2048 * 2);
    u16*  fqT   = (u16*)alloc(2048ULL * 2048 * 2);
    u16*  fkT   = (u16*)alloc(512ULL * 2048 * 2);
    u16*  fvT   = (u16*)alloc(512ULL * 2048 * 2);
    u16*  foT   = (u16*)alloc(2048ULL * 2048 * 2);
    float* doc_part = (float*)alloc(8 * 128 * 4);
    float* biasb    = (float*)alloc(4096 * 4);

    hipMemsetAsync(doc_part, 0, 8 * 128 * 4, stream);

    // weight transposes, batched: 4 big (2048x2048) + 4 small (2048x512)
    transpose_cvt4<<<dim3(64, 64, 4), 256, 0, stream>>>(cq_w, co_w, fq_w, fo_w,
                                                        cqT, coT, fqT, foT, 2048, 2048);
    transpose_cvt4<<<dim3(16, 64, 4), 256, 0, stream>>>(ck_w, cv_w, fk_w, fv_w,
                                                        ckT, cvT, fkT, fvT, 2048, 512);

    cvt_f32_bf16_2<<<(2 * 128 * 2048 / 4 + 255) / 256, 256, 0, stream>>>(
        dsk, dskb, dsv, dsvb, 128 * 2048 / 4);
    rmsnorm_kernel<<<4096, 256, 0, stream>>>(hidden, cn_w, normA);

    // coarse projections
    gemm_tn<0, 128><<<dim3(16, 32), 256, 0, stream>>>(normA, cqT, qbuf, nullptr, nullptr, nullptr, 4096, 2048, 2048);
    gemm_tn_z2<0, 64><<<dim3(8, 1, 2), 256, 0, stream>>>(dskb, ckT, kc, dsvb, cvT, vc, 512, 2048);

    // coarse attention (attn_c into normA) + doc-score partials
    coarse_attn<<<1024, 256, 0, stream>>>(qbuf, kc, vc, dsmask, doc_part, normA);
    bias_kernel<<<16, 256, 0, stream>>>(doc_part, map, tmask, biasb);

    // coarse o-proj + residual + gate -> d_out (f32)
    gemm_tn<1, 128><<<dim3(16, 32), 256, 0, stream>>>(normA, coT, nullptr, out_f, hidden, c_gate, 4096, 2048, 2048);

    // fine stage
    rmsnorm_kernel<<<4096, 256, 0, stream>>>(out_f, fn_w, qbuf);
    gemm_tn<0, 128><<<dim3(16, 32), 256, 0, stream>>>(qbuf, fqT, normA, nullptr, nullptr, nullptr, 4096, 2048, 2048);
    cvt_f32_bf16<<<(4096 * 2048 / 4 + 255) / 256, 256, 0, stream>>>(tk, qbuf, 4096 * 2048 / 4);
    gemm_tn<0, 64><<<dim3(8, 32), 256, 0, stream>>>(qbuf, fkT, kfb, nullptr, nullptr, nullptr, 4096, 512, 2048);
    cvt_f32_bf16<<<(4096 * 2048 / 4 + 255) / 256, 256, 0, stream>>>(tv, qbuf, 4096 * 2048 / 4);
    // V^T directly from the projection: vT[d][token] = fvT[d][:] . tv[token][:]
    gemm_tn<0, 64><<<dim3(64, 4), 256, 0, stream>>>(fvT, qbuf, vTb, nullptr, nullptr, nullptr, 512, 4096, 2048);

    flash_attn<<<512, 256, 0, stream>>>(normA, kfb, vTb, biasb, qbuf);

    // final o-proj + residual + gate -> d_out
    gemm_tn<1, 128><<<dim3(16, 32), 256, 0, stream>>>(qbuf, foT, nullptr, out_f, out_f, f_gate, 4096, 2048, 2048);
}